// Round 12
// baseline (168.085 us; speedup 1.0000x reference)
//
#include <hip/hip_runtime.h>
#include <hip/hip_bf16.h>

#define DEV static __device__ __forceinline__

typedef __attribute__((ext_vector_type(8))) short          s16x8;
typedef __attribute__((ext_vector_type(8))) unsigned short u16x8;
typedef __attribute__((ext_vector_type(4))) float          f32x4;
typedef __attribute__((ext_vector_type(4))) unsigned int   u32x4;

#define MFMA16(A,B,C) __builtin_amdgcn_mfma_f32_16x16x32_bf16((A),(B),(C),0,0,0)

DEV unsigned short f2bf(float f) {
  unsigned int u = __builtin_bit_cast(unsigned int, f);
  u += 0x7fffu + ((u >> 16) & 1u);
  return (unsigned short)(u >> 16);
}

// 1/sqrt(32) * log2(e): fold into Q projection so softmax uses exp2 directly
#define QSCL 0.25503562201f

// ------------------------- grid params -------------------------
#define GRID_LO  (-5.0f)
#define GRID_IH  (3.2f)        // 1/h, h = 0.3125, 32 cells over [-5,5]

DEV int cellc(float v) {
  int c = (int)floorf((v - GRID_LO) * GRID_IH);
  return min(31, max(0, c));
}

// ------------------------- ws layout -------------------------
constexpr size_t OFF_POS4  = 0;                       // 32768*16      = 524288
constexpr size_t OFF_COL   = 524288;                  // 4096*32*4     = 524288
constexpr size_t OFF_W1T   = 1048576;                 // 128*96*2
constexpr size_t OFF_W2T   = OFF_W1T  + 24576;
constexpr size_t OFF_WRT   = OFF_W2T  + 65536;
constexpr size_t OFF_WQKVT = OFF_WRT  + 65536;
constexpr size_t OFF_WOUTT = OFF_WQKVT+ 98304;
constexpr size_t OFF_WM1T  = OFF_WOUTT+ 32768;
constexpr size_t OFF_WM2T  = OFF_WM1T + 65536;
constexpr size_t OFF_H     = OFF_WM2T + 65536;        // 33554432 bytes (shared region)
// phase 1 (pre-conv): cell structures live in the H region
constexpr size_t OFF_SPOS    = OFF_H;                 // 32768*16 = 524288
constexpr size_t OFF_CELLCNT = OFF_H + 524288;        // 131072
constexpr size_t OFF_CELLDSC = OFF_H + 655360;        // 262144
constexpr size_t OFF_FILL    = OFF_H + 917504;        // 131072
// phase 2 (post-conv): attention partials live in the H region
constexpr size_t OFF_PO      = OFF_H;                 // 8*4096*128*4 = 16777216
constexpr size_t OFF_PL      = OFF_H + 16777216;      // 8*4*4096*4  = 524288
constexpr size_t OFF_AGG   = OFF_H    + 33554432;
constexpr size_t OFF_XT0   = OFF_AGG  + 4194304;
constexpr size_t OFF_QKV   = OFF_XT0  + 2097152;      // bf16 qkv
constexpr size_t OFF_ATT   = OFF_QKV  + 6291456;      // (unused now)
constexpr size_t OFF_PRE   = OFF_ATT  + 2097152;      // (unused now)
constexpr size_t OFF_XT1   = OFF_PRE  + 2097152;
constexpr size_t OFF_MLP1  = OFF_XT1  + 2097152;
constexpr size_t OFF_SBIAS = OFF_MLP1 + 4194304;      // 384*4 = 1536

// ------------------------- zero cell counts -------------------------
__global__ __launch_bounds__(256) void zero_k(int* __restrict__ p) {
  p[blockIdx.x * 256 + threadIdx.x] = 0;
}

// ------------------------- prep -------------------------
__global__ __launch_bounds__(256) void prep_k(
    const float* __restrict__ pos, const float* __restrict__ W1,
    const float* __restrict__ W2, const float* __restrict__ Wr,
    const float* __restrict__ ipw, const float* __restrict__ ipb,
    const float* __restrict__ opw,
    const float* __restrict__ Wm1, const float* __restrict__ Wm2,
    float4* __restrict__ pos4, unsigned short* __restrict__ w1t,
    unsigned short* __restrict__ w2t, unsigned short* __restrict__ wrt,
    unsigned short* __restrict__ wqkvt, unsigned short* __restrict__ woutt,
    unsigned short* __restrict__ wm1t, unsigned short* __restrict__ wm2t,
    int* __restrict__ cellcnt, float* __restrict__ sbias) {
  int T = blockIdx.x * 256 + threadIdx.x;
  if (T < 32768) {
    float px = pos[T*3], py = pos[T*3+1], pz = pos[T*3+2];
    pos4[T] = make_float4(px, py, pz, 0.f);
    int cid = (cellc(pz)*32 + cellc(py))*32 + cellc(px);
    atomicAdd(&cellcnt[cid], 1);
    return;
  }
  T -= 32768;
  if (T < 128*96)  { int n=T/96,  k=T%96;  w1t[T]  = f2bf(k < 67 ? W1[k*128+n] : 0.f); return; }
  T -= 128*96;
  if (T < 256*128) { int n=T/128, k=T%128; w2t[T]  = f2bf(W2[k*256+n]);  return; }
  T -= 256*128;
  if (T < 128*256) { int n=T/256, k=T%256; wrt[T]  = f2bf(Wr[k*128+n]);  return; }
  T -= 128*256;
  if (T < 384*128) { int n=T/128, k=T%128;
                     float v = ipw[k*384+n];
                     if (n < 128) v *= QSCL;
                     wqkvt[T]= f2bf(v); return; }
  T -= 384*128;
  if (T < 128*128) { int n=T/128, k=T%128; woutt[T]= f2bf(opw[k*128+n]); return; }
  T -= 128*128;
  if (T < 256*128) { int n=T/128, k=T%128; wm1t[T] = f2bf(Wm1[k*256+n]); return; }
  T -= 256*128;
  if (T < 128*256) { int n=T/256, k=T%256; wm2t[T] = f2bf(Wm2[k*128+n]); return; }
  T -= 128*256;
  if (T < 384) { sbias[T] = ipb[T] * (T < 128 ? QSCL : 1.f); return; }
}

// ------------------------- prefix over 32768 cell counts -------------------
__global__ __launch_bounds__(1024) void prefix_k(const int* __restrict__ cnt,
                                                 int2* __restrict__ desc,
                                                 int* __restrict__ fill) {
  __shared__ int wsum[16];
  const int tid = threadIdx.x, lane = tid & 63, w = tid >> 6;
  int loc[32]; int s = 0;
  #pragma unroll
  for (int i = 0; i < 32; ++i) { loc[i] = cnt[tid*32 + i]; s += loc[i]; }
  int sc = s;
  #pragma unroll
  for (int off = 1; off < 64; off <<= 1) {
    int v = __shfl_up(sc, off);
    if (lane >= off) sc += v;
  }
  if (lane == 63) wsum[w] = sc;
  __syncthreads();
  if (tid == 0) {
    int run = 0;
    #pragma unroll
    for (int i = 0; i < 16; ++i) { int v = wsum[i]; wsum[i] = run; run += v; }
  }
  __syncthreads();
  int base = wsum[w] + (sc - s);
  #pragma unroll
  for (int i = 0; i < 32; ++i) {
    int c = tid*32 + i;
    desc[c] = make_int2(base, loc[i]);
    fill[c] = base;
    base += loc[i];
  }
}

// ------------------------- scatter -------------------------
__global__ __launch_bounds__(256) void scatter_k(const float4* __restrict__ pos4,
                                                 int* __restrict__ fill,
                                                 float4* __restrict__ spos) {
  int T = blockIdx.x * 256 + threadIdx.x;
  float4 p = pos4[T];
  int cid = (cellc(p.z)*32 + cellc(p.y))*32 + cellc(p.x);
  int slot = atomicAdd(&fill[cid], 1);
  spos[slot] = make_float4(p.x, p.y, p.z, __int_as_float(T));
}

// ------------------------- KNN -------------------------
#define KNN_CAP  320
#define KNN_TRIG 192
#define KNN_KEEP 33
#define KNN_INF  3e37f

__global__ __launch_bounds__(256) void knn_k(
    const float4* __restrict__ spos, const int2* __restrict__ desc,
    const float4* __restrict__ pos4, const int* __restrict__ idx,
    int* __restrict__ col,
    float* __restrict__ outqpos, float* __restrict__ outbatch) {
  __shared__ float bufd[4][KNN_CAP];
  __shared__ int   bufi[4][KNN_CAP];
  __shared__ int   shist[4][64];
  __shared__ int2  segs[4][128];
  const int tid = threadIdx.x, lane = tid & 63, w = tid >> 6;
  const unsigned long long ltmask = (1ull << lane) - 1ull;

  const int q = blockIdx.x * 4 + w;
  const int iq = idx[q];
  const float4 qp = pos4[iq];
  const float qx = qp.x, qy = qp.y, qz = qp.z;
  const int cx0 = cellc(qx), cy0 = cellc(qy), cz0 = cellc(qz);

  float t = KNN_INF;
  int cnt = 0;

  auto compact = [&]() {
    int c_ = min(cnt, KNN_CAP);
    float vd[5]; int vi[5], bs[5]; bool okv[5];
    float dmax = 1e-30f;
    #pragma unroll
    for (int s = 0; s < 5; ++s) {
      int o2 = s*64 + lane;
      okv[s] = o2 < c_;
      vd[s] = okv[s] ? bufd[w][o2] : 0.f;
      vi[s] = okv[s] ? bufi[w][o2] : 0;
      dmax = fmaxf(dmax, vd[s]);
    }
    #pragma unroll
    for (int off = 1; off < 64; off <<= 1) dmax = fmaxf(dmax, __shfl_xor(dmax, off));
    float scale = 63.99f / dmax;
    shist[w][lane] = 0;
    #pragma unroll
    for (int s = 0; s < 5; ++s) {
      bs[s] = okv[s] ? min(63, (int)(vd[s] * scale)) : 64;
      if (okv[s]) atomicAdd(&shist[w][bs[s]], 1);
    }
    int h = shist[w][lane];
    #pragma unroll
    for (int off = 1; off < 64; off <<= 1) {
      int v = __shfl_up(h, off);
      if (lane >= off) h += v;
    }
    unsigned long long mk = __ballot(h >= KNN_KEEP);
    int E = mk ? (__ffsll((long long)mk) - 1) : 63;
    int base = 0;
    #pragma unroll
    for (int s = 0; s < 5; ++s) {
      bool keep = okv[s] && bs[s] <= E;
      unsigned long long km = __ballot(keep);
      int pp = base + (int)__popcll(km & ltmask);
      if (keep) { bufd[w][pp] = vd[s]; bufi[w][pp] = vi[s]; }
      base += (int)__popcll(km);
    }
    cnt = base;
    t = fminf(t, (float)(E + 1) / scale);
  };

  auto scan_rows = [&](int knew, int kold) {
    const int S = 2*knew + 1;
    const int NR = S*S;
    const float invS = 1.f / (float)S;
    for (int r0 = 0; r0 < NR; r0 += 64) {
      int r = r0 + lane;
      bool v = r < NR;
      int dz = (int)((float)r * invS);
      int rem = r - dz*S;
      if (rem < 0) { dz--; rem += S; } else if (rem >= S) { dz++; rem -= S; }
      int ccz = cz0 + dz - knew, ccy = cy0 + rem - knew;
      bool rowok = v && ccz >= 0 && ccz < 32 && ccy >= 0 && ccy < 32;
      bool inner = kold >= 0 && abs(dz - knew) <= kold && abs(rem - knew) <= kold;
      int cbase = (ccz*32 + ccy) * 32;
      int sL = 0, lL = 0, sR = 0, lR = 0;
      if (rowok) {
        int xa = max(cx0 - knew, 0);
        int xb = inner ? (cx0 - kold - 1) : min(cx0 + knew, 31);
        if (xa <= xb) {
          int2 d0 = desc[cbase + xa];
          int2 d1 = desc[cbase + xb];
          sL = d0.x; lL = d1.x + d1.y - d0.x;
        }
        if (inner) {
          int xa2 = cx0 + kold + 1, xb2 = min(cx0 + knew, 31);
          if (xa2 <= xb2 && xa2 >= 0) {
            int2 d0 = desc[cbase + xa2];
            int2 d1 = desc[cbase + xb2];
            sR = d0.x; lR = d1.x + d1.y - d0.x;
          }
        }
      }
      int cumL = lL;
      #pragma unroll
      for (int off = 1; off < 64; off <<= 1) {
        int vv = __shfl_up(cumL, off);
        if (lane >= off) cumL += vv;
      }
      int sumL = __shfl(cumL, 63);
      int cumR = lR;
      #pragma unroll
      for (int off = 1; off < 64; off <<= 1) {
        int vv = __shfl_up(cumR, off);
        if (lane >= off) cumR += vv;
      }
      int sumR = __shfl(cumR, 63);
      segs[w][lane]      = make_int2(sL, cumL - lL);
      segs[w][64 + lane] = make_int2(sR, sumL + cumR - lR);
      const int total = sumL + sumR;

      for (int b = 0; b < total; b += 320) {
        float d2v[5]; int piv[5]; bool hv[5];
        #pragma unroll
        for (int s5 = 0; s5 < 5; ++s5) {
          int p = b + s5*64 + lane;
          bool act = p < total;
          hv[s5] = false; d2v[s5] = 0.f; piv[s5] = 0;
          if (act) {
            int lo = 0;
            #pragma unroll
            for (int st = 64; st > 0; st >>= 1)
              if (segs[w][lo + st].y <= p) lo += st;
            int2 e = segs[w][lo];
            float4 pt = spos[e.x + (p - e.y)];
            float ddx = qx-pt.x, ddy = qy-pt.y, ddz = qz-pt.z;
            float d2 = ddx*ddx + ddy*ddy + ddz*ddz;
            d2v[s5] = d2; piv[s5] = __float_as_int(pt.w);
            hv[s5] = d2 < t;
          }
        }
        #pragma unroll
        for (int s5 = 0; s5 < 5; ++s5) {
          unsigned long long hm = __ballot(hv[s5]);
          if (hm) {
            int pp = cnt + (int)__popcll(hm & ltmask);
            if (hv[s5] && pp < KNN_CAP) { bufd[w][pp] = d2v[s5]; bufi[w][pp] = piv[s5]; }
            cnt += (int)__popcll(hm);
            if (cnt >= KNN_TRIG) compact();
          }
        }
      }
    }
  };

  auto bound32 = [&]() -> float {
    int c_ = min(cnt, KNN_CAP);
    float vv[5]; bool okv[5];
    float dmax = 1e-30f;
    #pragma unroll
    for (int s = 0; s < 5; ++s) {
      int o2 = s*64 + lane;
      okv[s] = o2 < c_;
      vv[s] = okv[s] ? bufd[w][o2] : 0.f;
      dmax = fmaxf(dmax, vv[s]);
    }
    #pragma unroll
    for (int off = 1; off < 64; off <<= 1) dmax = fmaxf(dmax, __shfl_xor(dmax, off));
    float scale = 63.99f / dmax;
    shist[w][lane] = 0;
    #pragma unroll
    for (int s = 0; s < 5; ++s)
      if (okv[s]) atomicAdd(&shist[w][min(63, (int)(vv[s] * scale))], 1);
    int h = shist[w][lane];
    #pragma unroll
    for (int off = 1; off < 64; off <<= 1) {
      int v = __shfl_up(h, off);
      if (lane >= off) h += v;
    }
    unsigned long long m = __ballot(h >= 32);
    int E = m ? (__ffsll((long long)m) - 1) : 63;
    return (float)(E + 1) / scale;
  };

  int kcur = 1;
  scan_rows(1, -1);
  for (int it = 0; it < 64; ++it) {
    if (cnt >= 32) {
      float t32u = bound32();
      t = fminf(t, t32u);
      int kneed = (int)(__builtin_sqrtf(t32u) * GRID_IH) + 1;
      if (kneed <= kcur || kcur >= 31) break;
      int knew = min(kneed, 31);
      scan_rows(knew, kcur);
      kcur = knew;
    } else {
      if (kcur >= 31) break;
      int knew = min(kcur + (cnt == 0 ? 2 : 1), 31);
      scan_rows(knew, kcur);
      kcur = knew;
    }
  }

  // ---- final exact top-32 ----
  {
    int c_ = min(cnt, KNN_CAP);
    float vd[5]; int vi[5], bs[5]; bool okf[5];
    float dmax = 1e-30f;
    #pragma unroll
    for (int s = 0; s < 5; ++s) {
      int o2 = s*64 + lane;
      okf[s] = o2 < c_;
      vd[s] = okf[s] ? bufd[w][o2] : KNN_INF;
      vi[s] = okf[s] ? bufi[w][o2] : 0;
      dmax = fmaxf(dmax, okf[s] ? vd[s] : 0.f);
    }
    #pragma unroll
    for (int off = 1; off < 64; off <<= 1) dmax = fmaxf(dmax, __shfl_xor(dmax, off));
    float sc64 = 63.99f / dmax;
    shist[w][lane] = 0;
    #pragma unroll
    for (int s = 0; s < 5; ++s) {
      bs[s] = okf[s] ? min(63, (int)(vd[s] * sc64)) : 64;
      if (okf[s]) atomicAdd(&shist[w][bs[s]], 1);
    }
    int h = shist[w][lane];
    #pragma unroll
    for (int off = 1; off < 64; off <<= 1) {
      int v = __shfl_up(h, off);
      if (lane >= off) h += v;
    }
    unsigned long long m = __ballot(h >= 32);
    int E = m ? (__ffsll((long long)m) - 1) : 63;
    int c0 = (E > 0) ? __shfl(h, E - 1) : 0;
    int base = 0;
    #pragma unroll
    for (int s = 0; s < 5; ++s) {
      bool wr = okf[s] && (bs[s] < E);
      unsigned long long km = __ballot(wr);
      int pp = base + (int)__popcll(km & ltmask);
      if (wr) col[q*32 + pp] = vi[s];
      base += (int)__popcll(km);
    }
    #pragma unroll
    for (int s = 0; s < 5; ++s)
      if (!(okf[s] && bs[s] == E)) vd[s] = KNN_INF;
    int r = 32 - c0;
    #pragma unroll 1
    for (int kk = 0; kk < r; ++kk) {
      float bd = vd[0]; int bi = vi[0]; int bc = lane*8;
      #pragma unroll
      for (int s = 1; s < 5; ++s)
        if (vd[s] < bd) { bd = vd[s]; bi = vi[s]; bc = lane*8 + s; }
      #pragma unroll
      for (int off = 1; off < 64; off <<= 1) {
        float od = __shfl_xor(bd, off);
        int   oi = __shfl_xor(bi, off);
        int   oc = __shfl_xor(bc, off);
        if (od < bd || (od == bd && oc < bc)) { bd = od; bi = oi; bc = oc; }
      }
      if ((bc >> 3) == lane) {
        int sl = bc & 7;
        #pragma unroll
        for (int s = 0; s < 5; ++s) if (sl == s) vd[s] = KNN_INF;
      }
      if (lane == 0) col[q*32 + c0 + kk] = bi;
    }
  }
  if (lane == 0) {
    outqpos[q*3+0] = qx; outqpos[q*3+1] = qy; outqpos[q*3+2] = qz;
    outbatch[q] = 0.f;
  }
}

// ------------------------- fused conv -------------------------
#define LA1(r,c) S[(r)*104 + (c)]
#define LB1(r,c) S[13312 + (r)*104 + (c)]
#define HB(r,c)  S[(r)*136 + (c)]
#define W2C(r,c) S[17408 + (r)*136 + (c)]

__global__ __launch_bounds__(256) void conv_k(
    const float* __restrict__ x, const float4* __restrict__ pos4,
    const int* __restrict__ idx, const int* __restrict__ col,
    const unsigned short* __restrict__ w1t, const float* __restrict__ b1,
    const unsigned short* __restrict__ w2t, const float* __restrict__ b2,
    float* __restrict__ agg) {
  __shared__ __align__(16) unsigned short S[26624];
  __shared__ int   sci[128];
  __shared__ float sqp[4][3];
  const int tid = threadIdx.x, lane = tid & 63, w = tid >> 6;
  const int wm = w >> 1, wn = w & 1;
  const int m0 = blockIdx.x * 4;

  if (tid < 128) sci[tid] = col[m0*32 + tid];
  if (tid >= 128 && tid < 132) {
    int m = m0 + tid - 128;
    float4 p = pos4[idx[m]];
    sqp[tid-128][0] = p.x; sqp[tid-128][1] = p.y; sqp[tid-128][2] = p.z;
  }
  #pragma unroll
  for (int rnd = 0; rnd < 6; ++rnd) {
    int e = (rnd*256 + tid) * 8;
    int n = e / 96, k = e % 96;
    *(u16x8*)&LB1(n, k) = *(const u16x8*)&w1t[e];
  }
  __syncthreads();

  {
    int r = tid >> 1, half = tid & 1;
    int ci = sci[r];
    const float* src = x + (size_t)ci*64 + half*32;
    #pragma unroll
    for (int c = 0; c < 4; ++c) {
      float4 va = ((const float4*)src)[c*2], vb = ((const float4*)src)[c*2+1];
      u16x8 v;
      v[0]=f2bf(va.x); v[1]=f2bf(va.y); v[2]=f2bf(va.z); v[3]=f2bf(va.w);
      v[4]=f2bf(vb.x); v[5]=f2bf(vb.y); v[6]=f2bf(vb.z); v[7]=f2bf(vb.w);
      *(u16x8*)&LA1(r, half*32 + c*8) = v;
    }
  }
  if (tid < 128) {
    int r = tid, g = r >> 5;
    float4 p = pos4[sci[r]];
    u16x8 z;
    #pragma unroll
    for (int e = 0; e < 8; ++e) z[e] = 0;
    u16x8 v0 = z;
    v0[0] = f2bf(p.x - sqp[g][0]); v0[1] = f2bf(p.y - sqp[g][1]); v0[2] = f2bf(p.z - sqp[g][2]);
    *(u16x8*)&LA1(r, 64) = v0;
    #pragma unroll
    for (int c = 1; c < 5; ++c) *(u16x8*)&LA1(r, 64 + c*8) = z;
  }
  __syncthreads();

  f32x4 acc[4][4];
  #pragma unroll
  for (int nf = 0; nf < 4; ++nf) {
    float bv = b1[wn*64 + nf*16 + (lane & 15)];
    #pragma unroll
    for (int mf = 0; mf < 4; ++mf) acc[mf][nf] = f32x4{bv, bv, bv, bv};
  }
  #pragma unroll
  for (int kc = 0; kc < 3; ++kc) {
    s16x8 af[4], bf_[4];
    #pragma unroll
    for (int mf = 0; mf < 4; ++mf)
      af[mf] = *(const s16x8*)&LA1(wm*64 + mf*16 + (lane&15), kc*32 + (lane>>4)*8);
    #pragma unroll
    for (int nf = 0; nf < 4; ++nf)
      bf_[nf] = *(const s16x8*)&LB1(wn*64 + nf*16 + (lane&15), kc*32 + (lane>>4)*8);
    #pragma unroll
    for (int mf = 0; mf < 4; ++mf)
      #pragma unroll
      for (int nf = 0; nf < 4; ++nf)
        acc[mf][nf] = MFMA16(af[mf], bf_[nf], acc[mf][nf]);
  }
  __syncthreads();

  #pragma unroll
  for (int mf = 0; mf < 4; ++mf)
    #pragma unroll
    for (int nf = 0; nf < 4; ++nf)
      #pragma unroll
      for (int j = 0; j < 4; ++j) {
        int rloc = wm*64 + mf*16 + ((lane>>4)<<2) + j;
        int cloc = wn*64 + nf*16 + (lane & 15);
        HB(rloc, cloc) = f2bf(fmaxf(acc[mf][nf][j], 0.f));
      }
  {
    int r2 = tid >> 2, kq = (tid & 3) * 32;
    const unsigned short* src = w2t + (size_t)r2*128 + kq;
    #pragma unroll
    for (int c = 0; c < 4; ++c)
      *(u16x8*)&W2C(r2, kq + c*8) = *(const u16x8*)&src[c*8];
  }
  __syncthreads();

  #pragma unroll 1
  for (int nc = 0; nc < 4; ++nc) {
    f32x4 acc2[2][4];
    #pragma unroll
    for (int nf = 0; nf < 4; ++nf) {
      float bv = b2[nc*64 + nf*16 + (lane & 15)];
      acc2[0][nf] = f32x4{bv, bv, bv, bv};
      acc2[1][nf] = f32x4{bv, bv, bv, bv};
    }
    #pragma unroll
    for (int ks = 0; ks < 4; ++ks) {
      s16x8 af[2], bf_[4];
      #pragma unroll
      for (int mf = 0; mf < 2; ++mf)
        af[mf] = *(const s16x8*)&HB(w*32 + mf*16 + (lane&15), ks*32 + (lane>>4)*8);
      #pragma unroll
      for (int nf = 0; nf < 4; ++nf)
        bf_[nf] = *(const s16x8*)&W2C(nf*16 + (lane&15), ks*32 + (lane>>4)*8);
      #pragma unroll
      for (int mf = 0; mf < 2; ++mf)
        #pragma unroll
        for (int nf = 0; nf < 4; ++nf)
          acc2[mf][nf] = MFMA16(af[mf], bf_[nf], acc2[mf][nf]);
    }
    #pragma unroll
    for (int nf = 0; nf < 4; ++nf) {
      float mx = acc2[0][nf][0];
      #pragma unroll
      for (int j = 1; j < 4; ++j) mx = fmaxf(mx, acc2[0][nf][j]);
      #pragma unroll
      for (int j = 0; j < 4; ++j) mx = fmaxf(mx, acc2[1][nf][j]);
      mx = fmaxf(mx, __shfl_xor(mx, 16));
      mx = fmaxf(mx, __shfl_xor(mx, 32));
      if (lane < 16) agg[(size_t)(m0 + w)*256 + nc*64 + nf*16 + lane] = mx;
    }
    if (nc < 3) {
      __syncthreads();
      int r2 = tid >> 2, kq = (tid & 3) * 32;
      const unsigned short* src = w2t + (size_t)((nc+1)*64 + r2)*128 + kq;
      #pragma unroll
      for (int c = 0; c < 4; ++c)
        *(u16x8*)&W2C(r2, kq + c*8) = *(const u16x8*)&src[c*8];
      __syncthreads();
    }
  }
}

// ------------------------- 64x64-tile GEMM -------------------------
template<int KFULL, int NFULL, bool RELU, bool HAS_RES, bool OBF16>
__global__ __launch_bounds__(256) void gemm_k(
    const float* __restrict__ A, const unsigned short* __restrict__ Bt,
    const float* __restrict__ bias, const float* __restrict__ res,
    float* __restrict__ out) {
  __shared__ unsigned short lA[64][72];
  __shared__ unsigned short lB[64][72];
  const int tid = threadIdx.x, lane = tid & 63, w = tid >> 6;
  const int m0 = blockIdx.x * 64, n0 = blockIdx.y * 64;

  f32x4 acc[4];
  #pragma unroll
  for (int nf = 0; nf < 4; ++nf) {
    float bv = bias[n0 + nf*16 + (lane & 15)];
    acc[nf] = f32x4{bv, bv, bv, bv};
  }

  for (int kb = 0; kb < KFULL; kb += 64) {
    __syncthreads();
    {
      int r = tid >> 2, kq = (tid & 3) * 16;
      const float* src = A + (size_t)(m0 + r)*KFULL + kb + kq;
      #pragma unroll
      for (int c = 0; c < 2; ++c) {
        float4 va = ((const float4*)src)[c*2], vb = ((const float4*)src)[c*2+1];
        u16x8 v;
        v[0]=f2bf(va.x); v[1]=f2bf(va.y); v[2]=f2bf(va.z); v[3]=f2bf(va.w);
        v[4]=f2bf(vb.x); v[5]=f2bf(vb.y); v[6]=f2bf(vb.z); v[7]=f2bf(vb.w);
        *(u16x8*)&lA[r][kq + c*8] = v;
      }
      const unsigned short* srcb = Bt + (size_t)(n0 + r)*KFULL + kb + kq;
      #pragma unroll
      for (int c = 0; c < 2; ++c)
        *(u16x8*)&lB[r][kq + c*8] = *(const u16x8*)&srcb[c*8];
    }
    __syncthreads();
    #pragma unroll
    for (int ks = 0; ks < 2; ++ks) {
      s16x8 af = *(const s16x8*)&lA[w*16 + (lane&15)][ks*32 + (lane>>4)*8];
      s16x8 bf_[4];
      #pragma unroll
      for (int nf = 0; nf < 4; ++nf)
        bf_[nf] = *(const s16x8*)&lB[nf*16 + (lane&15)][ks*32 + (lane>>4)*8];
      #pragma unroll
      for (int nf = 0; nf < 4; ++nf)
        acc[nf] = MFMA16(af, bf_[nf], acc[nf]);
    }
  }
  #pragma unroll
  for (int nf = 0; nf < 4; ++nf)
    #pragma unroll
    for (int j = 0; j < 4; ++j) {
      int row = m0 + w*16 + ((lane>>4)<<2) + j;
      int colg = n0 + nf*16 + (lane & 15);
      float v = acc[nf][j];
      if (HAS_RES) v += res[(size_t)row*NFULL + colg];
      if (RELU)    v = fmaxf(v, 0.f);
      if (OBF16) ((unsigned short*)out)[(size_t)row*NFULL + colg] = f2bf(v);
      else       out[(size_t)row*NFULL + colg] = v;
    }
}

// ------------------------- fused GEMM + residual + LayerNorm ---------------
// C_row = LN( (A @ Bt + bias) + res )  per 128-wide row; 64 rows/block.
// COMBINE: A is built on the fly from 8 attention partials (po, pl).
template<int KFULL, bool COMBINE>
__global__ __launch_bounds__(256) void gemmln_k(
    const float* __restrict__ A,
    const float* __restrict__ po, const float* __restrict__ pl,
    const unsigned short* __restrict__ Bt, const float* __restrict__ bias,
    const float* __restrict__ res,
    const float* __restrict__ gam, const float* __restrict__ bet,
    float* __restrict__ out) {
  __shared__ unsigned short lA[64][KFULL + 8];
  __shared__ unsigned short lB[128][72];
  const int tid = threadIdx.x, lane = tid & 63, w = tid >> 6;
  const int g = lane >> 4, ln_ = lane & 15;
  const int m0 = blockIdx.x * 64;

  // ---- stage A (full K width) ----
  if (COMBINE) {
    int r = tid >> 2, hh = tid & 3;          // thread covers head hh cols
    int row = m0 + r;
    float lsum = 0.f;
    #pragma unroll
    for (int s = 0; s < 8; ++s) lsum += pl[((s*4 + hh) << 12) + row];
    float inv = 1.f / lsum;
    const float4* pob = (const float4*)po;
    #pragma unroll
    for (int c2 = 0; c2 < 4; ++c2) {
      float ax=0,ay=0,az=0,aw=0, bx=0,by=0,bz=0,bw=0;
      #pragma unroll
      for (int s = 0; s < 8; ++s) {
        size_t b = ((size_t)s*4096 + row)*32 + hh*8 + c2*2;
        float4 x0 = pob[b], x1 = pob[b+1];
        ax+=x0.x; ay+=x0.y; az+=x0.z; aw+=x0.w;
        bx+=x1.x; by+=x1.y; bz+=x1.z; bw+=x1.w;
      }
      u16x8 v;
      v[0]=f2bf(ax*inv); v[1]=f2bf(ay*inv); v[2]=f2bf(az*inv); v[3]=f2bf(aw*inv);
      v[4]=f2bf(bx*inv); v[5]=f2bf(by*inv); v[6]=f2bf(bz*inv); v[7]=f2bf(bw*inv);
      *(u16x8*)&lA[r][hh*32 + c2*8] = v;
    }
  } else {
    int r = tid >> 2, kq = (tid & 3) * (KFULL/4);
    const float* src = A + (size_t)(m0 + r)*KFULL + kq;
    #pragma unroll
    for (int c = 0; c < KFULL/32; ++c) {
      float4 va = ((const float4*)src)[c*2], vb = ((const float4*)src)[c*2+1];
      u16x8 v;
      v[0]=f2bf(va.x); v[1]=f2bf(va.y); v[2]=f2bf(va.z); v[3]=f2bf(va.w);
      v[4]=f2bf(vb.x); v[5]=f2bf(vb.y); v[6]=f2bf(vb.z); v[7]=f2bf(vb.w);
      *(u16x8*)&lA[r][kq + c*8] = v;
    }
  }

  float bv[8], gm[8], bt[8];
  #pragma unroll
  for (int nf = 0; nf < 8; ++nf) {
    bv[nf] = bias[nf*16 + ln_];
    gm[nf] = gam[nf*16 + ln_];
    bt[nf] = bet[nf*16 + ln_];
  }
  f32x4 acc[8];
  #pragma unroll
  for (int nf = 0; nf < 8; ++nf) acc[nf] = f32x4{bv[nf], bv[nf], bv[nf], bv[nf]};

  for (int kb = 0; kb < KFULL; kb += 64) {
    __syncthreads();
    { // stage lB: 128 output cols x 64 k
      int r = tid >> 1, kq = (tid & 1) * 32;
      const unsigned short* src = Bt + (size_t)r*KFULL + kb + kq;
      #pragma unroll
      for (int c = 0; c < 4; ++c)
        *(u16x8*)&lB[r][kq + c*8] = *(const u16x8*)&src[c*8];
    }
    __syncthreads();
    #pragma unroll
    for (int ks = 0; ks < 2; ++ks) {
      s16x8 af = *(const s16x8*)&lA[w*16 + ln_][kb + ks*32 + g*8];
      s16x8 bf_[8];
      #pragma unroll
      for (int nf = 0; nf < 8; ++nf)
        bf_[nf] = *(const s16x8*)&lB[nf*16 + ln_][ks*32 + g*8];
      #pragma unroll
      for (int nf = 0; nf < 8; ++nf)
        acc[nf] = MFMA16(af, bf_[nf], acc[nf]);
    }
  }

  // ---- epilogue: + res, row LayerNorm, write ----
  #pragma unroll
  for (int j = 0; j < 4; ++j) {
    int row = m0 + w*16 + g*4 + j;
    float sm = 0.f;
    #pragma unroll
    for (int nf = 0; nf < 8; ++nf) {
      acc[nf][j] += res[(size_t)row*128 + nf*16 + ln_];
      sm += acc[nf][j];
    }
    sm += __shfl_xor(sm, 1); sm += __shfl_xor(sm, 2);
    sm += __shfl_xor(sm, 4); sm += __shfl_xor(sm, 8);
    float mu = sm * 0.0078125f;
    float qv = 0.f;
    #pragma unroll
    for (int nf = 0; nf < 8; ++nf) {
      float d = acc[nf][j] - mu;
      qv += d*d;
    }
    qv += __shfl_xor(qv, 1); qv += __shfl_xor(qv, 2);
    qv += __shfl_xor(qv, 4); qv += __shfl_xor(qv, 8);
    float rr = rsqrtf(qv * 0.0078125f + 1e-5f);
    #pragma unroll
    for (int nf = 0; nf < 8; ++nf)
      out[(size_t)row*128 + nf*16 + ln_] = (acc[nf][j] - mu) * rr * gm[nf] + bt[nf];
  }
}

// ------------------------- flash attention (swapped-QK, no-max, KV-split 8) -
__global__ __launch_bounds__(256) void attn_k(
    const unsigned short* __restrict__ qkvb,
    float* __restrict__ po, float* __restrict__ pl) {
  __shared__ unsigned short lK[128][40];
  __shared__ unsigned short lV[32][136];
  const int tid = threadIdx.x, lane = tid & 63, w = tid >> 6;
  const int hh = blockIdx.y, sp = blockIdx.z;
  const int qr = blockIdx.x * 64 + w * 16;
  const int g = lane >> 4, q = lane & 15;

  s16x8 qf = *(const s16x8*)&qkvb[(size_t)(qr + q)*384 + hh*32 + g*8];

  f32x4 o[2];
  o[0] = f32x4{0.f,0.f,0.f,0.f}; o[1] = f32x4{0.f,0.f,0.f,0.f};
  float lrun = 0.f;

  const int srcA = q | ((2*(g & 1)) << 4);
  const int srcB = srcA + 16;
  const bool hi = (g >> 1) != 0;

  for (int kt = sp*4; kt < sp*4 + 4; ++kt) {
    const int k0 = kt * 128;
    __syncthreads();
    {
      int key = tid >> 1, d0 = (tid & 1) * 16;
      const unsigned short* src = qkvb + (size_t)(k0 + key)*384 + 128 + hh*32 + d0;
      *(u16x8*)&lK[key][d0]     = *(const u16x8*)&src[0];
      *(u16x8*)&lK[key][d0 + 8] = *(const u16x8*)&src[8];
    }
    {
      int kp = tid & 63, gg = tid >> 6;
      const unsigned short* s0 = qkvb + (size_t)(k0 + 2*kp)*384 + 256 + hh*32 + gg*8;
      u16x8 e0 = *(const u16x8*)s0;
      u16x8 e1 = *(const u16x8*)(s0 + 384);
      #pragma unroll
      for (int d = 0; d < 8; ++d) {
        unsigned int pkk = (unsigned int)e0[d] | ((unsigned int)e1[d] << 16);
        *(unsigned int*)&lV[gg*8 + d][2*kp] = pkk;
      }
    }
    __syncthreads();

    unsigned int pk[8][2];
    float ps = 0.f;
    #pragma unroll
    for (int nf = 0; nf < 8; ++nf) {
      s16x8 kf = *(const s16x8*)&lK[nf*16 + q][g*8];
      f32x4 c = MFMA16(kf, qf, (f32x4{0.f,0.f,0.f,0.f}));
      float p0 = exp2f(c[0]), p1 = exp2f(c[1]);
      float p2 = exp2f(c[2]), p3 = exp2f(c[3]);
      ps += (p0 + p1) + (p2 + p3);
      unsigned int u0 = __builtin_bit_cast(unsigned int, p0) + 0x8000u;
      unsigned int u1 = __builtin_bit_cast(unsigned int, p1) + 0x8000u;
      unsigned int u2 = __builtin_bit_cast(unsigned int, p2) + 0x8000u;
      unsigned int u3 = __builtin_bit_cast(unsigned int, p3) + 0x8000u;
      pk[nf][0] = (u0 >> 16) | (u1 & 0xffff0000u);
      pk[nf][1] = (u2 >> 16) | (u3 & 0xffff0000u);
    }
    ps += __shfl_xor(ps, 16);
    ps += __shfl_xor(ps, 32);
    lrun += ps;

    #pragma unroll
    for (int kc = 0; kc < 4; ++kc) {
      unsigned int a0 = (unsigned int)__shfl((int)pk[2*kc][0],   srcA);
      unsigned int b0 = (unsigned int)__shfl((int)pk[2*kc+1][0], srcA);
      unsigned int a1 = (unsigned int)__shfl((int)pk[2*kc][1],   srcA);
      unsigned int b1 = (unsigned int)__shfl((int)pk[2*kc+1][1], srcA);
      unsigned int a2 = (unsigned int)__shfl((int)pk[2*kc][0],   srcB);
      unsigned int b2 = (unsigned int)__shfl((int)pk[2*kc+1][0], srcB);
      unsigned int a3 = (unsigned int)__shfl((int)pk[2*kc][1],   srcB);
      unsigned int b3 = (unsigned int)__shfl((int)pk[2*kc+1][1], srcB);
      u32x4 wv;
      wv[0] = hi ? b0 : a0; wv[1] = hi ? b1 : a1;
      wv[2] = hi ? b2 : a2; wv[3] = hi ? b3 : a3;
      s16x8 pa = __builtin_bit_cast(s16x8, wv);
      #pragma unroll
      for (int df = 0; df < 2; ++df) {
        s16x8 vf = *(const s16x8*)&lV[df*16 + q][kc*32 + g*8];
        o[df] = MFMA16(pa, vf, o[df]);
      }
    }
  }
  #pragma unroll
  for (int df = 0; df < 2; ++df)
    #pragma unroll
    for (int j = 0; j < 4; ++j) {
      int row = qr + g*4 + j;
      po[((size_t)sp*4096 + row)*128 + hh*32 + df*16 + q] = o[df][j];
    }
  if (lane < 16)
    pl[((sp*4 + hh) << 12) + qr + lane] = lrun;
}

// ------------------------- launch -------------------------
extern "C" void kernel_launch(void* const* d_in, const int* in_sizes, int n_in,
                              void* d_out, int out_size, void* d_ws, size_t ws_size,
                              hipStream_t stream) {
  const float* x    = (const float*)d_in[0];
  const float* pos  = (const float*)d_in[1];
  const int*   idx  = (const int*)d_in[2];
  const float* W1   = (const float*)d_in[4];
  const float* b1   = (const float*)d_in[5];
  const float* W2   = (const float*)d_in[6];
  const float* b2   = (const float*)d_in[7];
  const float* Wr   = (const float*)d_in[8];
  const float* br   = (const float*)d_in[9];
  const float* ipw  = (const float*)d_in[10];
  const float* ipb  = (const float*)d_in[11];
  const float* opw  = (const float*)d_in[12];
  const float* opb  = (const float*)d_in[13];
  const float* Wm1  = (const float*)d_in[14];
  const float* bm1  = (const float*)d_in[15];
  const float* Wm2  = (const float*)d_in[16];
  const float* bm2  = (const float*)d_in[17];
  const float* g1   = (const float*)d_in[18];
  const float* be1  = (const float*)d_in[19];
  const float* g2   = (const float*)d_in[20];
  const float* be2  = (const float*)d_in[21];
  float* out = (float*)d_out;
  char* ws = (char*)d_ws;

  float4*         pos4  = (float4*)(ws + OFF_POS4);
  int*            colp  = (int*)(ws + OFF_COL);
  unsigned short* w1t   = (unsigned short*)(ws + OFF_W1T);
  unsigned short* w2t   = (unsigned short*)(ws + OFF_W2T);
  unsigned short* wrt   = (unsigned short*)(ws + OFF_WRT);
  unsigned short* wqkvt = (unsigned short*)(ws + OFF_WQKVT);
  unsigned short* woutt = (unsigned short*)(ws + OFF_WOUTT);
  unsigned short* wm1t  = (unsigned short*)(ws + OFF_WM1T);
  unsigned short* wm2t  = (unsigned short*)(ws + OFF_WM2T);
  float4* sposp = (float4*)(ws + OFF_SPOS);
  int*    ccnt  = (int*)(ws + OFF_CELLCNT);
  int2*   cdesc = (int2*)(ws + OFF_CELLDSC);
  int*    cfill = (int*)(ws + OFF_FILL);
  float*  pop   = (float*)(ws + OFF_PO);
  float*  plp   = (float*)(ws + OFF_PL);
  float* aggp  = (float*)(ws + OFF_AGG);
  float* xt0p  = (float*)(ws + OFF_XT0);
  unsigned short* qkvb = (unsigned short*)(ws + OFF_QKV);
  float* xt1p  = (float*)(ws + OFF_XT1);
  float* mlp1p = (float*)(ws + OFF_MLP1);
  float* sbias = (float*)(ws + OFF_SBIAS);

  zero_k<<<128, 256, 0, stream>>>(ccnt);
  prep_k<<<946, 256, 0, stream>>>(pos, W1, W2, Wr, ipw, ipb, opw, Wm1, Wm2,
                                  pos4, w1t, w2t, wrt, wqkvt, woutt, wm1t, wm2t,
                                  ccnt, sbias);
  prefix_k<<<1, 1024, 0, stream>>>(ccnt, cdesc, cfill);
  scatter_k<<<128, 256, 0, stream>>>(pos4, cfill, sposp);
  knn_k<<<1024, 256, 0, stream>>>(sposp, cdesc, pos4, idx, colp,
                                  out + 524288, out + 536576);
  conv_k<<<1024, 256, 0, stream>>>(x, pos4, idx, colp, w1t, b1, w2t, b2, aggp);
  gemm_k<256, 128, false, false, false><<<dim3(64, 2), 256, 0, stream>>>(aggp, wrt, br, nullptr, xt0p);
  gemm_k<128, 384, false, false, true><<<dim3(64, 6), 256, 0, stream>>>(xt0p, wqkvt, sbias, nullptr, (float*)qkvb);
  attn_k<<<dim3(64, 4, 8), 256, 0, stream>>>(qkvb, pop, plp);
  gemmln_k<128, true><<<64, 256, 0, stream>>>(nullptr, pop, plp, woutt, opb, xt0p, g1, be1, xt1p);
  gemm_k<128, 256, true, false, false><<<dim3(64, 4), 256, 0, stream>>>(xt1p, wm1t, bm1, nullptr, mlp1p);
  gemmln_k<256, false><<<64, 256, 0, stream>>>(mlp1p, nullptr, nullptr, wm2t, bm2, xt1p, g2, be2, out);
}

// Round 13
// 158.123 us; speedup vs baseline: 1.0630x; 1.0630x over previous
//
#include <hip/hip_runtime.h>
#include <hip/hip_bf16.h>

#define DEV static __device__ __forceinline__

typedef __attribute__((ext_vector_type(8))) short          s16x8;
typedef __attribute__((ext_vector_type(8))) unsigned short u16x8;
typedef __attribute__((ext_vector_type(4))) float          f32x4;
typedef __attribute__((ext_vector_type(4))) unsigned int   u32x4;

#define MFMA16(A,B,C) __builtin_amdgcn_mfma_f32_16x16x32_bf16((A),(B),(C),0,0,0)

DEV unsigned short f2bf(float f) {
  unsigned int u = __builtin_bit_cast(unsigned int, f);
  u += 0x7fffu + ((u >> 16) & 1u);
  return (unsigned short)(u >> 16);
}

// 1/sqrt(32) * log2(e): fold into Q projection so softmax uses exp2 directly
#define QSCL 0.25503562201f

// ------------------------- grid params -------------------------
#define GRID_LO  (-5.0f)
#define GRID_IH  (3.2f)        // 1/h, h = 0.3125, 32 cells over [-5,5]

DEV int cellc(float v) {
  int c = (int)floorf((v - GRID_LO) * GRID_IH);
  return min(31, max(0, c));
}

// ------------------------- ws layout -------------------------
constexpr size_t OFF_POS4  = 0;                       // 32768*16      = 524288
constexpr size_t OFF_COL   = 524288;                  // 4096*32*4     = 524288
constexpr size_t OFF_W1T   = 1048576;                 // 128*96*2
constexpr size_t OFF_W2T   = OFF_W1T  + 24576;
constexpr size_t OFF_WRT   = OFF_W2T  + 65536;
constexpr size_t OFF_WQKVT = OFF_WRT  + 65536;
constexpr size_t OFF_WOUTT = OFF_WQKVT+ 98304;
constexpr size_t OFF_WM1T  = OFF_WOUTT+ 32768;
constexpr size_t OFF_WM2T  = OFF_WM1T + 65536;
constexpr size_t OFF_H     = OFF_WM2T + 65536;        // 33554432 bytes (shared region)
// phase 1 (pre-conv): cell structures live in the H region
constexpr size_t OFF_SPOS    = OFF_H;                 // 32768*16 = 524288
constexpr size_t OFF_CELLCNT = OFF_H + 524288;        // 131072
constexpr size_t OFF_CELLDSC = OFF_H + 655360;        // 262144
constexpr size_t OFF_FILL    = OFF_H + 917504;        // 131072
// phase 2 (post-conv): attention partials live in the H region
constexpr size_t OFF_PO      = OFF_H;                 // 8*4096*128*4 = 16777216
constexpr size_t OFF_PL      = OFF_H + 16777216;      // 8*4*4096*4  = 524288
constexpr size_t OFF_AGG   = OFF_H    + 33554432;
constexpr size_t OFF_XT0   = OFF_AGG  + 4194304;
constexpr size_t OFF_QKV   = OFF_XT0  + 2097152;      // bf16 qkv
constexpr size_t OFF_ATT   = OFF_QKV  + 6291456;      // (unused)
constexpr size_t OFF_PRE   = OFF_ATT  + 2097152;      // (unused)
constexpr size_t OFF_XT1   = OFF_PRE  + 2097152;
constexpr size_t OFF_MLP1  = OFF_XT1  + 2097152;
constexpr size_t OFF_SBIAS = OFF_MLP1 + 4194304;      // 384*4 = 1536

// ------------------------- zero cell counts -------------------------
__global__ __launch_bounds__(256) void zero_k(int* __restrict__ p) {
  p[blockIdx.x * 256 + threadIdx.x] = 0;
}

// ------------------------- prep -------------------------
__global__ __launch_bounds__(256) void prep_k(
    const float* __restrict__ pos, const float* __restrict__ W1,
    const float* __restrict__ W2, const float* __restrict__ Wr,
    const float* __restrict__ ipw, const float* __restrict__ ipb,
    const float* __restrict__ opw,
    const float* __restrict__ Wm1, const float* __restrict__ Wm2,
    float4* __restrict__ pos4, unsigned short* __restrict__ w1t,
    unsigned short* __restrict__ w2t, unsigned short* __restrict__ wrt,
    unsigned short* __restrict__ wqkvt, unsigned short* __restrict__ woutt,
    unsigned short* __restrict__ wm1t, unsigned short* __restrict__ wm2t,
    int* __restrict__ cellcnt, float* __restrict__ sbias) {
  int T = blockIdx.x * 256 + threadIdx.x;
  if (T < 32768) {
    float px = pos[T*3], py = pos[T*3+1], pz = pos[T*3+2];
    pos4[T] = make_float4(px, py, pz, 0.f);
    int cid = (cellc(pz)*32 + cellc(py))*32 + cellc(px);
    atomicAdd(&cellcnt[cid], 1);
    return;
  }
  T -= 32768;
  if (T < 128*96)  { int n=T/96,  k=T%96;  w1t[T]  = f2bf(k < 67 ? W1[k*128+n] : 0.f); return; }
  T -= 128*96;
  if (T < 256*128) { int n=T/128, k=T%128; w2t[T]  = f2bf(W2[k*256+n]);  return; }
  T -= 256*128;
  if (T < 128*256) { int n=T/256, k=T%256; wrt[T]  = f2bf(Wr[k*128+n]);  return; }
  T -= 128*256;
  if (T < 384*128) { int n=T/128, k=T%128;
                     float v = ipw[k*384+n];
                     if (n < 128) v *= QSCL;
                     wqkvt[T]= f2bf(v); return; }
  T -= 384*128;
  if (T < 128*128) { int n=T/128, k=T%128; woutt[T]= f2bf(opw[k*128+n]); return; }
  T -= 128*128;
  if (T < 256*128) { int n=T/128, k=T%128; wm1t[T] = f2bf(Wm1[k*256+n]); return; }
  T -= 256*128;
  if (T < 128*256) { int n=T/256, k=T%256; wm2t[T] = f2bf(Wm2[k*128+n]); return; }
  T -= 128*256;
  if (T < 384) { sbias[T] = ipb[T] * (T < 128 ? QSCL : 1.f); return; }
}

// ------------------------- prefix over 32768 cell counts -------------------
__global__ __launch_bounds__(1024) void prefix_k(const int* __restrict__ cnt,
                                                 int2* __restrict__ desc,
                                                 int* __restrict__ fill) {
  __shared__ int wsum[16];
  const int tid = threadIdx.x, lane = tid & 63, w = tid >> 6;
  int loc[32]; int s = 0;
  #pragma unroll
  for (int i = 0; i < 32; ++i) { loc[i] = cnt[tid*32 + i]; s += loc[i]; }
  int sc = s;
  #pragma unroll
  for (int off = 1; off < 64; off <<= 1) {
    int v = __shfl_up(sc, off);
    if (lane >= off) sc += v;
  }
  if (lane == 63) wsum[w] = sc;
  __syncthreads();
  if (tid == 0) {
    int run = 0;
    #pragma unroll
    for (int i = 0; i < 16; ++i) { int v = wsum[i]; wsum[i] = run; run += v; }
  }
  __syncthreads();
  int base = wsum[w] + (sc - s);
  #pragma unroll
  for (int i = 0; i < 32; ++i) {
    int c = tid*32 + i;
    desc[c] = make_int2(base, loc[i]);
    fill[c] = base;
    base += loc[i];
  }
}

// ------------------------- scatter -------------------------
__global__ __launch_bounds__(256) void scatter_k(const float4* __restrict__ pos4,
                                                 int* __restrict__ fill,
                                                 float4* __restrict__ spos) {
  int T = blockIdx.x * 256 + threadIdx.x;
  float4 p = pos4[T];
  int cid = (cellc(p.z)*32 + cellc(p.y))*32 + cellc(p.x);
  int slot = atomicAdd(&fill[cid], 1);
  spos[slot] = make_float4(p.x, p.y, p.z, __int_as_float(T));
}

// ------------------------- KNN -------------------------
#define KNN_CAP  320
#define KNN_TRIG 192
#define KNN_KEEP 33
#define KNN_INF  3e37f

__global__ __launch_bounds__(256) void knn_k(
    const float4* __restrict__ spos, const int2* __restrict__ desc,
    const float4* __restrict__ pos4, const int* __restrict__ idx,
    int* __restrict__ col,
    float* __restrict__ outqpos, float* __restrict__ outbatch) {
  __shared__ float bufd[4][KNN_CAP];
  __shared__ int   bufi[4][KNN_CAP];
  __shared__ int   shist[4][64];
  __shared__ int2  segs[4][128];
  const int tid = threadIdx.x, lane = tid & 63, w = tid >> 6;
  const unsigned long long ltmask = (1ull << lane) - 1ull;

  const int q = blockIdx.x * 4 + w;
  const int iq = idx[q];
  const float4 qp = pos4[iq];
  const float qx = qp.x, qy = qp.y, qz = qp.z;
  const int cx0 = cellc(qx), cy0 = cellc(qy), cz0 = cellc(qz);

  float t = KNN_INF;
  int cnt = 0;

  auto compact = [&]() {
    int c_ = min(cnt, KNN_CAP);
    float vd[5]; int vi[5], bs[5]; bool okv[5];
    float dmax = 1e-30f;
    #pragma unroll
    for (int s = 0; s < 5; ++s) {
      int o2 = s*64 + lane;
      okv[s] = o2 < c_;
      vd[s] = okv[s] ? bufd[w][o2] : 0.f;
      vi[s] = okv[s] ? bufi[w][o2] : 0;
      dmax = fmaxf(dmax, vd[s]);
    }
    #pragma unroll
    for (int off = 1; off < 64; off <<= 1) dmax = fmaxf(dmax, __shfl_xor(dmax, off));
    float scale = 63.99f / dmax;
    shist[w][lane] = 0;
    #pragma unroll
    for (int s = 0; s < 5; ++s) {
      bs[s] = okv[s] ? min(63, (int)(vd[s] * scale)) : 64;
      if (okv[s]) atomicAdd(&shist[w][bs[s]], 1);
    }
    int h = shist[w][lane];
    #pragma unroll
    for (int off = 1; off < 64; off <<= 1) {
      int v = __shfl_up(h, off);
      if (lane >= off) h += v;
    }
    unsigned long long mk = __ballot(h >= KNN_KEEP);
    int E = mk ? (__ffsll((long long)mk) - 1) : 63;
    int base = 0;
    #pragma unroll
    for (int s = 0; s < 5; ++s) {
      bool keep = okv[s] && bs[s] <= E;
      unsigned long long km = __ballot(keep);
      int pp = base + (int)__popcll(km & ltmask);
      if (keep) { bufd[w][pp] = vd[s]; bufi[w][pp] = vi[s]; }
      base += (int)__popcll(km);
    }
    cnt = base;
    t = fminf(t, (float)(E + 1) / scale);
  };

  auto scan_rows = [&](int knew, int kold) {
    const int S = 2*knew + 1;
    const int NR = S*S;
    const float invS = 1.f / (float)S;
    for (int r0 = 0; r0 < NR; r0 += 64) {
      int r = r0 + lane;
      bool v = r < NR;
      int dz = (int)((float)r * invS);
      int rem = r - dz*S;
      if (rem < 0) { dz--; rem += S; } else if (rem >= S) { dz++; rem -= S; }
      int ccz = cz0 + dz - knew, ccy = cy0 + rem - knew;
      bool rowok = v && ccz >= 0 && ccz < 32 && ccy >= 0 && ccy < 32;
      bool inner = kold >= 0 && abs(dz - knew) <= kold && abs(rem - knew) <= kold;
      int cbase = (ccz*32 + ccy) * 32;
      int sL = 0, lL = 0, sR = 0, lR = 0;
      if (rowok) {
        int xa = max(cx0 - knew, 0);
        int xb = inner ? (cx0 - kold - 1) : min(cx0 + knew, 31);
        if (xa <= xb) {
          int2 d0 = desc[cbase + xa];
          int2 d1 = desc[cbase + xb];
          sL = d0.x; lL = d1.x + d1.y - d0.x;
        }
        if (inner) {
          int xa2 = cx0 + kold + 1, xb2 = min(cx0 + knew, 31);
          if (xa2 <= xb2 && xa2 >= 0) {
            int2 d0 = desc[cbase + xa2];
            int2 d1 = desc[cbase + xb2];
            sR = d0.x; lR = d1.x + d1.y - d0.x;
          }
        }
      }
      int cumL = lL;
      #pragma unroll
      for (int off = 1; off < 64; off <<= 1) {
        int vv = __shfl_up(cumL, off);
        if (lane >= off) cumL += vv;
      }
      int sumL = __shfl(cumL, 63);
      int cumR = lR;
      #pragma unroll
      for (int off = 1; off < 64; off <<= 1) {
        int vv = __shfl_up(cumR, off);
        if (lane >= off) cumR += vv;
      }
      int sumR = __shfl(cumR, 63);
      segs[w][lane]      = make_int2(sL, cumL - lL);
      segs[w][64 + lane] = make_int2(sR, sumL + cumR - lR);
      const int total = sumL + sumR;

      for (int b = 0; b < total; b += 320) {
        float d2v[5]; int piv[5]; bool hv[5];
        #pragma unroll
        for (int s5 = 0; s5 < 5; ++s5) {
          int p = b + s5*64 + lane;
          bool act = p < total;
          hv[s5] = false; d2v[s5] = 0.f; piv[s5] = 0;
          if (act) {
            int lo = 0;
            #pragma unroll
            for (int st = 64; st > 0; st >>= 1)
              if (segs[w][lo + st].y <= p) lo += st;
            int2 e = segs[w][lo];
            float4 pt = spos[e.x + (p - e.y)];
            float ddx = qx-pt.x, ddy = qy-pt.y, ddz = qz-pt.z;
            float d2 = ddx*ddx + ddy*ddy + ddz*ddz;
            d2v[s5] = d2; piv[s5] = __float_as_int(pt.w);
            hv[s5] = d2 < t;
          }
        }
        #pragma unroll
        for (int s5 = 0; s5 < 5; ++s5) {
          unsigned long long hm = __ballot(hv[s5]);
          if (hm) {
            int pp = cnt + (int)__popcll(hm & ltmask);
            if (hv[s5] && pp < KNN_CAP) { bufd[w][pp] = d2v[s5]; bufi[w][pp] = piv[s5]; }
            cnt += (int)__popcll(hm);
            if (cnt >= KNN_TRIG) compact();
          }
        }
      }
    }
  };

  auto bound32 = [&]() -> float {
    int c_ = min(cnt, KNN_CAP);
    float vv[5]; bool okv[5];
    float dmax = 1e-30f;
    #pragma unroll
    for (int s = 0; s < 5; ++s) {
      int o2 = s*64 + lane;
      okv[s] = o2 < c_;
      vv[s] = okv[s] ? bufd[w][o2] : 0.f;
      dmax = fmaxf(dmax, vv[s]);
    }
    #pragma unroll
    for (int off = 1; off < 64; off <<= 1) dmax = fmaxf(dmax, __shfl_xor(dmax, off));
    float scale = 63.99f / dmax;
    shist[w][lane] = 0;
    #pragma unroll
    for (int s = 0; s < 5; ++s)
      if (okv[s]) atomicAdd(&shist[w][min(63, (int)(vv[s] * scale))], 1);
    int h = shist[w][lane];
    #pragma unroll
    for (int off = 1; off < 64; off <<= 1) {
      int v = __shfl_up(h, off);
      if (lane >= off) h += v;
    }
    unsigned long long m = __ballot(h >= 32);
    int E = m ? (__ffsll((long long)m) - 1) : 63;
    return (float)(E + 1) / scale;
  };

  int kcur = 1;
  scan_rows(1, -1);
  for (int it = 0; it < 64; ++it) {
    if (cnt >= 32) {
      float t32u = bound32();
      t = fminf(t, t32u);
      int kneed = (int)(__builtin_sqrtf(t32u) * GRID_IH) + 1;
      if (kneed <= kcur || kcur >= 31) break;
      int knew = min(kneed, 31);
      scan_rows(knew, kcur);
      kcur = knew;
    } else {
      if (kcur >= 31) break;
      int knew = min(kcur + (cnt == 0 ? 2 : 1), 31);
      scan_rows(knew, kcur);
      kcur = knew;
    }
  }

  // ---- final exact top-32 ----
  {
    int c_ = min(cnt, KNN_CAP);
    float vd[5]; int vi[5], bs[5]; bool okf[5];
    float dmax = 1e-30f;
    #pragma unroll
    for (int s = 0; s < 5; ++s) {
      int o2 = s*64 + lane;
      okf[s] = o2 < c_;
      vd[s] = okf[s] ? bufd[w][o2] : KNN_INF;
      vi[s] = okf[s] ? bufi[w][o2] : 0;
      dmax = fmaxf(dmax, okf[s] ? vd[s] : 0.f);
    }
    #pragma unroll
    for (int off = 1; off < 64; off <<= 1) dmax = fmaxf(dmax, __shfl_xor(dmax, off));
    float sc64 = 63.99f / dmax;
    shist[w][lane] = 0;
    #pragma unroll
    for (int s = 0; s < 5; ++s) {
      bs[s] = okf[s] ? min(63, (int)(vd[s] * sc64)) : 64;
      if (okf[s]) atomicAdd(&shist[w][bs[s]], 1);
    }
    int h = shist[w][lane];
    #pragma unroll
    for (int off = 1; off < 64; off <<= 1) {
      int v = __shfl_up(h, off);
      if (lane >= off) h += v;
    }
    unsigned long long m = __ballot(h >= 32);
    int E = m ? (__ffsll((long long)m) - 1) : 63;
    int c0 = (E > 0) ? __shfl(h, E - 1) : 0;
    int base = 0;
    #pragma unroll
    for (int s = 0; s < 5; ++s) {
      bool wr = okf[s] && (bs[s] < E);
      unsigned long long km = __ballot(wr);
      int pp = base + (int)__popcll(km & ltmask);
      if (wr) col[q*32 + pp] = vi[s];
      base += (int)__popcll(km);
    }
    #pragma unroll
    for (int s = 0; s < 5; ++s)
      if (!(okf[s] && bs[s] == E)) vd[s] = KNN_INF;
    int r = 32 - c0;
    #pragma unroll 1
    for (int kk = 0; kk < r; ++kk) {
      float bd = vd[0]; int bi = vi[0]; int bc = lane*8;
      #pragma unroll
      for (int s = 1; s < 5; ++s)
        if (vd[s] < bd) { bd = vd[s]; bi = vi[s]; bc = lane*8 + s; }
      #pragma unroll
      for (int off = 1; off < 64; off <<= 1) {
        float od = __shfl_xor(bd, off);
        int   oi = __shfl_xor(bi, off);
        int   oc = __shfl_xor(bc, off);
        if (od < bd || (od == bd && oc < bc)) { bd = od; bi = oi; bc = oc; }
      }
      if ((bc >> 3) == lane) {
        int sl = bc & 7;
        #pragma unroll
        for (int s = 0; s < 5; ++s) if (sl == s) vd[s] = KNN_INF;
      }
      if (lane == 0) col[q*32 + c0 + kk] = bi;
    }
  }
  if (lane == 0) {
    outqpos[q*3+0] = qx; outqpos[q*3+1] = qy; outqpos[q*3+2] = qz;
    outbatch[q] = 0.f;
  }
}

// ------------------------- fused conv -------------------------
#define LA1(r,c) S[(r)*104 + (c)]
#define LB1(r,c) S[13312 + (r)*104 + (c)]
#define HB(r,c)  S[(r)*136 + (c)]
#define W2C(r,c) S[17408 + (r)*136 + (c)]

__global__ __launch_bounds__(256) void conv_k(
    const float* __restrict__ x, const float4* __restrict__ pos4,
    const int* __restrict__ idx, const int* __restrict__ col,
    const unsigned short* __restrict__ w1t, const float* __restrict__ b1,
    const unsigned short* __restrict__ w2t, const float* __restrict__ b2,
    float* __restrict__ agg) {
  __shared__ __align__(16) unsigned short S[26624];
  __shared__ int   sci[128];
  __shared__ float sqp[4][3];
  const int tid = threadIdx.x, lane = tid & 63, w = tid >> 6;
  const int wm = w >> 1, wn = w & 1;
  const int m0 = blockIdx.x * 4;

  if (tid < 128) sci[tid] = col[m0*32 + tid];
  if (tid >= 128 && tid < 132) {
    int m = m0 + tid - 128;
    float4 p = pos4[idx[m]];
    sqp[tid-128][0] = p.x; sqp[tid-128][1] = p.y; sqp[tid-128][2] = p.z;
  }
  #pragma unroll
  for (int rnd = 0; rnd < 6; ++rnd) {
    int e = (rnd*256 + tid) * 8;
    int n = e / 96, k = e % 96;
    *(u16x8*)&LB1(n, k) = *(const u16x8*)&w1t[e];
  }
  __syncthreads();

  {
    int r = tid >> 1, half = tid & 1;
    int ci = sci[r];
    const float* src = x + (size_t)ci*64 + half*32;
    #pragma unroll
    for (int c = 0; c < 4; ++c) {
      float4 va = ((const float4*)src)[c*2], vb = ((const float4*)src)[c*2+1];
      u16x8 v;
      v[0]=f2bf(va.x); v[1]=f2bf(va.y); v[2]=f2bf(va.z); v[3]=f2bf(va.w);
      v[4]=f2bf(vb.x); v[5]=f2bf(vb.y); v[6]=f2bf(vb.z); v[7]=f2bf(vb.w);
      *(u16x8*)&LA1(r, half*32 + c*8) = v;
    }
  }
  if (tid < 128) {
    int r = tid, g = r >> 5;
    float4 p = pos4[sci[r]];
    u16x8 z;
    #pragma unroll
    for (int e = 0; e < 8; ++e) z[e] = 0;
    u16x8 v0 = z;
    v0[0] = f2bf(p.x - sqp[g][0]); v0[1] = f2bf(p.y - sqp[g][1]); v0[2] = f2bf(p.z - sqp[g][2]);
    *(u16x8*)&LA1(r, 64) = v0;
    #pragma unroll
    for (int c = 1; c < 5; ++c) *(u16x8*)&LA1(r, 64 + c*8) = z;
  }
  __syncthreads();

  f32x4 acc[4][4];
  #pragma unroll
  for (int nf = 0; nf < 4; ++nf) {
    float bv = b1[wn*64 + nf*16 + (lane & 15)];
    #pragma unroll
    for (int mf = 0; mf < 4; ++mf) acc[mf][nf] = f32x4{bv, bv, bv, bv};
  }
  #pragma unroll
  for (int kc = 0; kc < 3; ++kc) {
    s16x8 af[4], bf_[4];
    #pragma unroll
    for (int mf = 0; mf < 4; ++mf)
      af[mf] = *(const s16x8*)&LA1(wm*64 + mf*16 + (lane&15), kc*32 + (lane>>4)*8);
    #pragma unroll
    for (int nf = 0; nf < 4; ++nf)
      bf_[nf] = *(const s16x8*)&LB1(wn*64 + nf*16 + (lane&15), kc*32 + (lane>>4)*8);
    #pragma unroll
    for (int mf = 0; mf < 4; ++mf)
      #pragma unroll
      for (int nf = 0; nf < 4; ++nf)
        acc[mf][nf] = MFMA16(af[mf], bf_[nf], acc[mf][nf]);
  }
  __syncthreads();

  #pragma unroll
  for (int mf = 0; mf < 4; ++mf)
    #pragma unroll
    for (int nf = 0; nf < 4; ++nf)
      #pragma unroll
      for (int j = 0; j < 4; ++j) {
        int rloc = wm*64 + mf*16 + ((lane>>4)<<2) + j;
        int cloc = wn*64 + nf*16 + (lane & 15);
        HB(rloc, cloc) = f2bf(fmaxf(acc[mf][nf][j], 0.f));
      }
  {
    int r2 = tid >> 2, kq = (tid & 3) * 32;
    const unsigned short* src = w2t + (size_t)r2*128 + kq;
    #pragma unroll
    for (int c = 0; c < 4; ++c)
      *(u16x8*)&W2C(r2, kq + c*8) = *(const u16x8*)&src[c*8];
  }
  __syncthreads();

  #pragma unroll 1
  for (int nc = 0; nc < 4; ++nc) {
    f32x4 acc2[2][4];
    #pragma unroll
    for (int nf = 0; nf < 4; ++nf) {
      float bv = b2[nc*64 + nf*16 + (lane & 15)];
      acc2[0][nf] = f32x4{bv, bv, bv, bv};
      acc2[1][nf] = f32x4{bv, bv, bv, bv};
    }
    #pragma unroll
    for (int ks = 0; ks < 4; ++ks) {
      s16x8 af[2], bf_[4];
      #pragma unroll
      for (int mf = 0; mf < 2; ++mf)
        af[mf] = *(const s16x8*)&HB(w*32 + mf*16 + (lane&15), ks*32 + (lane>>4)*8);
      #pragma unroll
      for (int nf = 0; nf < 4; ++nf)
        bf_[nf] = *(const s16x8*)&W2C(nf*16 + (lane&15), ks*32 + (lane>>4)*8);
      #pragma unroll
      for (int mf = 0; mf < 2; ++mf)
        #pragma unroll
        for (int nf = 0; nf < 4; ++nf)
          acc2[mf][nf] = MFMA16(af[mf], bf_[nf], acc2[mf][nf]);
    }
    #pragma unroll
    for (int nf = 0; nf < 4; ++nf) {
      float mx = acc2[0][nf][0];
      #pragma unroll
      for (int j = 1; j < 4; ++j) mx = fmaxf(mx, acc2[0][nf][j]);
      #pragma unroll
      for (int j = 0; j < 4; ++j) mx = fmaxf(mx, acc2[1][nf][j]);
      mx = fmaxf(mx, __shfl_xor(mx, 16));
      mx = fmaxf(mx, __shfl_xor(mx, 32));
      if (lane < 16) agg[(size_t)(m0 + w)*256 + nc*64 + nf*16 + lane] = mx;
    }
    if (nc < 3) {
      __syncthreads();
      int r2 = tid >> 2, kq = (tid & 3) * 32;
      const unsigned short* src = w2t + (size_t)((nc+1)*64 + r2)*128 + kq;
      #pragma unroll
      for (int c = 0; c < 4; ++c)
        *(u16x8*)&W2C(r2, kq + c*8) = *(const u16x8*)&src[c*8];
      __syncthreads();
    }
  }
}

// ------------------------- 64x64-tile GEMM -------------------------
template<int KFULL, int NFULL, bool RELU, bool HAS_RES, bool OBF16>
__global__ __launch_bounds__(256) void gemm_k(
    const float* __restrict__ A, const unsigned short* __restrict__ Bt,
    const float* __restrict__ bias, const float* __restrict__ res,
    float* __restrict__ out) {
  __shared__ unsigned short lA[64][72];
  __shared__ unsigned short lB[64][72];
  const int tid = threadIdx.x, lane = tid & 63, w = tid >> 6;
  const int m0 = blockIdx.x * 64, n0 = blockIdx.y * 64;

  f32x4 acc[4];
  #pragma unroll
  for (int nf = 0; nf < 4; ++nf) {
    float bv = bias[n0 + nf*16 + (lane & 15)];
    acc[nf] = f32x4{bv, bv, bv, bv};
  }

  for (int kb = 0; kb < KFULL; kb += 64) {
    __syncthreads();
    {
      int r = tid >> 2, kq = (tid & 3) * 16;
      const float* src = A + (size_t)(m0 + r)*KFULL + kb + kq;
      #pragma unroll
      for (int c = 0; c < 2; ++c) {
        float4 va = ((const float4*)src)[c*2], vb = ((const float4*)src)[c*2+1];
        u16x8 v;
        v[0]=f2bf(va.x); v[1]=f2bf(va.y); v[2]=f2bf(va.z); v[3]=f2bf(va.w);
        v[4]=f2bf(vb.x); v[5]=f2bf(vb.y); v[6]=f2bf(vb.z); v[7]=f2bf(vb.w);
        *(u16x8*)&lA[r][kq + c*8] = v;
      }
      const unsigned short* srcb = Bt + (size_t)(n0 + r)*KFULL + kb + kq;
      #pragma unroll
      for (int c = 0; c < 2; ++c)
        *(u16x8*)&lB[r][kq + c*8] = *(const u16x8*)&srcb[c*8];
    }
    __syncthreads();
    #pragma unroll
    for (int ks = 0; ks < 2; ++ks) {
      s16x8 af = *(const s16x8*)&lA[w*16 + (lane&15)][ks*32 + (lane>>4)*8];
      s16x8 bf_[4];
      #pragma unroll
      for (int nf = 0; nf < 4; ++nf)
        bf_[nf] = *(const s16x8*)&lB[nf*16 + (lane&15)][ks*32 + (lane>>4)*8];
      #pragma unroll
      for (int nf = 0; nf < 4; ++nf)
        acc[nf] = MFMA16(af, bf_[nf], acc[nf]);
    }
  }
  #pragma unroll
  for (int nf = 0; nf < 4; ++nf)
    #pragma unroll
    for (int j = 0; j < 4; ++j) {
      int row = m0 + w*16 + ((lane>>4)<<2) + j;
      int colg = n0 + nf*16 + (lane & 15);
      float v = acc[nf][j];
      if (HAS_RES) v += res[(size_t)row*NFULL + colg];
      if (RELU)    v = fmaxf(v, 0.f);
      if (OBF16) ((unsigned short*)out)[(size_t)row*NFULL + colg] = f2bf(v);
      else       out[(size_t)row*NFULL + colg] = v;
    }
}

// ------------------------- K-split fused GEMM + residual + LayerNorm -------
// 16 rows/block, 256 blocks. Wave w computes K-quarter kw=[w*K/4,(w+1)*K/4);
// partials reduced via padded LDS; 16-thread/row shfl LayerNorm epilogue.
template<int KFULL, bool COMBINE>
__global__ __launch_bounds__(256) void gemmln_k(
    const float* __restrict__ A,
    const float* __restrict__ po, const float* __restrict__ pl,
    const unsigned short* __restrict__ Bt, const float* __restrict__ bias,
    const float* __restrict__ res,
    const float* __restrict__ gam, const float* __restrict__ bet,
    float* __restrict__ out) {
  constexpr int KP = KFULL + 8;
  __shared__ __align__(16) unsigned short lA[16 * KP];
  __shared__ __align__(16) unsigned short lB[128 * KP];
  __shared__ float red[4][16 * 132];
  const int tid = threadIdx.x, lane = tid & 63, w = tid >> 6;
  const int g = lane >> 4, ln_ = lane & 15;
  const int m0 = blockIdx.x * 16;

  // ---- stage A (16 rows x K) ----
  {
    int r = tid >> 4, seg = tid & 15;
    int row = m0 + r;
    if (COMBINE) {
      int hh = seg >> 2;                       // cols seg*8..seg*8+7 -> head seg>>2
      float lsum = 0.f;
      #pragma unroll
      for (int s = 0; s < 8; ++s) lsum += pl[((s*4 + hh) << 12) + row];
      float inv = 1.f / lsum;
      float a0=0,a1=0,a2=0,a3=0,a4=0,a5=0,a6=0,a7=0;
      #pragma unroll
      for (int s = 0; s < 8; ++s) {
        const float4* pb = (const float4*)(po + ((size_t)s*4096 + row)*128 + seg*8);
        float4 x0 = pb[0], x1 = pb[1];
        a0+=x0.x; a1+=x0.y; a2+=x0.z; a3+=x0.w;
        a4+=x1.x; a5+=x1.y; a6+=x1.z; a7+=x1.w;
      }
      u16x8 v;
      v[0]=f2bf(a0*inv); v[1]=f2bf(a1*inv); v[2]=f2bf(a2*inv); v[3]=f2bf(a3*inv);
      v[4]=f2bf(a4*inv); v[5]=f2bf(a5*inv); v[6]=f2bf(a6*inv); v[7]=f2bf(a7*inv);
      *(u16x8*)&lA[r*KP + seg*8] = v;
    } else {
      // thread covers KFULL/16 contiguous cols
      const float* src = A + (size_t)row*KFULL + seg*(KFULL/16);
      #pragma unroll
      for (int c = 0; c < KFULL/128; ++c) {
        float4 va = ((const float4*)src)[c*2], vb = ((const float4*)src)[c*2+1];
        u16x8 v;
        v[0]=f2bf(va.x); v[1]=f2bf(va.y); v[2]=f2bf(va.z); v[3]=f2bf(va.w);
        v[4]=f2bf(vb.x); v[5]=f2bf(vb.y); v[6]=f2bf(vb.z); v[7]=f2bf(vb.w);
        *(u16x8*)&lA[r*KP + seg*(KFULL/16) + c*8] = v;
      }
    }
  }
  // ---- stage B (128 cols x K) ----
  {
    int n = tid >> 1, half = tid & 1;
    int kb = half * (KFULL/2);
    const unsigned short* src = Bt + (size_t)n*KFULL + kb;
    #pragma unroll
    for (int c = 0; c < KFULL/16; ++c)
      *(u16x8*)&lB[n*KP + kb + c*8] = *(const u16x8*)&src[c*8];
  }

  f32x4 acc[8];
  #pragma unroll
  for (int nf = 0; nf < 8; ++nf) {
    float bv = (w == 0) ? bias[nf*16 + ln_] : 0.f;
    acc[nf] = f32x4{bv, bv, bv, bv};
  }
  __syncthreads();

  const int kw = w * (KFULL/4);
  #pragma unroll
  for (int ks = 0; ks < KFULL/128; ++ks) {
    s16x8 af = *(const s16x8*)&lA[ln_*KP + kw + ks*32 + g*8];
    s16x8 bf_[8];
    #pragma unroll
    for (int nf = 0; nf < 8; ++nf)
      bf_[nf] = *(const s16x8*)&lB[(nf*16 + ln_)*KP + kw + ks*32 + g*8];
    #pragma unroll
    for (int nf = 0; nf < 8; ++nf)
      acc[nf] = MFMA16(af, bf_[nf], acc[nf]);
  }

  // ---- write per-wave partials (padded rows: conflict-free) ----
  #pragma unroll
  for (int nf = 0; nf < 8; ++nf)
    #pragma unroll
    for (int j = 0; j < 4; ++j)
      red[w][(g*4 + j)*132 + nf*16 + ln_] = acc[nf][j];
  __syncthreads();

  // ---- epilogue: sum 4 partials + res, row LN, write ----
  {
    int r = tid >> 4, seg = tid & 15;
    int row = m0 + r;
    float v[8]; float sm = 0.f;
    #pragma unroll
    for (int nf = 0; nf < 8; ++nf) {
      int c = nf*16 + seg;
      float xx = red[0][r*132 + c] + red[1][r*132 + c]
               + red[2][r*132 + c] + red[3][r*132 + c]
               + res[(size_t)row*128 + c];
      v[nf] = xx; sm += xx;
    }
    sm += __shfl_xor(sm, 1); sm += __shfl_xor(sm, 2);
    sm += __shfl_xor(sm, 4); sm += __shfl_xor(sm, 8);
    float mu = sm * 0.0078125f;
    float qv = 0.f;
    #pragma unroll
    for (int nf = 0; nf < 8; ++nf) { float d = v[nf] - mu; qv += d*d; }
    qv += __shfl_xor(qv, 1); qv += __shfl_xor(qv, 2);
    qv += __shfl_xor(qv, 4); qv += __shfl_xor(qv, 8);
    float rr = rsqrtf(qv * 0.0078125f + 1e-5f);
    #pragma unroll
    for (int nf = 0; nf < 8; ++nf) {
      int c = nf*16 + seg;
      out[(size_t)row*128 + c] = (v[nf] - mu) * rr * gam[c] + bet[c];
    }
  }
}

// ------------------------- flash attention (swapped-QK, no-max, KV-split 8) -
__global__ __launch_bounds__(256) void attn_k(
    const unsigned short* __restrict__ qkvb,
    float* __restrict__ po, float* __restrict__ pl) {
  __shared__ unsigned short lK[128][40];
  __shared__ unsigned short lV[32][136];
  const int tid = threadIdx.x, lane = tid & 63, w = tid >> 6;
  const int hh = blockIdx.y, sp = blockIdx.z;
  const int qr = blockIdx.x * 64 + w * 16;
  const int g = lane >> 4, q = lane & 15;

  s16x8 qf = *(const s16x8*)&qkvb[(size_t)(qr + q)*384 + hh*32 + g*8];

  f32x4 o[2];
  o[0] = f32x4{0.f,0.f,0.f,0.f}; o[1] = f32x4{0.f,0.f,0.f,0.f};
  float lrun = 0.f;

  const int srcA = q | ((2*(g & 1)) << 4);
  const int srcB = srcA + 16;
  const bool hi = (g >> 1) != 0;

  for (int kt = sp*4; kt < sp*4 + 4; ++kt) {
    const int k0 = kt * 128;
    __syncthreads();
    {
      int key = tid >> 1, d0 = (tid & 1) * 16;
      const unsigned short* src = qkvb + (size_t)(k0 + key)*384 + 128 + hh*32 + d0;
      *(u16x8*)&lK[key][d0]     = *(const u16x8*)&src[0];
      *(u16x8*)&lK[key][d0 + 8] = *(const u16x8*)&src[8];
    }
    {
      int kp = tid & 63, gg = tid >> 6;
      const unsigned short* s0 = qkvb + (size_t)(k0 + 2*kp)*384 + 256 + hh*32 + gg*8;
      u16x8 e0 = *(const u16x8*)s0;
      u16x8 e1 = *(const u16x8*)(s0 + 384);
      #pragma unroll
      for (int d = 0; d < 8; ++d) {
        unsigned int pkk = (unsigned int)e0[d] | ((unsigned int)e1[d] << 16);
        *(unsigned int*)&lV[gg*8 + d][2*kp] = pkk;
      }
    }
    __syncthreads();

    unsigned int pk[8][2];
    float ps = 0.f;
    #pragma unroll
    for (int nf = 0; nf < 8; ++nf) {
      s16x8 kf = *(const s16x8*)&lK[nf*16 + q][g*8];
      f32x4 c = MFMA16(kf, qf, (f32x4{0.f,0.f,0.f,0.f}));
      float p0 = exp2f(c[0]), p1 = exp2f(c[1]);
      float p2 = exp2f(c[2]), p3 = exp2f(c[3]);
      ps += (p0 + p1) + (p2 + p3);
      unsigned int u0 = __builtin_bit_cast(unsigned int, p0) + 0x8000u;
      unsigned int u1 = __builtin_bit_cast(unsigned int, p1) + 0x8000u;
      unsigned int u2 = __builtin_bit_cast(unsigned int, p2) + 0x8000u;
      unsigned int u3 = __builtin_bit_cast(unsigned int, p3) + 0x8000u;
      pk[nf][0] = (u0 >> 16) | (u1 & 0xffff0000u);
      pk[nf][1] = (u2 >> 16) | (u3 & 0xffff0000u);
    }
    ps += __shfl_xor(ps, 16);
    ps += __shfl_xor(ps, 32);
    lrun += ps;

    #pragma unroll
    for (int kc = 0; kc < 4; ++kc) {
      unsigned int a0 = (unsigned int)__shfl((int)pk[2*kc][0],   srcA);
      unsigned int b0 = (unsigned int)__shfl((int)pk[2*kc+1][0], srcA);
      unsigned int a1 = (unsigned int)__shfl((int)pk[2*kc][1],   srcA);
      unsigned int b1 = (unsigned int)__shfl((int)pk[2*kc+1][1], srcA);
      unsigned int a2 = (unsigned int)__shfl((int)pk[2*kc][0],   srcB);
      unsigned int b2 = (unsigned int)__shfl((int)pk[2*kc+1][0], srcB);
      unsigned int a3 = (unsigned int)__shfl((int)pk[2*kc][1],   srcB);
      unsigned int b3 = (unsigned int)__shfl((int)pk[2*kc+1][1], srcB);
      u32x4 wv;
      wv[0] = hi ? b0 : a0; wv[1] = hi ? b1 : a1;
      wv[2] = hi ? b2 : a2; wv[3] = hi ? b3 : a3;
      s16x8 pa = __builtin_bit_cast(s16x8, wv);
      #pragma unroll
      for (int df = 0; df < 2; ++df) {
        s16x8 vf = *(const s16x8*)&lV[df*16 + q][kc*32 + g*8];
        o[df] = MFMA16(pa, vf, o[df]);
      }
    }
  }
  #pragma unroll
  for (int df = 0; df < 2; ++df)
    #pragma unroll
    for (int j = 0; j < 4; ++j) {
      int row = qr + g*4 + j;
      po[((size_t)sp*4096 + row)*128 + hh*32 + df*16 + q] = o[df][j];
    }
  if (lane < 16)
    pl[((sp*4 + hh) << 12) + qr + lane] = lrun;
}

// ------------------------- launch -------------------------
extern "C" void kernel_launch(void* const* d_in, const int* in_sizes, int n_in,
                              void* d_out, int out_size, void* d_ws, size_t ws_size,
                              hipStream_t stream) {
  const float* x    = (const float*)d_in[0];
  const float* pos  = (const float*)d_in[1];
  const int*   idx  = (const int*)d_in[2];
  const float* W1   = (const float*)d_in[4];
  const float* b1   = (const float*)d_in[5];
  const float* W2   = (const float*)d_in[6];
  const float* b2   = (const float*)d_in[7];
  const float* Wr   = (const float*)d_in[8];
  const float* br   = (const float*)d_in[9];
  const float* ipw  = (const float*)d_in[10];
  const float* ipb  = (const float*)d_in[11];
  const float* opw  = (const float*)d_in[12];
  const float* opb  = (const float*)d_in[13];
  const float* Wm1  = (const float*)d_in[14];
  const float* bm1  = (const float*)d_in[15];
  const float* Wm2  = (const float*)d_in[16];
  const float* bm2  = (const float*)d_in[17];
  const float* g1   = (const float*)d_in[18];
  const float* be1  = (const float*)d_in[19];
  const float* g2   = (const float*)d_in[20];
  const float* be2  = (const float*)d_in[21];
  float* out = (float*)d_out;
  char* ws = (char*)d_ws;

  float4*         pos4  = (float4*)(ws + OFF_POS4);
  int*            colp  = (int*)(ws + OFF_COL);
  unsigned short* w1t   = (unsigned short*)(ws + OFF_W1T);
  unsigned short* w2t   = (unsigned short*)(ws + OFF_W2T);
  unsigned short* wrt   = (unsigned short*)(ws + OFF_WRT);
  unsigned short* wqkvt = (unsigned short*)(ws + OFF_WQKVT);
  unsigned short* woutt = (unsigned short*)(ws + OFF_WOUTT);
  unsigned short* wm1t  = (unsigned short*)(ws + OFF_WM1T);
  unsigned short* wm2t  = (unsigned short*)(ws + OFF_WM2T);
  float4* sposp = (float4*)(ws + OFF_SPOS);
  int*    ccnt  = (int*)(ws + OFF_CELLCNT);
  int2*   cdesc = (int2*)(ws + OFF_CELLDSC);
  int*    cfill = (int*)(ws + OFF_FILL);
  float*  pop   = (float*)(ws + OFF_PO);
  float*  plp   = (float*)(ws + OFF_PL);
  float* aggp  = (float*)(ws + OFF_AGG);
  float* xt0p  = (float*)(ws + OFF_XT0);
  unsigned short* qkvb = (unsigned short*)(ws + OFF_QKV);
  float* xt1p  = (float*)(ws + OFF_XT1);
  float* mlp1p = (float*)(ws + OFF_MLP1);
  float* sbias = (float*)(ws + OFF_SBIAS);

  zero_k<<<128, 256, 0, stream>>>(ccnt);
  prep_k<<<946, 256, 0, stream>>>(pos, W1, W2, Wr, ipw, ipb, opw, Wm1, Wm2,
                                  pos4, w1t, w2t, wrt, wqkvt, woutt, wm1t, wm2t,
                                  ccnt, sbias);
  prefix_k<<<1, 1024, 0, stream>>>(ccnt, cdesc, cfill);
  scatter_k<<<128, 256, 0, stream>>>(pos4, cfill, sposp);
  knn_k<<<1024, 256, 0, stream>>>(sposp, cdesc, pos4, idx, colp,
                                  out + 524288, out + 536576);
  conv_k<<<1024, 256, 0, stream>>>(x, pos4, idx, colp, w1t, b1, w2t, b2, aggp);
  gemm_k<256, 128, false, false, false><<<dim3(64, 2), 256, 0, stream>>>(aggp, wrt, br, nullptr, xt0p);
  gemm_k<128, 384, false, false, true><<<dim3(64, 6), 256, 0, stream>>>(xt0p, wqkvt, sbias, nullptr, (float*)qkvb);
  attn_k<<<dim3(64, 4, 8), 256, 0, stream>>>(qkvb, pop, plp);
  gemmln_k<128, true><<<256, 256, 0, stream>>>(nullptr, pop, plp, woutt, opb, xt0p, g1, be1, xt1p);
  gemm_k<128, 256, true, false, false><<<dim3(64, 4), 256, 0, stream>>>(xt1p, wm1t, bm1, nullptr, mlp1p);
  gemmln_k<256, false><<<256, 256, 0, stream>>>(mlp1p, nullptr, nullptr, wm2t, bm2, xt1p, g2, be2, out);
}

// Round 14
// 156.765 us; speedup vs baseline: 1.0722x; 1.0087x over previous
//
#include <hip/hip_runtime.h>
#include <hip/hip_bf16.h>

#define DEV static __device__ __forceinline__

typedef __attribute__((ext_vector_type(8))) short          s16x8;
typedef __attribute__((ext_vector_type(8))) unsigned short u16x8;
typedef __attribute__((ext_vector_type(4))) float          f32x4;
typedef __attribute__((ext_vector_type(4))) unsigned int   u32x4;

#define MFMA16(A,B,C) __builtin_amdgcn_mfma_f32_16x16x32_bf16((A),(B),(C),0,0,0)

DEV unsigned short f2bf(float f) {
  unsigned int u = __builtin_bit_cast(unsigned int, f);
  u += 0x7fffu + ((u >> 16) & 1u);
  return (unsigned short)(u >> 16);
}
DEV float bf2f(unsigned short u) {
  unsigned int x = ((unsigned int)u) << 16;
  return __builtin_bit_cast(float, x);
}

// 1/sqrt(32) * log2(e): fold into Q projection so softmax uses exp2 directly
#define QSCL 0.25503562201f

// ------------------------- grid params -------------------------
#define GRID_LO  (-5.0f)
#define GRID_IH  (3.2f)

DEV int cellc(float v) {
  int c = (int)floorf((v - GRID_LO) * GRID_IH);
  return min(31, max(0, c));
}

// ------------------------- ws layout -------------------------
constexpr size_t OFF_POS4  = 0;
constexpr size_t OFF_COL   = 524288;
constexpr size_t OFF_W1T   = 1048576;
constexpr size_t OFF_W2T   = OFF_W1T  + 24576;
constexpr size_t OFF_WRT   = OFF_W2T  + 65536;
constexpr size_t OFF_WQKVT = OFF_WRT  + 65536;
constexpr size_t OFF_WOUTT = OFF_WQKVT+ 98304;
constexpr size_t OFF_WM1T  = OFF_WOUTT+ 32768;
constexpr size_t OFF_WM2T  = OFF_WM1T + 65536;
constexpr size_t OFF_H     = OFF_WM2T + 65536;        // 33554432-byte shared region
// phase 1: cell structures
constexpr size_t OFF_SPOS    = OFF_H;
constexpr size_t OFF_CELLCNT = OFF_H + 524288;
constexpr size_t OFF_CELLDSC = OFF_H + 655360;
constexpr size_t OFF_FILL    = OFF_H + 917504;
// phase 2: attention partials (po now bf16: 8*4096*128*2 = 8388608)
constexpr size_t OFF_PO      = OFF_H;
constexpr size_t OFF_PL      = OFF_H + 16777216;      // 524288 (f32)
constexpr size_t OFF_AGG   = OFF_H    + 33554432;
constexpr size_t OFF_XT0   = OFF_AGG  + 4194304;
constexpr size_t OFF_QKV   = OFF_XT0  + 2097152;
constexpr size_t OFF_ATT   = OFF_QKV  + 6291456;
constexpr size_t OFF_PRE   = OFF_ATT  + 2097152;
constexpr size_t OFF_XT1   = OFF_PRE  + 2097152;
constexpr size_t OFF_MLP1  = OFF_XT1  + 2097152;
constexpr size_t OFF_SBIAS = OFF_MLP1 + 4194304;

// ------------------------- zero cell counts -------------------------
__global__ __launch_bounds__(256) void zero_k(int* __restrict__ p) {
  p[blockIdx.x * 256 + threadIdx.x] = 0;
}

// ------------------------- prep -------------------------
__global__ __launch_bounds__(256) void prep_k(
    const float* __restrict__ pos, const float* __restrict__ W1,
    const float* __restrict__ W2, const float* __restrict__ Wr,
    const float* __restrict__ ipw, const float* __restrict__ ipb,
    const float* __restrict__ opw,
    const float* __restrict__ Wm1, const float* __restrict__ Wm2,
    float4* __restrict__ pos4, unsigned short* __restrict__ w1t,
    unsigned short* __restrict__ w2t, unsigned short* __restrict__ wrt,
    unsigned short* __restrict__ wqkvt, unsigned short* __restrict__ woutt,
    unsigned short* __restrict__ wm1t, unsigned short* __restrict__ wm2t,
    int* __restrict__ cellcnt, float* __restrict__ sbias) {
  int T = blockIdx.x * 256 + threadIdx.x;
  if (T < 32768) {
    float px = pos[T*3], py = pos[T*3+1], pz = pos[T*3+2];
    pos4[T] = make_float4(px, py, pz, 0.f);
    int cid = (cellc(pz)*32 + cellc(py))*32 + cellc(px);
    atomicAdd(&cellcnt[cid], 1);
    return;
  }
  T -= 32768;
  if (T < 128*96)  { int n=T/96,  k=T%96;  w1t[T]  = f2bf(k < 67 ? W1[k*128+n] : 0.f); return; }
  T -= 128*96;
  if (T < 256*128) { int n=T/128, k=T%128; w2t[T]  = f2bf(W2[k*256+n]);  return; }
  T -= 256*128;
  if (T < 128*256) { int n=T/256, k=T%256; wrt[T]  = f2bf(Wr[k*128+n]);  return; }
  T -= 128*256;
  if (T < 384*128) { int n=T/128, k=T%128;
                     float v = ipw[k*384+n];
                     if (n < 128) v *= QSCL;
                     wqkvt[T]= f2bf(v); return; }
  T -= 384*128;
  if (T < 128*128) { int n=T/128, k=T%128; woutt[T]= f2bf(opw[k*128+n]); return; }
  T -= 128*128;
  if (T < 256*128) { int n=T/128, k=T%128; wm1t[T] = f2bf(Wm1[k*256+n]); return; }
  T -= 256*128;
  if (T < 128*256) { int n=T/256, k=T%256; wm2t[T] = f2bf(Wm2[k*128+n]); return; }
  T -= 128*256;
  if (T < 384) { sbias[T] = ipb[T] * (T < 128 ? QSCL : 1.f); return; }
}

// ------------------------- prefix over 32768 cell counts -------------------
__global__ __launch_bounds__(1024) void prefix_k(const int* __restrict__ cnt,
                                                 int2* __restrict__ desc,
                                                 int* __restrict__ fill) {
  __shared__ int wsum[16];
  const int tid = threadIdx.x, lane = tid & 63, w = tid >> 6;
  int loc[32]; int s = 0;
  #pragma unroll
  for (int i = 0; i < 32; ++i) { loc[i] = cnt[tid*32 + i]; s += loc[i]; }
  int sc = s;
  #pragma unroll
  for (int off = 1; off < 64; off <<= 1) {
    int v = __shfl_up(sc, off);
    if (lane >= off) sc += v;
  }
  if (lane == 63) wsum[w] = sc;
  __syncthreads();
  if (tid == 0) {
    int run = 0;
    #pragma unroll
    for (int i = 0; i < 16; ++i) { int v = wsum[i]; wsum[i] = run; run += v; }
  }
  __syncthreads();
  int base = wsum[w] + (sc - s);
  #pragma unroll
  for (int i = 0; i < 32; ++i) {
    int c = tid*32 + i;
    desc[c] = make_int2(base, loc[i]);
    fill[c] = base;
    base += loc[i];
  }
}

// ------------------------- scatter -------------------------
__global__ __launch_bounds__(256) void scatter_k(const float4* __restrict__ pos4,
                                                 int* __restrict__ fill,
                                                 float4* __restrict__ spos) {
  int T = blockIdx.x * 256 + threadIdx.x;
  float4 p = pos4[T];
  int cid = (cellc(p.z)*32 + cellc(p.y))*32 + cellc(p.x);
  int slot = atomicAdd(&fill[cid], 1);
  spos[slot] = make_float4(p.x, p.y, p.z, __int_as_float(T));
}

// ------------------------- KNN -------------------------
#define KNN_CAP  320
#define KNN_TRIG 192
#define KNN_KEEP 33
#define KNN_INF  3e37f

__global__ __launch_bounds__(256) void knn_k(
    const float4* __restrict__ spos, const int2* __restrict__ desc,
    const float4* __restrict__ pos4, const int* __restrict__ idx,
    int* __restrict__ col,
    float* __restrict__ outqpos, float* __restrict__ outbatch) {
  __shared__ float bufd[4][KNN_CAP];
  __shared__ int   bufi[4][KNN_CAP];
  __shared__ int   shist[4][64];
  __shared__ int2  segs[4][128];
  const int tid = threadIdx.x, lane = tid & 63, w = tid >> 6;
  const unsigned long long ltmask = (1ull << lane) - 1ull;

  const int q = blockIdx.x * 4 + w;
  const int iq = idx[q];
  const float4 qp = pos4[iq];
  const float qx = qp.x, qy = qp.y, qz = qp.z;
  const int cx0 = cellc(qx), cy0 = cellc(qy), cz0 = cellc(qz);

  float t = KNN_INF;
  int cnt = 0;

  auto compact = [&]() {
    int c_ = min(cnt, KNN_CAP);
    float vd[5]; int vi[5], bs[5]; bool okv[5];
    float dmax = 1e-30f;
    #pragma unroll
    for (int s = 0; s < 5; ++s) {
      int o2 = s*64 + lane;
      okv[s] = o2 < c_;
      vd[s] = okv[s] ? bufd[w][o2] : 0.f;
      vi[s] = okv[s] ? bufi[w][o2] : 0;
      dmax = fmaxf(dmax, vd[s]);
    }
    #pragma unroll
    for (int off = 1; off < 64; off <<= 1) dmax = fmaxf(dmax, __shfl_xor(dmax, off));
    float scale = 63.99f / dmax;
    shist[w][lane] = 0;
    #pragma unroll
    for (int s = 0; s < 5; ++s) {
      bs[s] = okv[s] ? min(63, (int)(vd[s] * scale)) : 64;
      if (okv[s]) atomicAdd(&shist[w][bs[s]], 1);
    }
    int h = shist[w][lane];
    #pragma unroll
    for (int off = 1; off < 64; off <<= 1) {
      int v = __shfl_up(h, off);
      if (lane >= off) h += v;
    }
    unsigned long long mk = __ballot(h >= KNN_KEEP);
    int E = mk ? (__ffsll((long long)mk) - 1) : 63;
    int base = 0;
    #pragma unroll
    for (int s = 0; s < 5; ++s) {
      bool keep = okv[s] && bs[s] <= E;
      unsigned long long km = __ballot(keep);
      int pp = base + (int)__popcll(km & ltmask);
      if (keep) { bufd[w][pp] = vd[s]; bufi[w][pp] = vi[s]; }
      base += (int)__popcll(km);
    }
    cnt = base;
    t = fminf(t, (float)(E + 1) / scale);
  };

  auto scan_rows = [&](int knew, int kold) {
    const int S = 2*knew + 1;
    const int NR = S*S;
    const float invS = 1.f / (float)S;
    for (int r0 = 0; r0 < NR; r0 += 64) {
      int r = r0 + lane;
      bool v = r < NR;
      int dz = (int)((float)r * invS);
      int rem = r - dz*S;
      if (rem < 0) { dz--; rem += S; } else if (rem >= S) { dz++; rem -= S; }
      int ccz = cz0 + dz - knew, ccy = cy0 + rem - knew;
      bool rowok = v && ccz >= 0 && ccz < 32 && ccy >= 0 && ccy < 32;
      bool inner = kold >= 0 && abs(dz - knew) <= kold && abs(rem - knew) <= kold;
      int cbase = (ccz*32 + ccy) * 32;
      int sL = 0, lL = 0, sR = 0, lR = 0;
      if (rowok) {
        int xa = max(cx0 - knew, 0);
        int xb = inner ? (cx0 - kold - 1) : min(cx0 + knew, 31);
        if (xa <= xb) {
          int2 d0 = desc[cbase + xa];
          int2 d1 = desc[cbase + xb];
          sL = d0.x; lL = d1.x + d1.y - d0.x;
        }
        if (inner) {
          int xa2 = cx0 + kold + 1, xb2 = min(cx0 + knew, 31);
          if (xa2 <= xb2 && xa2 >= 0) {
            int2 d0 = desc[cbase + xa2];
            int2 d1 = desc[cbase + xb2];
            sR = d0.x; lR = d1.x + d1.y - d0.x;
          }
        }
      }
      int cumL = lL;
      #pragma unroll
      for (int off = 1; off < 64; off <<= 1) {
        int vv = __shfl_up(cumL, off);
        if (lane >= off) cumL += vv;
      }
      int sumL = __shfl(cumL, 63);
      int cumR = lR;
      #pragma unroll
      for (int off = 1; off < 64; off <<= 1) {
        int vv = __shfl_up(cumR, off);
        if (lane >= off) cumR += vv;
      }
      int sumR = __shfl(cumR, 63);
      segs[w][lane]      = make_int2(sL, cumL - lL);
      segs[w][64 + lane] = make_int2(sR, sumL + cumR - lR);
      const int total = sumL + sumR;

      for (int b = 0; b < total; b += 320) {
        float d2v[5]; int piv[5]; bool hv[5];
        #pragma unroll
        for (int s5 = 0; s5 < 5; ++s5) {
          int p = b + s5*64 + lane;
          bool act = p < total;
          hv[s5] = false; d2v[s5] = 0.f; piv[s5] = 0;
          if (act) {
            int lo = 0;
            #pragma unroll
            for (int st = 64; st > 0; st >>= 1)
              if (segs[w][lo + st].y <= p) lo += st;
            int2 e = segs[w][lo];
            float4 pt = spos[e.x + (p - e.y)];
            float ddx = qx-pt.x, ddy = qy-pt.y, ddz = qz-pt.z;
            float d2 = ddx*ddx + ddy*ddy + ddz*ddz;
            d2v[s5] = d2; piv[s5] = __float_as_int(pt.w);
            hv[s5] = d2 < t;
          }
        }
        #pragma unroll
        for (int s5 = 0; s5 < 5; ++s5) {
          unsigned long long hm = __ballot(hv[s5]);
          if (hm) {
            int pp = cnt + (int)__popcll(hm & ltmask);
            if (hv[s5] && pp < KNN_CAP) { bufd[w][pp] = d2v[s5]; bufi[w][pp] = piv[s5]; }
            cnt += (int)__popcll(hm);
            if (cnt >= KNN_TRIG) compact();
          }
        }
      }
    }
  };

  auto bound32 = [&]() -> float {
    int c_ = min(cnt, KNN_CAP);
    float vv[5]; bool okv[5];
    float dmax = 1e-30f;
    #pragma unroll
    for (int s = 0; s < 5; ++s) {
      int o2 = s*64 + lane;
      okv[s] = o2 < c_;
      vv[s] = okv[s] ? bufd[w][o2] : 0.f;
      dmax = fmaxf(dmax, vv[s]);
    }
    #pragma unroll
    for (int off = 1; off < 64; off <<= 1) dmax = fmaxf(dmax, __shfl_xor(dmax, off));
    float scale = 63.99f / dmax;
    shist[w][lane] = 0;
    #pragma unroll
    for (int s = 0; s < 5; ++s)
      if (okv[s]) atomicAdd(&shist[w][min(63, (int)(vv[s] * scale))], 1);
    int h = shist[w][lane];
    #pragma unroll
    for (int off = 1; off < 64; off <<= 1) {
      int v = __shfl_up(h, off);
      if (lane >= off) h += v;
    }
    unsigned long long m = __ballot(h >= 32);
    int E = m ? (__ffsll((long long)m) - 1) : 63;
    return (float)(E + 1) / scale;
  };

  int kcur = 1;
  scan_rows(1, -1);
  for (int it = 0; it < 64; ++it) {
    if (cnt >= 32) {
      float t32u = bound32();
      t = fminf(t, t32u);
      int kneed = (int)(__builtin_sqrtf(t32u) * GRID_IH) + 1;
      if (kneed <= kcur || kcur >= 31) break;
      int knew = min(kneed, 31);
      scan_rows(knew, kcur);
      kcur = knew;
    } else {
      if (kcur >= 31) break;
      int knew = min(kcur + (cnt == 0 ? 2 : 1), 31);
      scan_rows(knew, kcur);
      kcur = knew;
    }
  }

  // ---- final exact top-32 ----
  {
    int c_ = min(cnt, KNN_CAP);
    float vd[5]; int vi[5], bs[5]; bool okf[5];
    float dmax = 1e-30f;
    #pragma unroll
    for (int s = 0; s < 5; ++s) {
      int o2 = s*64 + lane;
      okf[s] = o2 < c_;
      vd[s] = okf[s] ? bufd[w][o2] : KNN_INF;
      vi[s] = okf[s] ? bufi[w][o2] : 0;
      dmax = fmaxf(dmax, okf[s] ? vd[s] : 0.f);
    }
    #pragma unroll
    for (int off = 1; off < 64; off <<= 1) dmax = fmaxf(dmax, __shfl_xor(dmax, off));
    float sc64 = 63.99f / dmax;
    shist[w][lane] = 0;
    #pragma unroll
    for (int s = 0; s < 5; ++s) {
      bs[s] = okf[s] ? min(63, (int)(vd[s] * sc64)) : 64;
      if (okf[s]) atomicAdd(&shist[w][bs[s]], 1);
    }
    int h = shist[w][lane];
    #pragma unroll
    for (int off = 1; off < 64; off <<= 1) {
      int v = __shfl_up(h, off);
      if (lane >= off) h += v;
    }
    unsigned long long m = __ballot(h >= 32);
    int E = m ? (__ffsll((long long)m) - 1) : 63;
    int c0 = (E > 0) ? __shfl(h, E - 1) : 0;
    int base = 0;
    #pragma unroll
    for (int s = 0; s < 5; ++s) {
      bool wr = okf[s] && (bs[s] < E);
      unsigned long long km = __ballot(wr);
      int pp = base + (int)__popcll(km & ltmask);
      if (wr) col[q*32 + pp] = vi[s];
      base += (int)__popcll(km);
    }
    #pragma unroll
    for (int s = 0; s < 5; ++s)
      if (!(okf[s] && bs[s] == E)) vd[s] = KNN_INF;
    int r = 32 - c0;
    #pragma unroll 1
    for (int kk = 0; kk < r; ++kk) {
      float bd = vd[0]; int bi = vi[0]; int bc = lane*8;
      #pragma unroll
      for (int s = 1; s < 5; ++s)
        if (vd[s] < bd) { bd = vd[s]; bi = vi[s]; bc = lane*8 + s; }
      #pragma unroll
      for (int off = 1; off < 64; off <<= 1) {
        float od = __shfl_xor(bd, off);
        int   oi = __shfl_xor(bi, off);
        int   oc = __shfl_xor(bc, off);
        if (od < bd || (od == bd && oc < bc)) { bd = od; bi = oi; bc = oc; }
      }
      if ((bc >> 3) == lane) {
        int sl = bc & 7;
        #pragma unroll
        for (int s = 0; s < 5; ++s) if (sl == s) vd[s] = KNN_INF;
      }
      if (lane == 0) col[q*32 + c0 + kk] = bi;
    }
  }
  if (lane == 0) {
    outqpos[q*3+0] = qx; outqpos[q*3+1] = qy; outqpos[q*3+2] = qz;
    outbatch[q] = 0.f;
  }
}

// ------------------------- fused conv -------------------------
// LDS pool (u16): phase1 feat [128][104] @0 + W1 [128][104] @13312
//                 phase2 h [128][136] @0 + W2 dbuf 2x[32][136] @17408/@21760
#define LA1(r,c) S[(r)*104 + (c)]
#define LB1(r,c) S[13312 + (r)*104 + (c)]
#define HB(r,c)  S[(r)*136 + (c)]

__global__ __launch_bounds__(256) void conv_k(
    const float* __restrict__ x, const float4* __restrict__ pos4,
    const int* __restrict__ idx, const int* __restrict__ col,
    const unsigned short* __restrict__ w1t, const float* __restrict__ b1,
    const unsigned short* __restrict__ w2t, const float* __restrict__ b2,
    float* __restrict__ agg) {
  __shared__ __align__(16) unsigned short S[26624];
  __shared__ int   sci[128];
  __shared__ float sqp[4][3];
  const int tid = threadIdx.x, lane = tid & 63, w = tid >> 6;
  const int wm = w >> 1, wn = w & 1;
  const int m0 = blockIdx.x * 4;

  if (tid < 128) sci[tid] = col[m0*32 + tid];
  if (tid >= 128 && tid < 132) {
    int m = m0 + tid - 128;
    float4 p = pos4[idx[m]];
    sqp[tid-128][0] = p.x; sqp[tid-128][1] = p.y; sqp[tid-128][2] = p.z;
  }
  #pragma unroll
  for (int rnd = 0; rnd < 6; ++rnd) {
    int e = (rnd*256 + tid) * 8;
    int n = e / 96, k = e % 96;
    *(u16x8*)&LB1(n, k) = *(const u16x8*)&w1t[e];
  }
  __syncthreads();

  {
    int r = tid >> 1, half = tid & 1;
    int ci = sci[r];
    const float* src = x + (size_t)ci*64 + half*32;
    #pragma unroll
    for (int c = 0; c < 4; ++c) {
      float4 va = ((const float4*)src)[c*2], vb = ((const float4*)src)[c*2+1];
      u16x8 v;
      v[0]=f2bf(va.x); v[1]=f2bf(va.y); v[2]=f2bf(va.z); v[3]=f2bf(va.w);
      v[4]=f2bf(vb.x); v[5]=f2bf(vb.y); v[6]=f2bf(vb.z); v[7]=f2bf(vb.w);
      *(u16x8*)&LA1(r, half*32 + c*8) = v;
    }
  }
  if (tid < 128) {
    int r = tid, g = r >> 5;
    float4 p = pos4[sci[r]];
    u16x8 z;
    #pragma unroll
    for (int e = 0; e < 8; ++e) z[e] = 0;
    u16x8 v0 = z;
    v0[0] = f2bf(p.x - sqp[g][0]); v0[1] = f2bf(p.y - sqp[g][1]); v0[2] = f2bf(p.z - sqp[g][2]);
    *(u16x8*)&LA1(r, 64) = v0;
    #pragma unroll
    for (int c = 1; c < 5; ++c) *(u16x8*)&LA1(r, 64 + c*8) = z;
  }
  __syncthreads();

  // GEMM1
  f32x4 acc[4][4];
  #pragma unroll
  for (int nf = 0; nf < 4; ++nf) {
    float bv = b1[wn*64 + nf*16 + (lane & 15)];
    #pragma unroll
    for (int mf = 0; mf < 4; ++mf) acc[mf][nf] = f32x4{bv, bv, bv, bv};
  }
  #pragma unroll
  for (int kc = 0; kc < 3; ++kc) {
    s16x8 af[4], bf_[4];
    #pragma unroll
    for (int mf = 0; mf < 4; ++mf)
      af[mf] = *(const s16x8*)&LA1(wm*64 + mf*16 + (lane&15), kc*32 + (lane>>4)*8);
    #pragma unroll
    for (int nf = 0; nf < 4; ++nf)
      bf_[nf] = *(const s16x8*)&LB1(wn*64 + nf*16 + (lane&15), kc*32 + (lane>>4)*8);
    #pragma unroll
    for (int mf = 0; mf < 4; ++mf)
      #pragma unroll
      for (int nf = 0; nf < 4; ++nf)
        acc[mf][nf] = MFMA16(af[mf], bf_[nf], acc[mf][nf]);
  }
  __syncthreads();

  // h tile -> HB; stage W2 chunk 0 ([32][128]) into buffer 0
  #pragma unroll
  for (int mf = 0; mf < 4; ++mf)
    #pragma unroll
    for (int nf = 0; nf < 4; ++nf)
      #pragma unroll
      for (int j = 0; j < 4; ++j) {
        int rloc = wm*64 + mf*16 + ((lane>>4)<<2) + j;
        int cloc = wn*64 + nf*16 + (lane & 15);
        HB(rloc, cloc) = f2bf(fmaxf(acc[mf][nf][j], 0.f));
      }
  {
    int r3 = tid >> 3, kq = (tid & 7) * 16;
    const unsigned short* src = w2t + (size_t)r3*128 + kq;
    *(u16x8*)&S[17408 + r3*136 + kq]     = *(const u16x8*)&src[0];
    *(u16x8*)&S[17408 + r3*136 + kq + 8] = *(const u16x8*)&src[8];
  }
  __syncthreads();

  // GEMM2 over 8 N-chunks of 32, double-buffered W2, reg-staged prefetch
  int bufo = 0;
  #pragma unroll 1
  for (int nc = 0; nc < 8; ++nc) {
    u16x8 nx0, nx1;
    if (nc < 7) {
      int r3 = tid >> 3, kq = (tid & 7) * 16;
      const unsigned short* src = w2t + (size_t)((nc+1)*32 + r3)*128 + kq;
      nx0 = *(const u16x8*)&src[0];
      nx1 = *(const u16x8*)&src[8];
    }
    f32x4 acc2[2][2];
    #pragma unroll
    for (int nf = 0; nf < 2; ++nf) {
      float bv = b2[nc*32 + nf*16 + (lane & 15)];
      acc2[0][nf] = f32x4{bv, bv, bv, bv};
      acc2[1][nf] = f32x4{bv, bv, bv, bv};
    }
    const int base2 = 17408 + bufo*4352;
    #pragma unroll
    for (int ks = 0; ks < 4; ++ks) {
      s16x8 af[2], bf_[2];
      #pragma unroll
      for (int mf = 0; mf < 2; ++mf)
        af[mf] = *(const s16x8*)&HB(w*32 + mf*16 + (lane&15), ks*32 + (lane>>4)*8);
      #pragma unroll
      for (int nf = 0; nf < 2; ++nf)
        bf_[nf] = *(const s16x8*)&S[base2 + (nf*16 + (lane&15))*136 + ks*32 + (lane>>4)*8];
      #pragma unroll
      for (int mf = 0; mf < 2; ++mf)
        #pragma unroll
        for (int nf = 0; nf < 2; ++nf)
          acc2[mf][nf] = MFMA16(af[mf], bf_[nf], acc2[mf][nf]);
    }
    #pragma unroll
    for (int nf = 0; nf < 2; ++nf) {
      float mx = acc2[0][nf][0];
      #pragma unroll
      for (int j = 1; j < 4; ++j) mx = fmaxf(mx, acc2[0][nf][j]);
      #pragma unroll
      for (int j = 0; j < 4; ++j) mx = fmaxf(mx, acc2[1][nf][j]);
      mx = fmaxf(mx, __shfl_xor(mx, 16));
      mx = fmaxf(mx, __shfl_xor(mx, 32));
      if (lane < 16) agg[(size_t)(m0 + w)*256 + nc*32 + nf*16 + lane] = mx;
    }
    if (nc < 7) {
      int r3 = tid >> 3, kq = (tid & 7) * 16;
      int nb = 17408 + (bufo^1)*4352;
      *(u16x8*)&S[nb + r3*136 + kq]     = nx0;
      *(u16x8*)&S[nb + r3*136 + kq + 8] = nx1;
      __syncthreads();
      bufo ^= 1;
    }
  }
}

// ------------------------- 64x64-tile GEMM -------------------------
template<int KFULL, int NFULL, bool RELU, bool HAS_RES, bool OBF16>
__global__ __launch_bounds__(256) void gemm_k(
    const float* __restrict__ A, const unsigned short* __restrict__ Bt,
    const float* __restrict__ bias, const float* __restrict__ res,
    float* __restrict__ out) {
  __shared__ unsigned short lA[64][72];
  __shared__ unsigned short lB[64][72];
  const int tid = threadIdx.x, lane = tid & 63, w = tid >> 6;
  const int m0 = blockIdx.x * 64, n0 = blockIdx.y * 64;

  f32x4 acc[4];
  #pragma unroll
  for (int nf = 0; nf < 4; ++nf) {
    float bv = bias[n0 + nf*16 + (lane & 15)];
    acc[nf] = f32x4{bv, bv, bv, bv};
  }

  for (int kb = 0; kb < KFULL; kb += 64) {
    __syncthreads();
    {
      int r = tid >> 2, kq = (tid & 3) * 16;
      const float* src = A + (size_t)(m0 + r)*KFULL + kb + kq;
      #pragma unroll
      for (int c = 0; c < 2; ++c) {
        float4 va = ((const float4*)src)[c*2], vb = ((const float4*)src)[c*2+1];
        u16x8 v;
        v[0]=f2bf(va.x); v[1]=f2bf(va.y); v[2]=f2bf(va.z); v[3]=f2bf(va.w);
        v[4]=f2bf(vb.x); v[5]=f2bf(vb.y); v[6]=f2bf(vb.z); v[7]=f2bf(vb.w);
        *(u16x8*)&lA[r][kq + c*8] = v;
      }
      const unsigned short* srcb = Bt + (size_t)(n0 + r)*KFULL + kb + kq;
      #pragma unroll
      for (int c = 0; c < 2; ++c)
        *(u16x8*)&lB[r][kq + c*8] = *(const u16x8*)&srcb[c*8];
    }
    __syncthreads();
    #pragma unroll
    for (int ks = 0; ks < 2; ++ks) {
      s16x8 af = *(const s16x8*)&lA[w*16 + (lane&15)][ks*32 + (lane>>4)*8];
      s16x8 bf_[4];
      #pragma unroll
      for (int nf = 0; nf < 4; ++nf)
        bf_[nf] = *(const s16x8*)&lB[nf*16 + (lane&15)][ks*32 + (lane>>4)*8];
      #pragma unroll
      for (int nf = 0; nf < 4; ++nf)
        acc[nf] = MFMA16(af, bf_[nf], acc[nf]);
    }
  }
  #pragma unroll
  for (int nf = 0; nf < 4; ++nf)
    #pragma unroll
    for (int j = 0; j < 4; ++j) {
      int row = m0 + w*16 + ((lane>>4)<<2) + j;
      int colg = n0 + nf*16 + (lane & 15);
      float v = acc[nf][j];
      if (HAS_RES) v += res[(size_t)row*NFULL + colg];
      if (RELU)    v = fmaxf(v, 0.f);
      if (OBF16) ((unsigned short*)out)[(size_t)row*NFULL + colg] = f2bf(v);
      else       out[(size_t)row*NFULL + colg] = v;
    }
}

// ------------------------- fused out_proj + residual + LN (N-split) --------
// 16 rows/block, 256 blocks. Wave w computes output cols [w*32, w*32+32) with
// full K; B-frags read directly from global (L2-resident weights).
template<int KFULL, bool COMBINE>
__global__ __launch_bounds__(256) void gemmln2_k(
    const float* __restrict__ A,
    const unsigned short* __restrict__ po, const float* __restrict__ pl,
    const unsigned short* __restrict__ Bt, const float* __restrict__ bias,
    const float* __restrict__ res,
    const float* __restrict__ gam, const float* __restrict__ bet,
    float* __restrict__ out) {
  constexpr int KP = KFULL + 8;
  __shared__ __align__(16) unsigned short lA[16 * KP];
  __shared__ float vout[16 * 132];
  const int tid = threadIdx.x, lane = tid & 63, w = tid >> 6;
  const int g = lane >> 4, ln_ = lane & 15;
  const int m0 = blockIdx.x * 16;

  {
    int r = tid >> 4, seg = tid & 15;
    int row = m0 + r;
    if (COMBINE) {
      int hh = seg >> 2;
      float lsum = 0.f;
      #pragma unroll
      for (int s = 0; s < 8; ++s) lsum += pl[((s*4 + hh) << 12) + row];
      float inv = 1.f / lsum;
      float a[8] = {0,0,0,0,0,0,0,0};
      #pragma unroll
      for (int s = 0; s < 8; ++s) {
        u16x8 v = *(const u16x8*)&po[((size_t)s*4096 + row)*128 + seg*8];
        #pragma unroll
        for (int e = 0; e < 8; ++e) a[e] += bf2f(v[e]);
      }
      u16x8 ov;
      #pragma unroll
      for (int e = 0; e < 8; ++e) ov[e] = f2bf(a[e] * inv);
      *(u16x8*)&lA[r*KP + seg*8] = ov;
    } else {
      const float* src = A + (size_t)row*KFULL + seg*(KFULL/16);
      #pragma unroll
      for (int c = 0; c < KFULL/128; ++c) {
        float4 va = ((const float4*)src)[c*2], vb = ((const float4*)src)[c*2+1];
        u16x8 v;
        v[0]=f2bf(va.x); v[1]=f2bf(va.y); v[2]=f2bf(va.z); v[3]=f2bf(va.w);
        v[4]=f2bf(vb.x); v[5]=f2bf(vb.y); v[6]=f2bf(vb.z); v[7]=f2bf(vb.w);
        *(u16x8*)&lA[r*KP + seg*(KFULL/16) + c*8] = v;
      }
    }
  }
  __syncthreads();

  const int n0 = w * 32;
  f32x4 acc[2];
  #pragma unroll
  for (int nf = 0; nf < 2; ++nf) {
    float bv = bias[n0 + nf*16 + ln_];
    acc[nf] = f32x4{bv, bv, bv, bv};
  }
  #pragma unroll
  for (int ks = 0; ks < KFULL/32; ++ks) {
    s16x8 af = *(const s16x8*)&lA[ln_*KP + ks*32 + g*8];
    #pragma unroll
    for (int nf = 0; nf < 2; ++nf) {
      s16x8 bf_ = *(const s16x8*)&Bt[(size_t)(n0 + nf*16 + ln_)*KFULL + ks*32 + g*8];
      acc[nf] = MFMA16(af, bf_, acc[nf]);
    }
  }
  #pragma unroll
  for (int nf = 0; nf < 2; ++nf)
    #pragma unroll
    for (int j = 0; j < 4; ++j)
      vout[(g*4 + j)*132 + n0 + nf*16 + ln_] = acc[nf][j];
  __syncthreads();

  {
    int r = tid >> 4, seg = tid & 15;
    int row = m0 + r;
    float v[8]; float sm = 0.f;
    #pragma unroll
    for (int nf = 0; nf < 8; ++nf) {
      int c = nf*16 + seg;
      float xx = vout[r*132 + c] + res[(size_t)row*128 + c];
      v[nf] = xx; sm += xx;
    }
    sm += __shfl_xor(sm, 1); sm += __shfl_xor(sm, 2);
    sm += __shfl_xor(sm, 4); sm += __shfl_xor(sm, 8);
    float mu = sm * 0.0078125f;
    float qv = 0.f;
    #pragma unroll
    for (int nf = 0; nf < 8; ++nf) { float d = v[nf] - mu; qv += d*d; }
    qv += __shfl_xor(qv, 1); qv += __shfl_xor(qv, 2);
    qv += __shfl_xor(qv, 4); qv += __shfl_xor(qv, 8);
    float rr = rsqrtf(qv * 0.0078125f + 1e-5f);
    #pragma unroll
    for (int nf = 0; nf < 8; ++nf) {
      int c = nf*16 + seg;
      out[(size_t)row*128 + c] = (v[nf] - mu) * rr * gam[c] + bet[c];
    }
  }
}

// ------------------------- fused MLP (mlp1+relu+mlp2+res+LN) ---------------
// 16 rows/block, 256 blocks. Weights read via global B-frags (L2-resident).
__global__ __launch_bounds__(256) void mlpln_k(
    const float* __restrict__ xt1,
    const unsigned short* __restrict__ wm1t, const float* __restrict__ bm1,
    const unsigned short* __restrict__ wm2t, const float* __restrict__ bm2,
    const float* __restrict__ gam, const float* __restrict__ bet,
    float* __restrict__ out) {
  __shared__ __align__(16) unsigned short lA[16 * 136];
  __shared__ __align__(16) unsigned short lH[16 * 264];
  __shared__ float vout[16 * 132];
  const int tid = threadIdx.x, lane = tid & 63, w = tid >> 6;
  const int g = lane >> 4, ln_ = lane & 15;
  const int m0 = blockIdx.x * 16;

  {
    int r = tid >> 4, seg = tid & 15;
    const float* src = xt1 + (size_t)(m0 + r)*128 + seg*8;
    float4 va = ((const float4*)src)[0], vb = ((const float4*)src)[1];
    u16x8 v;
    v[0]=f2bf(va.x); v[1]=f2bf(va.y); v[2]=f2bf(va.z); v[3]=f2bf(va.w);
    v[4]=f2bf(vb.x); v[5]=f2bf(vb.y); v[6]=f2bf(vb.z); v[7]=f2bf(vb.w);
    *(u16x8*)&lA[r*136 + seg*8] = v;
  }
  __syncthreads();

  { // mlp1: wave w covers h1 cols [w*64, w*64+64)
    const int n0 = w * 64;
    f32x4 acc1[4];
    #pragma unroll
    for (int nf = 0; nf < 4; ++nf) {
      float bv = bm1[n0 + nf*16 + ln_];
      acc1[nf] = f32x4{bv, bv, bv, bv};
    }
    #pragma unroll
    for (int ks = 0; ks < 4; ++ks) {
      s16x8 af = *(const s16x8*)&lA[ln_*136 + ks*32 + g*8];
      #pragma unroll
      for (int nf = 0; nf < 4; ++nf) {
        s16x8 bf_ = *(const s16x8*)&wm1t[(size_t)(n0 + nf*16 + ln_)*128 + ks*32 + g*8];
        acc1[nf] = MFMA16(af, bf_, acc1[nf]);
      }
    }
    #pragma unroll
    for (int nf = 0; nf < 4; ++nf)
      #pragma unroll
      for (int j = 0; j < 4; ++j)
        lH[(g*4 + j)*264 + n0 + nf*16 + ln_] = f2bf(fmaxf(acc1[nf][j], 0.f));
  }
  __syncthreads();

  { // mlp2: wave w covers out cols [w*32, w*32+32), K=256
    const int n0 = w * 32;
    f32x4 acc2[2];
    #pragma unroll
    for (int nf = 0; nf < 2; ++nf) {
      float bv = bm2[n0 + nf*16 + ln_];
      acc2[nf] = f32x4{bv, bv, bv, bv};
    }
    #pragma unroll
    for (int ks = 0; ks < 8; ++ks) {
      s16x8 af = *(const s16x8*)&lH[ln_*264 + ks*32 + g*8];
      #pragma unroll
      for (int nf = 0; nf < 2; ++nf) {
        s16x8 bf_ = *(const s16x8*)&wm2t[(size_t)(n0 + nf*16 + ln_)*256 + ks*32 + g*8];
        acc2[nf] = MFMA16(af, bf_, acc2[nf]);
      }
    }
    #pragma unroll
    for (int nf = 0; nf < 2; ++nf)
      #pragma unroll
      for (int j = 0; j < 4; ++j)
        vout[(g*4 + j)*132 + n0 + nf*16 + ln_] = acc2[nf][j];
  }
  __syncthreads();

  {
    int r = tid >> 4, seg = tid & 15;
    int row = m0 + r;
    float v[8]; float sm = 0.f;
    #pragma unroll
    for (int nf = 0; nf < 8; ++nf) {
      int c = nf*16 + seg;
      float xx = vout[r*132 + c] + xt1[(size_t)row*128 + c];
      v[nf] = xx; sm += xx;
    }
    sm += __shfl_xor(sm, 1); sm += __shfl_xor(sm, 2);
    sm += __shfl_xor(sm, 4); sm += __shfl_xor(sm, 8);
    float mu = sm * 0.0078125f;
    float qv = 0.f;
    #pragma unroll
    for (int nf = 0; nf < 8; ++nf) { float d = v[nf] - mu; qv += d*d; }
    qv += __shfl_xor(qv, 1); qv += __shfl_xor(qv, 2);
    qv += __shfl_xor(qv, 4); qv += __shfl_xor(qv, 8);
    float rr = rsqrtf(qv * 0.0078125f + 1e-5f);
    #pragma unroll
    for (int nf = 0; nf < 8; ++nf) {
      int c = nf*16 + seg;
      out[(size_t)row*128 + c] = (v[nf] - mu) * rr * gam[c] + bet[c];
    }
  }
}

// ------------------------- flash attention (swapped-QK, no-max, KV-split 8) -
__global__ __launch_bounds__(256) void attn_k(
    const unsigned short* __restrict__ qkvb,
    unsigned short* __restrict__ po, float* __restrict__ pl) {
  __shared__ unsigned short lK[128][40];
  __shared__ unsigned short lV[32][136];
  const int tid = threadIdx.x, lane = tid & 63, w = tid >> 6;
  const int hh = blockIdx.y, sp = blockIdx.z;
  const int qr = blockIdx.x * 64 + w * 16;
  const int g = lane >> 4, q = lane & 15;

  s16x8 qf = *(const s16x8*)&qkvb[(size_t)(qr + q)*384 + hh*32 + g*8];

  f32x4 o[2];
  o[0] = f32x4{0.f,0.f,0.f,0.f}; o[1] = f32x4{0.f,0.f,0.f,0.f};
  float lrun = 0.f;

  const int srcA = q | ((2*(g & 1)) << 4);
  const int srcB = srcA + 16;
  const bool hi = (g >> 1) != 0;

  for (int kt = sp*4; kt < sp*4 + 4; ++kt) {
    const int k0 = kt * 128;
    __syncthreads();
    {
      int key = tid >> 1, d0 = (tid & 1) * 16;
      const unsigned short* src = qkvb + (size_t)(k0 + key)*384 + 128 + hh*32 + d0;
      *(u16x8*)&lK[key][d0]     = *(const u16x8*)&src[0];
      *(u16x8*)&lK[key][d0 + 8] = *(const u16x8*)&src[8];
    }
    {
      int kp = tid & 63, gg = tid >> 6;
      const unsigned short* s0 = qkvb + (size_t)(k0 + 2*kp)*384 + 256 + hh*32 + gg*8;
      u16x8 e0 = *(const u16x8*)s0;
      u16x8 e1 = *(const u16x8*)(s0 + 384);
      #pragma unroll
      for (int d = 0; d < 8; ++d) {
        unsigned int pkk = (unsigned int)e0[d] | ((unsigned int)e1[d] << 16);
        *(unsigned int*)&lV[gg*8 + d][2*kp] = pkk;
      }
    }
    __syncthreads();

    unsigned int pk[8][2];
    float ps = 0.f;
    #pragma unroll
    for (int nf = 0; nf < 8; ++nf) {
      s16x8 kf = *(const s16x8*)&lK[nf*16 + q][g*8];
      f32x4 c = MFMA16(kf, qf, (f32x4{0.f,0.f,0.f,0.f}));
      float p0 = exp2f(c[0]), p1 = exp2f(c[1]);
      float p2 = exp2f(c[2]), p3 = exp2f(c[3]);
      ps += (p0 + p1) + (p2 + p3);
      unsigned int u0 = __builtin_bit_cast(unsigned int, p0) + 0x8000u;
      unsigned int u1 = __builtin_bit_cast(unsigned int, p1) + 0x8000u;
      unsigned int u2 = __builtin_bit_cast(unsigned int, p2) + 0x8000u;
      unsigned int u3 = __builtin_bit_cast(unsigned int, p3) + 0x8000u;
      pk[nf][0] = (u0 >> 16) | (u1 & 0xffff0000u);
      pk[nf][1] = (u2 >> 16) | (u3 & 0xffff0000u);
    }
    ps += __shfl_xor(ps, 16);
    ps += __shfl_xor(ps, 32);
    lrun += ps;

    #pragma unroll
    for (int kc = 0; kc < 4; ++kc) {
      unsigned int a0 = (unsigned int)__shfl((int)pk[2*kc][0],   srcA);
      unsigned int b0 = (unsigned int)__shfl((int)pk[2*kc+1][0], srcA);
      unsigned int a1 = (unsigned int)__shfl((int)pk[2*kc][1],   srcA);
      unsigned int b1 = (unsigned int)__shfl((int)pk[2*kc+1][1], srcA);
      unsigned int a2 = (unsigned int)__shfl((int)pk[2*kc][0],   srcB);
      unsigned int b2 = (unsigned int)__shfl((int)pk[2*kc+1][0], srcB);
      unsigned int a3 = (unsigned int)__shfl((int)pk[2*kc][1],   srcB);
      unsigned int b3 = (unsigned int)__shfl((int)pk[2*kc+1][1], srcB);
      u32x4 wv;
      wv[0] = hi ? b0 : a0; wv[1] = hi ? b1 : a1;
      wv[2] = hi ? b2 : a2; wv[3] = hi ? b3 : a3;
      s16x8 pa = __builtin_bit_cast(s16x8, wv);
      #pragma unroll
      for (int df = 0; df < 2; ++df) {
        s16x8 vf = *(const s16x8*)&lV[df*16 + q][kc*32 + g*8];
        o[df] = MFMA16(pa, vf, o[df]);
      }
    }
  }
  #pragma unroll
  for (int df = 0; df < 2; ++df)
    #pragma unroll
    for (int j = 0; j < 4; ++j) {
      int row = qr + g*4 + j;
      po[((size_t)sp*4096 + row)*128 + hh*32 + df*16 + q] = f2bf(o[df][j]);
    }
  if (lane < 16)
    pl[((sp*4 + hh) << 12) + qr + lane] = lrun;
}

// ------------------------- launch -------------------------
extern "C" void kernel_launch(void* const* d_in, const int* in_sizes, int n_in,
                              void* d_out, int out_size, void* d_ws, size_t ws_size,
                              hipStream_t stream) {
  const float* x    = (const float*)d_in[0];
  const float* pos  = (const float*)d_in[1];
  const int*   idx  = (const int*)d_in[2];
  const float* W1   = (const float*)d_in[4];
  const float* b1   = (const float*)d_in[5];
  const float* W2   = (const float*)d_in[6];
  const float* b2   = (const float*)d_in[7];
  const float* Wr   = (const float*)d_in[8];
  const float* br   = (const float*)d_in[9];
  const float* ipw  = (const float*)d_in[10];
  const float* ipb  = (const float*)d_in[11];
  const float* opw  = (const float*)d_in[12];
  const float* opb  = (const float*)d_in[13];
  const float* Wm1  = (const float*)d_in[14];
  const float* bm1  = (const float*)d_in[15];
  const float* Wm2  = (const float*)d_in[16];
  const float* bm2  = (const float*)d_in[17];
  const float* g1   = (const float*)d_in[18];
  const float* be1  = (const float*)d_in[19];
  const float* g2   = (const float*)d_in[20];
  const float* be2  = (const float*)d_in[21];
  float* out = (float*)d_out;
  char* ws = (char*)d_ws;

  float4*         pos4  = (float4*)(ws + OFF_POS4);
  int*            colp  = (int*)(ws + OFF_COL);
  unsigned short* w1t   = (unsigned short*)(ws + OFF_W1T);
  unsigned short* w2t   = (unsigned short*)(ws + OFF_W2T);
  unsigned short* wrt   = (unsigned short*)(ws + OFF_WRT);
  unsigned short* wqkvt = (unsigned short*)(ws + OFF_WQKVT);
  unsigned short* woutt = (unsigned short*)(ws + OFF_WOUTT);
  unsigned short* wm1t  = (unsigned short*)(ws + OFF_WM1T);
  unsigned short* wm2t  = (unsigned short*)(ws + OFF_WM2T);
  float4* sposp = (float4*)(ws + OFF_SPOS);
  int*    ccnt  = (int*)(ws + OFF_CELLCNT);
  int2*   cdesc = (int2*)(ws + OFF_CELLDSC);
  int*    cfill = (int*)(ws + OFF_FILL);
  unsigned short* pou = (unsigned short*)(ws + OFF_PO);
  float*  plp   = (float*)(ws + OFF_PL);
  float* aggp  = (float*)(ws + OFF_AGG);
  float* xt0p  = (float*)(ws + OFF_XT0);
  unsigned short* qkvb = (unsigned short*)(ws + OFF_QKV);
  float* xt1p  = (float*)(ws + OFF_XT1);
  float* sbias = (float*)(ws + OFF_SBIAS);

  zero_k<<<128, 256, 0, stream>>>(ccnt);
  prep_k<<<946, 256, 0, stream>>>(pos, W1, W2, Wr, ipw, ipb, opw, Wm1, Wm2,
                                  pos4, w1t, w2t, wrt, wqkvt, woutt, wm1t, wm2t,
                                  ccnt, sbias);
  prefix_k<<<1, 1024, 0, stream>>>(ccnt, cdesc, cfill);
  scatter_k<<<128, 256, 0, stream>>>(pos4, cfill, sposp);
  knn_k<<<1024, 256, 0, stream>>>(sposp, cdesc, pos4, idx, colp,
                                  out + 524288, out + 536576);
  conv_k<<<1024, 256, 0, stream>>>(x, pos4, idx, colp, w1t, b1, w2t, b2, aggp);
  gemm_k<256, 128, false, false, false><<<dim3(64, 2), 256, 0, stream>>>(aggp, wrt, br, nullptr, xt0p);
  gemm_k<128, 384, false, false, true><<<dim3(64, 6), 256, 0, stream>>>(xt0p, wqkvt, sbias, nullptr, (float*)qkvb);
  attn_k<<<dim3(64, 4, 8), 256, 0, stream>>>(qkvb, pou, plp);
  gemmln2_k<128, true><<<256, 256, 0, stream>>>(nullptr, pou, plp, woutt, opb, xt0p, g1, be1, xt1p);
  mlpln_k<<<256, 256, 0, stream>>>(xt1p, wm1t, bm1, wm2t, bm2, g2, be2, out);
}

// Round 15
// 156.628 us; speedup vs baseline: 1.0731x; 1.0009x over previous
//
#include <hip/hip_runtime.h>
#include <hip/hip_bf16.h>

#define DEV static __device__ __forceinline__

typedef __attribute__((ext_vector_type(8))) short          s16x8;
typedef __attribute__((ext_vector_type(8))) unsigned short u16x8;
typedef __attribute__((ext_vector_type(4))) float          f32x4;
typedef __attribute__((ext_vector_type(4))) unsigned int   u32x4;

#define MFMA16(A,B,C) __builtin_amdgcn_mfma_f32_16x16x32_bf16((A),(B),(C),0,0,0)

DEV unsigned short f2bf(float f) {
  unsigned int u = __builtin_bit_cast(unsigned int, f);
  u += 0x7fffu + ((u >> 16) & 1u);
  return (unsigned short)(u >> 16);
}
DEV float bf2f(unsigned short u) {
  unsigned int x = ((unsigned int)u) << 16;
  return __builtin_bit_cast(float, x);
}

// 1/sqrt(32) * log2(e): fold into Q projection so softmax uses exp2 directly
#define QSCL 0.25503562201f

// ------------------------- grid params -------------------------
#define GRID_LO  (-5.0f)
#define GRID_IH  (3.2f)

DEV int cellc(float v) {
  int c = (int)floorf((v - GRID_LO) * GRID_IH);
  return min(31, max(0, c));
}

// ------------------------- ws layout -------------------------
constexpr size_t OFF_POS4  = 0;
constexpr size_t OFF_COL   = 524288;
constexpr size_t OFF_W1T   = 1048576;
constexpr size_t OFF_W2T   = OFF_W1T  + 24576;
constexpr size_t OFF_WRT   = OFF_W2T  + 65536;
constexpr size_t OFF_WQKVT = OFF_WRT  + 65536;
constexpr size_t OFF_WOUTT = OFF_WQKVT+ 98304;
constexpr size_t OFF_WM1T  = OFF_WOUTT+ 32768;
constexpr size_t OFF_WM2T  = OFF_WM1T + 65536;
constexpr size_t OFF_H     = OFF_WM2T + 65536;        // 33554432-byte shared region
// phase 1: cell structures
constexpr size_t OFF_SPOS    = OFF_H;
constexpr size_t OFF_CELLCNT = OFF_H + 524288;
constexpr size_t OFF_CELLDSC = OFF_H + 655360;
constexpr size_t OFF_FILL    = OFF_H + 917504;
// phase 2: attention partials (po bf16: 4*4096*128*2 = 4194304)
constexpr size_t OFF_PO      = OFF_H;
constexpr size_t OFF_PL      = OFF_H + 16777216;      // 262144 (f32, 4 splits)
constexpr size_t OFF_AGG   = OFF_H    + 33554432;
constexpr size_t OFF_XT0   = OFF_AGG  + 4194304;
constexpr size_t OFF_QKV   = OFF_XT0  + 2097152;
constexpr size_t OFF_ATT   = OFF_QKV  + 6291456;
constexpr size_t OFF_PRE   = OFF_ATT  + 2097152;
constexpr size_t OFF_XT1   = OFF_PRE  + 2097152;
constexpr size_t OFF_MLP1  = OFF_XT1  + 2097152;
constexpr size_t OFF_SBIAS = OFF_MLP1 + 4194304;

// ------------------------- zero cell counts -------------------------
__global__ __launch_bounds__(256) void zero_k(int* __restrict__ p) {
  p[blockIdx.x * 256 + threadIdx.x] = 0;
}

// ------------------------- prep -------------------------
__global__ __launch_bounds__(256) void prep_k(
    const float* __restrict__ pos, const float* __restrict__ W1,
    const float* __restrict__ W2, const float* __restrict__ Wr,
    const float* __restrict__ ipw, const float* __restrict__ ipb,
    const float* __restrict__ opw,
    const float* __restrict__ Wm1, const float* __restrict__ Wm2,
    float4* __restrict__ pos4, unsigned short* __restrict__ w1t,
    unsigned short* __restrict__ w2t, unsigned short* __restrict__ wrt,
    unsigned short* __restrict__ wqkvt, unsigned short* __restrict__ woutt,
    unsigned short* __restrict__ wm1t, unsigned short* __restrict__ wm2t,
    int* __restrict__ cellcnt, float* __restrict__ sbias) {
  int T = blockIdx.x * 256 + threadIdx.x;
  if (T < 32768) {
    float px = pos[T*3], py = pos[T*3+1], pz = pos[T*3+2];
    pos4[T] = make_float4(px, py, pz, 0.f);
    int cid = (cellc(pz)*32 + cellc(py))*32 + cellc(px);
    atomicAdd(&cellcnt[cid], 1);
    return;
  }
  T -= 32768;
  if (T < 128*96)  { int n=T/96,  k=T%96;  w1t[T]  = f2bf(k < 67 ? W1[k*128+n] : 0.f); return; }
  T -= 128*96;
  if (T < 256*128) { int n=T/128, k=T%128; w2t[T]  = f2bf(W2[k*256+n]);  return; }
  T -= 256*128;
  if (T < 128*256) { int n=T/256, k=T%256; wrt[T]  = f2bf(Wr[k*128+n]);  return; }
  T -= 128*256;
  if (T < 384*128) { int n=T/128, k=T%128;
                     float v = ipw[k*384+n];
                     if (n < 128) v *= QSCL;
                     wqkvt[T]= f2bf(v); return; }
  T -= 384*128;
  if (T < 128*128) { int n=T/128, k=T%128; woutt[T]= f2bf(opw[k*128+n]); return; }
  T -= 128*128;
  if (T < 256*128) { int n=T/128, k=T%128; wm1t[T] = f2bf(Wm1[k*256+n]); return; }
  T -= 256*128;
  if (T < 128*256) { int n=T/256, k=T%256; wm2t[T] = f2bf(Wm2[k*128+n]); return; }
  T -= 128*256;
  if (T < 384) { sbias[T] = ipb[T] * (T < 128 ? QSCL : 1.f); return; }
}

// ------------------------- prefix over 32768 cell counts -------------------
__global__ __launch_bounds__(1024) void prefix_k(const int* __restrict__ cnt,
                                                 int2* __restrict__ desc,
                                                 int* __restrict__ fill) {
  __shared__ int wsum[16];
  const int tid = threadIdx.x, lane = tid & 63, w = tid >> 6;
  int loc[32]; int s = 0;
  #pragma unroll
  for (int i = 0; i < 32; ++i) { loc[i] = cnt[tid*32 + i]; s += loc[i]; }
  int sc = s;
  #pragma unroll
  for (int off = 1; off < 64; off <<= 1) {
    int v = __shfl_up(sc, off);
    if (lane >= off) sc += v;
  }
  if (lane == 63) wsum[w] = sc;
  __syncthreads();
  if (tid == 0) {
    int run = 0;
    #pragma unroll
    for (int i = 0; i < 16; ++i) { int v = wsum[i]; wsum[i] = run; run += v; }
  }
  __syncthreads();
  int base = wsum[w] + (sc - s);
  #pragma unroll
  for (int i = 0; i < 32; ++i) {
    int c = tid*32 + i;
    desc[c] = make_int2(base, loc[i]);
    fill[c] = base;
    base += loc[i];
  }
}

// ------------------------- scatter -------------------------
__global__ __launch_bounds__(256) void scatter_k(const float4* __restrict__ pos4,
                                                 int* __restrict__ fill,
                                                 float4* __restrict__ spos) {
  int T = blockIdx.x * 256 + threadIdx.x;
  float4 p = pos4[T];
  int cid = (cellc(p.z)*32 + cellc(p.y))*32 + cellc(p.x);
  int slot = atomicAdd(&fill[cid], 1);
  spos[slot] = make_float4(p.x, p.y, p.z, __int_as_float(T));
}

// ------------------------- KNN -------------------------
#define KNN_CAP  320
#define KNN_TRIG 192
#define KNN_KEEP 33
#define KNN_INF  3e37f

__global__ __launch_bounds__(256) void knn_k(
    const float4* __restrict__ spos, const int2* __restrict__ desc,
    const float4* __restrict__ pos4, const int* __restrict__ idx,
    int* __restrict__ col,
    float* __restrict__ outqpos, float* __restrict__ outbatch) {
  __shared__ float bufd[4][KNN_CAP];
  __shared__ int   bufi[4][KNN_CAP];
  __shared__ int   shist[4][64];
  __shared__ int2  segs[4][128];
  const int tid = threadIdx.x, lane = tid & 63, w = tid >> 6;
  const unsigned long long ltmask = (1ull << lane) - 1ull;

  const int q = blockIdx.x * 4 + w;
  const int iq = idx[q];
  const float4 qp = pos4[iq];
  const float qx = qp.x, qy = qp.y, qz = qp.z;
  const int cx0 = cellc(qx), cy0 = cellc(qy), cz0 = cellc(qz);

  float t = KNN_INF;
  int cnt = 0;

  auto compact = [&]() {
    int c_ = min(cnt, KNN_CAP);
    float vd[5]; int vi[5], bs[5]; bool okv[5];
    float dmax = 1e-30f;
    #pragma unroll
    for (int s = 0; s < 5; ++s) {
      int o2 = s*64 + lane;
      okv[s] = o2 < c_;
      vd[s] = okv[s] ? bufd[w][o2] : 0.f;
      vi[s] = okv[s] ? bufi[w][o2] : 0;
      dmax = fmaxf(dmax, vd[s]);
    }
    #pragma unroll
    for (int off = 1; off < 64; off <<= 1) dmax = fmaxf(dmax, __shfl_xor(dmax, off));
    float scale = 63.99f / dmax;
    shist[w][lane] = 0;
    #pragma unroll
    for (int s = 0; s < 5; ++s) {
      bs[s] = okv[s] ? min(63, (int)(vd[s] * scale)) : 64;
      if (okv[s]) atomicAdd(&shist[w][bs[s]], 1);
    }
    int h = shist[w][lane];
    #pragma unroll
    for (int off = 1; off < 64; off <<= 1) {
      int v = __shfl_up(h, off);
      if (lane >= off) h += v;
    }
    unsigned long long mk = __ballot(h >= KNN_KEEP);
    int E = mk ? (__ffsll((long long)mk) - 1) : 63;
    int base = 0;
    #pragma unroll
    for (int s = 0; s < 5; ++s) {
      bool keep = okv[s] && bs[s] <= E;
      unsigned long long km = __ballot(keep);
      int pp = base + (int)__popcll(km & ltmask);
      if (keep) { bufd[w][pp] = vd[s]; bufi[w][pp] = vi[s]; }
      base += (int)__popcll(km);
    }
    cnt = base;
    t = fminf(t, (float)(E + 1) / scale);
  };

  auto scan_rows = [&](int knew, int kold) {
    const int S = 2*knew + 1;
    const int NR = S*S;
    const float invS = 1.f / (float)S;
    for (int r0 = 0; r0 < NR; r0 += 64) {
      int r = r0 + lane;
      bool v = r < NR;
      int dz = (int)((float)r * invS);
      int rem = r - dz*S;
      if (rem < 0) { dz--; rem += S; } else if (rem >= S) { dz++; rem -= S; }
      int ccz = cz0 + dz - knew, ccy = cy0 + rem - knew;
      bool rowok = v && ccz >= 0 && ccz < 32 && ccy >= 0 && ccy < 32;
      bool inner = kold >= 0 && abs(dz - knew) <= kold && abs(rem - knew) <= kold;
      int cbase = (ccz*32 + ccy) * 32;
      int sL = 0, lL = 0, sR = 0, lR = 0;
      if (rowok) {
        int xa = max(cx0 - knew, 0);
        int xb = inner ? (cx0 - kold - 1) : min(cx0 + knew, 31);
        if (xa <= xb) {
          int2 d0 = desc[cbase + xa];
          int2 d1 = desc[cbase + xb];
          sL = d0.x; lL = d1.x + d1.y - d0.x;
        }
        if (inner) {
          int xa2 = cx0 + kold + 1, xb2 = min(cx0 + knew, 31);
          if (xa2 <= xb2 && xa2 >= 0) {
            int2 d0 = desc[cbase + xa2];
            int2 d1 = desc[cbase + xb2];
            sR = d0.x; lR = d1.x + d1.y - d0.x;
          }
        }
      }
      int cumL = lL;
      #pragma unroll
      for (int off = 1; off < 64; off <<= 1) {
        int vv = __shfl_up(cumL, off);
        if (lane >= off) cumL += vv;
      }
      int sumL = __shfl(cumL, 63);
      int cumR = lR;
      #pragma unroll
      for (int off = 1; off < 64; off <<= 1) {
        int vv = __shfl_up(cumR, off);
        if (lane >= off) cumR += vv;
      }
      int sumR = __shfl(cumR, 63);
      segs[w][lane]      = make_int2(sL, cumL - lL);
      segs[w][64 + lane] = make_int2(sR, sumL + cumR - lR);
      const int total = sumL + sumR;

      for (int b = 0; b < total; b += 320) {
        float d2v[5]; int piv[5]; bool hv[5];
        #pragma unroll
        for (int s5 = 0; s5 < 5; ++s5) {
          int p = b + s5*64 + lane;
          bool act = p < total;
          hv[s5] = false; d2v[s5] = 0.f; piv[s5] = 0;
          if (act) {
            int lo = 0;
            #pragma unroll
            for (int st = 64; st > 0; st >>= 1)
              if (segs[w][lo + st].y <= p) lo += st;
            int2 e = segs[w][lo];
            float4 pt = spos[e.x + (p - e.y)];
            float ddx = qx-pt.x, ddy = qy-pt.y, ddz = qz-pt.z;
            float d2 = ddx*ddx + ddy*ddy + ddz*ddz;
            d2v[s5] = d2; piv[s5] = __float_as_int(pt.w);
            hv[s5] = d2 < t;
          }
        }
        #pragma unroll
        for (int s5 = 0; s5 < 5; ++s5) {
          unsigned long long hm = __ballot(hv[s5]);
          if (hm) {
            int pp = cnt + (int)__popcll(hm & ltmask);
            if (hv[s5] && pp < KNN_CAP) { bufd[w][pp] = d2v[s5]; bufi[w][pp] = piv[s5]; }
            cnt += (int)__popcll(hm);
            if (cnt >= KNN_TRIG) compact();
          }
        }
      }
    }
  };

  auto bound32 = [&]() -> float {
    int c_ = min(cnt, KNN_CAP);
    float vv[5]; bool okv[5];
    float dmax = 1e-30f;
    #pragma unroll
    for (int s = 0; s < 5; ++s) {
      int o2 = s*64 + lane;
      okv[s] = o2 < c_;
      vv[s] = okv[s] ? bufd[w][o2] : 0.f;
      dmax = fmaxf(dmax, vv[s]);
    }
    #pragma unroll
    for (int off = 1; off < 64; off <<= 1) dmax = fmaxf(dmax, __shfl_xor(dmax, off));
    float scale = 63.99f / dmax;
    shist[w][lane] = 0;
    #pragma unroll
    for (int s = 0; s < 5; ++s)
      if (okv[s]) atomicAdd(&shist[w][min(63, (int)(vv[s] * scale))], 1);
    int h = shist[w][lane];
    #pragma unroll
    for (int off = 1; off < 64; off <<= 1) {
      int v = __shfl_up(h, off);
      if (lane >= off) h += v;
    }
    unsigned long long m = __ballot(h >= 32);
    int E = m ? (__ffsll((long long)m) - 1) : 63;
    return (float)(E + 1) / scale;
  };

  int kcur = 1;
  scan_rows(1, -1);
  for (int it = 0; it < 64; ++it) {
    if (cnt >= 32) {
      float t32u = bound32();
      t = fminf(t, t32u);
      int kneed = (int)(__builtin_sqrtf(t32u) * GRID_IH) + 1;
      if (kneed <= kcur || kcur >= 31) break;
      int knew = min(kneed, 31);
      scan_rows(knew, kcur);
      kcur = knew;
    } else {
      if (kcur >= 31) break;
      int knew = min(kcur + (cnt == 0 ? 2 : 1), 31);
      scan_rows(knew, kcur);
      kcur = knew;
    }
  }

  // ---- final exact top-32 ----
  {
    int c_ = min(cnt, KNN_CAP);
    float vd[5]; int vi[5], bs[5]; bool okf[5];
    float dmax = 1e-30f;
    #pragma unroll
    for (int s = 0; s < 5; ++s) {
      int o2 = s*64 + lane;
      okf[s] = o2 < c_;
      vd[s] = okf[s] ? bufd[w][o2] : KNN_INF;
      vi[s] = okf[s] ? bufi[w][o2] : 0;
      dmax = fmaxf(dmax, okf[s] ? vd[s] : 0.f);
    }
    #pragma unroll
    for (int off = 1; off < 64; off <<= 1) dmax = fmaxf(dmax, __shfl_xor(dmax, off));
    float sc64 = 63.99f / dmax;
    shist[w][lane] = 0;
    #pragma unroll
    for (int s = 0; s < 5; ++s) {
      bs[s] = okf[s] ? min(63, (int)(vd[s] * sc64)) : 64;
      if (okf[s]) atomicAdd(&shist[w][bs[s]], 1);
    }
    int h = shist[w][lane];
    #pragma unroll
    for (int off = 1; off < 64; off <<= 1) {
      int v = __shfl_up(h, off);
      if (lane >= off) h += v;
    }
    unsigned long long m = __ballot(h >= 32);
    int E = m ? (__ffsll((long long)m) - 1) : 63;
    int c0 = (E > 0) ? __shfl(h, E - 1) : 0;
    int base = 0;
    #pragma unroll
    for (int s = 0; s < 5; ++s) {
      bool wr = okf[s] && (bs[s] < E);
      unsigned long long km = __ballot(wr);
      int pp = base + (int)__popcll(km & ltmask);
      if (wr) col[q*32 + pp] = vi[s];
      base += (int)__popcll(km);
    }
    #pragma unroll
    for (int s = 0; s < 5; ++s)
      if (!(okf[s] && bs[s] == E)) vd[s] = KNN_INF;
    int r = 32 - c0;
    #pragma unroll 1
    for (int kk = 0; kk < r; ++kk) {
      float bd = vd[0]; int bi = vi[0]; int bc = lane*8;
      #pragma unroll
      for (int s = 1; s < 5; ++s)
        if (vd[s] < bd) { bd = vd[s]; bi = vi[s]; bc = lane*8 + s; }
      #pragma unroll
      for (int off = 1; off < 64; off <<= 1) {
        float od = __shfl_xor(bd, off);
        int   oi = __shfl_xor(bi, off);
        int   oc = __shfl_xor(bc, off);
        if (od < bd || (od == bd && oc < bc)) { bd = od; bi = oi; bc = oc; }
      }
      if ((bc >> 3) == lane) {
        int sl = bc & 7;
        #pragma unroll
        for (int s = 0; s < 5; ++s) if (sl == s) vd[s] = KNN_INF;
      }
      if (lane == 0) col[q*32 + c0 + kk] = bi;
    }
  }
  if (lane == 0) {
    outqpos[q*3+0] = qx; outqpos[q*3+1] = qy; outqpos[q*3+2] = qz;
    outbatch[q] = 0.f;
  }
}

// ------------------------- fused conv (round-13 structure) -----------------
#define LA1(r,c) S[(r)*104 + (c)]
#define LB1(r,c) S[13312 + (r)*104 + (c)]
#define HB(r,c)  S[(r)*136 + (c)]
#define W2C(r,c) S[17408 + (r)*136 + (c)]

__global__ __launch_bounds__(256) void conv_k(
    const float* __restrict__ x, const float4* __restrict__ pos4,
    const int* __restrict__ idx, const int* __restrict__ col,
    const unsigned short* __restrict__ w1t, const float* __restrict__ b1,
    const unsigned short* __restrict__ w2t, const float* __restrict__ b2,
    float* __restrict__ agg) {
  __shared__ __align__(16) unsigned short S[26624];
  __shared__ int   sci[128];
  __shared__ float sqp[4][3];
  const int tid = threadIdx.x, lane = tid & 63, w = tid >> 6;
  const int wm = w >> 1, wn = w & 1;
  const int m0 = blockIdx.x * 4;

  if (tid < 128) sci[tid] = col[m0*32 + tid];
  if (tid >= 128 && tid < 132) {
    int m = m0 + tid - 128;
    float4 p = pos4[idx[m]];
    sqp[tid-128][0] = p.x; sqp[tid-128][1] = p.y; sqp[tid-128][2] = p.z;
  }
  #pragma unroll
  for (int rnd = 0; rnd < 6; ++rnd) {
    int e = (rnd*256 + tid) * 8;
    int n = e / 96, k = e % 96;
    *(u16x8*)&LB1(n, k) = *(const u16x8*)&w1t[e];
  }
  __syncthreads();

  {
    int r = tid >> 1, half = tid & 1;
    int ci = sci[r];
    const float* src = x + (size_t)ci*64 + half*32;
    #pragma unroll
    for (int c = 0; c < 4; ++c) {
      float4 va = ((const float4*)src)[c*2], vb = ((const float4*)src)[c*2+1];
      u16x8 v;
      v[0]=f2bf(va.x); v[1]=f2bf(va.y); v[2]=f2bf(va.z); v[3]=f2bf(va.w);
      v[4]=f2bf(vb.x); v[5]=f2bf(vb.y); v[6]=f2bf(vb.z); v[7]=f2bf(vb.w);
      *(u16x8*)&LA1(r, half*32 + c*8) = v;
    }
  }
  if (tid < 128) {
    int r = tid, g = r >> 5;
    float4 p = pos4[sci[r]];
    u16x8 z;
    #pragma unroll
    for (int e = 0; e < 8; ++e) z[e] = 0;
    u16x8 v0 = z;
    v0[0] = f2bf(p.x - sqp[g][0]); v0[1] = f2bf(p.y - sqp[g][1]); v0[2] = f2bf(p.z - sqp[g][2]);
    *(u16x8*)&LA1(r, 64) = v0;
    #pragma unroll
    for (int c = 1; c < 5; ++c) *(u16x8*)&LA1(r, 64 + c*8) = z;
  }
  __syncthreads();

  f32x4 acc[4][4];
  #pragma unroll
  for (int nf = 0; nf < 4; ++nf) {
    float bv = b1[wn*64 + nf*16 + (lane & 15)];
    #pragma unroll
    for (int mf = 0; mf < 4; ++mf) acc[mf][nf] = f32x4{bv, bv, bv, bv};
  }
  #pragma unroll
  for (int kc = 0; kc < 3; ++kc) {
    s16x8 af[4], bf_[4];
    #pragma unroll
    for (int mf = 0; mf < 4; ++mf)
      af[mf] = *(const s16x8*)&LA1(wm*64 + mf*16 + (lane&15), kc*32 + (lane>>4)*8);
    #pragma unroll
    for (int nf = 0; nf < 4; ++nf)
      bf_[nf] = *(const s16x8*)&LB1(wn*64 + nf*16 + (lane&15), kc*32 + (lane>>4)*8);
    #pragma unroll
    for (int mf = 0; mf < 4; ++mf)
      #pragma unroll
      for (int nf = 0; nf < 4; ++nf)
        acc[mf][nf] = MFMA16(af[mf], bf_[nf], acc[mf][nf]);
  }
  __syncthreads();

  #pragma unroll
  for (int mf = 0; mf < 4; ++mf)
    #pragma unroll
    for (int nf = 0; nf < 4; ++nf)
      #pragma unroll
      for (int j = 0; j < 4; ++j) {
        int rloc = wm*64 + mf*16 + ((lane>>4)<<2) + j;
        int cloc = wn*64 + nf*16 + (lane & 15);
        HB(rloc, cloc) = f2bf(fmaxf(acc[mf][nf][j], 0.f));
      }
  {
    int r2 = tid >> 2, kq = (tid & 3) * 32;
    const unsigned short* src = w2t + (size_t)r2*128 + kq;
    #pragma unroll
    for (int c = 0; c < 4; ++c)
      *(u16x8*)&W2C(r2, kq + c*8) = *(const u16x8*)&src[c*8];
  }
  __syncthreads();

  #pragma unroll 1
  for (int nc = 0; nc < 4; ++nc) {
    f32x4 acc2[2][4];
    #pragma unroll
    for (int nf = 0; nf < 4; ++nf) {
      float bv = b2[nc*64 + nf*16 + (lane & 15)];
      acc2[0][nf] = f32x4{bv, bv, bv, bv};
      acc2[1][nf] = f32x4{bv, bv, bv, bv};
    }
    #pragma unroll
    for (int ks = 0; ks < 4; ++ks) {
      s16x8 af[2], bf_[4];
      #pragma unroll
      for (int mf = 0; mf < 2; ++mf)
        af[mf] = *(const s16x8*)&HB(w*32 + mf*16 + (lane&15), ks*32 + (lane>>4)*8);
      #pragma unroll
      for (int nf = 0; nf < 4; ++nf)
        bf_[nf] = *(const s16x8*)&W2C(nf*16 + (lane&15), ks*32 + (lane>>4)*8);
      #pragma unroll
      for (int mf = 0; mf < 2; ++mf)
        #pragma unroll
        for (int nf = 0; nf < 4; ++nf)
          acc2[mf][nf] = MFMA16(af[mf], bf_[nf], acc2[mf][nf]);
    }
    #pragma unroll
    for (int nf = 0; nf < 4; ++nf) {
      float mx = acc2[0][nf][0];
      #pragma unroll
      for (int j = 1; j < 4; ++j) mx = fmaxf(mx, acc2[0][nf][j]);
      #pragma unroll
      for (int j = 0; j < 4; ++j) mx = fmaxf(mx, acc2[1][nf][j]);
      mx = fmaxf(mx, __shfl_xor(mx, 16));
      mx = fmaxf(mx, __shfl_xor(mx, 32));
      if (lane < 16) agg[(size_t)(m0 + w)*256 + nc*64 + nf*16 + lane] = mx;
    }
    if (nc < 3) {
      __syncthreads();
      int r2 = tid >> 2, kq = (tid & 3) * 32;
      const unsigned short* src = w2t + (size_t)((nc+1)*64 + r2)*128 + kq;
      #pragma unroll
      for (int c = 0; c < 4; ++c)
        *(u16x8*)&W2C(r2, kq + c*8) = *(const u16x8*)&src[c*8];
      __syncthreads();
    }
  }
}

// ------------------------- 64x64-tile GEMM -------------------------
template<int KFULL, int NFULL, bool RELU, bool HAS_RES, bool OBF16>
__global__ __launch_bounds__(256) void gemm_k(
    const float* __restrict__ A, const unsigned short* __restrict__ Bt,
    const float* __restrict__ bias, const float* __restrict__ res,
    float* __restrict__ out) {
  __shared__ unsigned short lA[64][72];
  __shared__ unsigned short lB[64][72];
  const int tid = threadIdx.x, lane = tid & 63, w = tid >> 6;
  const int m0 = blockIdx.x * 64, n0 = blockIdx.y * 64;

  f32x4 acc[4];
  #pragma unroll
  for (int nf = 0; nf < 4; ++nf) {
    float bv = bias[n0 + nf*16 + (lane & 15)];
    acc[nf] = f32x4{bv, bv, bv, bv};
  }

  for (int kb = 0; kb < KFULL; kb += 64) {
    __syncthreads();
    {
      int r = tid >> 2, kq = (tid & 3) * 16;
      const float* src = A + (size_t)(m0 + r)*KFULL + kb + kq;
      #pragma unroll
      for (int c = 0; c < 2; ++c) {
        float4 va = ((const float4*)src)[c*2], vb = ((const float4*)src)[c*2+1];
        u16x8 v;
        v[0]=f2bf(va.x); v[1]=f2bf(va.y); v[2]=f2bf(va.z); v[3]=f2bf(va.w);
        v[4]=f2bf(vb.x); v[5]=f2bf(vb.y); v[6]=f2bf(vb.z); v[7]=f2bf(vb.w);
        *(u16x8*)&lA[r][kq + c*8] = v;
      }
      const unsigned short* srcb = Bt + (size_t)(n0 + r)*KFULL + kb + kq;
      #pragma unroll
      for (int c = 0; c < 2; ++c)
        *(u16x8*)&lB[r][kq + c*8] = *(const u16x8*)&srcb[c*8];
    }
    __syncthreads();
    #pragma unroll
    for (int ks = 0; ks < 2; ++ks) {
      s16x8 af = *(const s16x8*)&lA[w*16 + (lane&15)][ks*32 + (lane>>4)*8];
      s16x8 bf_[4];
      #pragma unroll
      for (int nf = 0; nf < 4; ++nf)
        bf_[nf] = *(const s16x8*)&lB[nf*16 + (lane&15)][ks*32 + (lane>>4)*8];
      #pragma unroll
      for (int nf = 0; nf < 4; ++nf)
        acc[nf] = MFMA16(af, bf_[nf], acc[nf]);
    }
  }
  #pragma unroll
  for (int nf = 0; nf < 4; ++nf)
    #pragma unroll
    for (int j = 0; j < 4; ++j) {
      int row = m0 + w*16 + ((lane>>4)<<2) + j;
      int colg = n0 + nf*16 + (lane & 15);
      float v = acc[nf][j];
      if (HAS_RES) v += res[(size_t)row*NFULL + colg];
      if (RELU)    v = fmaxf(v, 0.f);
      if (OBF16) ((unsigned short*)out)[(size_t)row*NFULL + colg] = f2bf(v);
      else       out[(size_t)row*NFULL + colg] = v;
    }
}

// ------------------------- fused out_proj + residual + LN (N-split) --------
template<int KFULL, bool COMBINE>
__global__ __launch_bounds__(256) void gemmln2_k(
    const float* __restrict__ A,
    const unsigned short* __restrict__ po, const float* __restrict__ pl,
    const unsigned short* __restrict__ Bt, const float* __restrict__ bias,
    const float* __restrict__ res,
    const float* __restrict__ gam, const float* __restrict__ bet,
    float* __restrict__ out) {
  constexpr int KP = KFULL + 8;
  __shared__ __align__(16) unsigned short lA[16 * KP];
  __shared__ float vout[16 * 132];
  const int tid = threadIdx.x, lane = tid & 63, w = tid >> 6;
  const int g = lane >> 4, ln_ = lane & 15;
  const int m0 = blockIdx.x * 16;

  {
    int r = tid >> 4, seg = tid & 15;
    int row = m0 + r;
    if (COMBINE) {
      int hh = seg >> 2;
      float lsum = 0.f;
      #pragma unroll
      for (int s = 0; s < 4; ++s) lsum += pl[((s*4 + hh) << 12) + row];
      float inv = 1.f / lsum;
      float a[8] = {0,0,0,0,0,0,0,0};
      #pragma unroll
      for (int s = 0; s < 4; ++s) {
        u16x8 v = *(const u16x8*)&po[((size_t)s*4096 + row)*128 + seg*8];
        #pragma unroll
        for (int e = 0; e < 8; ++e) a[e] += bf2f(v[e]);
      }
      u16x8 ov;
      #pragma unroll
      for (int e = 0; e < 8; ++e) ov[e] = f2bf(a[e] * inv);
      *(u16x8*)&lA[r*KP + seg*8] = ov;
    } else {
      const float* src = A + (size_t)row*KFULL + seg*(KFULL/16);
      #pragma unroll
      for (int c = 0; c < KFULL/128; ++c) {
        float4 va = ((const float4*)src)[c*2], vb = ((const float4*)src)[c*2+1];
        u16x8 v;
        v[0]=f2bf(va.x); v[1]=f2bf(va.y); v[2]=f2bf(va.z); v[3]=f2bf(va.w);
        v[4]=f2bf(vb.x); v[5]=f2bf(vb.y); v[6]=f2bf(vb.z); v[7]=f2bf(vb.w);
        *(u16x8*)&lA[r*KP + seg*(KFULL/16) + c*8] = v;
      }
    }
  }
  __syncthreads();

  const int n0 = w * 32;
  f32x4 acc[2];
  #pragma unroll
  for (int nf = 0; nf < 2; ++nf) {
    float bv = bias[n0 + nf*16 + ln_];
    acc[nf] = f32x4{bv, bv, bv, bv};
  }
  #pragma unroll
  for (int ks = 0; ks < KFULL/32; ++ks) {
    s16x8 af = *(const s16x8*)&lA[ln_*KP + ks*32 + g*8];
    #pragma unroll
    for (int nf = 0; nf < 2; ++nf) {
      s16x8 bf_ = *(const s16x8*)&Bt[(size_t)(n0 + nf*16 + ln_)*KFULL + ks*32 + g*8];
      acc[nf] = MFMA16(af, bf_, acc[nf]);
    }
  }
  #pragma unroll
  for (int nf = 0; nf < 2; ++nf)
    #pragma unroll
    for (int j = 0; j < 4; ++j)
      vout[(g*4 + j)*132 + n0 + nf*16 + ln_] = acc[nf][j];
  __syncthreads();

  {
    int r = tid >> 4, seg = tid & 15;
    int row = m0 + r;
    float v[8]; float sm = 0.f;
    #pragma unroll
    for (int nf = 0; nf < 8; ++nf) {
      int c = nf*16 + seg;
      float xx = vout[r*132 + c] + res[(size_t)row*128 + c];
      v[nf] = xx; sm += xx;
    }
    sm += __shfl_xor(sm, 1); sm += __shfl_xor(sm, 2);
    sm += __shfl_xor(sm, 4); sm += __shfl_xor(sm, 8);
    float mu = sm * 0.0078125f;
    float qv = 0.f;
    #pragma unroll
    for (int nf = 0; nf < 8; ++nf) { float d = v[nf] - mu; qv += d*d; }
    qv += __shfl_xor(qv, 1); qv += __shfl_xor(qv, 2);
    qv += __shfl_xor(qv, 4); qv += __shfl_xor(qv, 8);
    float rr = rsqrtf(qv * 0.0078125f + 1e-5f);
    #pragma unroll
    for (int nf = 0; nf < 8; ++nf) {
      int c = nf*16 + seg;
      out[(size_t)row*128 + c] = (v[nf] - mu) * rr * gam[c] + bet[c];
    }
  }
}

// ------------------------- fused MLP (mlp1+relu+mlp2+res+LN) ---------------
__global__ __launch_bounds__(256) void mlpln_k(
    const float* __restrict__ xt1,
    const unsigned short* __restrict__ wm1t, const float* __restrict__ bm1,
    const unsigned short* __restrict__ wm2t, const float* __restrict__ bm2,
    const float* __restrict__ gam, const float* __restrict__ bet,
    float* __restrict__ out) {
  __shared__ __align__(16) unsigned short lA[16 * 136];
  __shared__ __align__(16) unsigned short lH[16 * 264];
  __shared__ float vout[16 * 132];
  const int tid = threadIdx.x, lane = tid & 63, w = tid >> 6;
  const int g = lane >> 4, ln_ = lane & 15;
  const int m0 = blockIdx.x * 16;

  {
    int r = tid >> 4, seg = tid & 15;
    const float* src = xt1 + (size_t)(m0 + r)*128 + seg*8;
    float4 va = ((const float4*)src)[0], vb = ((const float4*)src)[1];
    u16x8 v;
    v[0]=f2bf(va.x); v[1]=f2bf(va.y); v[2]=f2bf(va.z); v[3]=f2bf(va.w);
    v[4]=f2bf(vb.x); v[5]=f2bf(vb.y); v[6]=f2bf(vb.z); v[7]=f2bf(vb.w);
    *(u16x8*)&lA[r*136 + seg*8] = v;
  }
  __syncthreads();

  {
    const int n0 = w * 64;
    f32x4 acc1[4];
    #pragma unroll
    for (int nf = 0; nf < 4; ++nf) {
      float bv = bm1[n0 + nf*16 + ln_];
      acc1[nf] = f32x4{bv, bv, bv, bv};
    }
    #pragma unroll
    for (int ks = 0; ks < 4; ++ks) {
      s16x8 af = *(const s16x8*)&lA[ln_*136 + ks*32 + g*8];
      #pragma unroll
      for (int nf = 0; nf < 4; ++nf) {
        s16x8 bf_ = *(const s16x8*)&wm1t[(size_t)(n0 + nf*16 + ln_)*128 + ks*32 + g*8];
        acc1[nf] = MFMA16(af, bf_, acc1[nf]);
      }
    }
    #pragma unroll
    for (int nf = 0; nf < 4; ++nf)
      #pragma unroll
      for (int j = 0; j < 4; ++j)
        lH[(g*4 + j)*264 + n0 + nf*16 + ln_] = f2bf(fmaxf(acc1[nf][j], 0.f));
  }
  __syncthreads();

  {
    const int n0 = w * 32;
    f32x4 acc2[2];
    #pragma unroll
    for (int nf = 0; nf < 2; ++nf) {
      float bv = bm2[n0 + nf*16 + ln_];
      acc2[nf] = f32x4{bv, bv, bv, bv};
    }
    #pragma unroll
    for (int ks = 0; ks < 8; ++ks) {
      s16x8 af = *(const s16x8*)&lH[ln_*264 + ks*32 + g*8];
      #pragma unroll
      for (int nf = 0; nf < 2; ++nf) {
        s16x8 bf_ = *(const s16x8*)&wm2t[(size_t)(n0 + nf*16 + ln_)*256 + ks*32 + g*8];
        acc2[nf] = MFMA16(af, bf_, acc2[nf]);
      }
    }
    #pragma unroll
    for (int nf = 0; nf < 2; ++nf)
      #pragma unroll
      for (int j = 0; j < 4; ++j)
        vout[(g*4 + j)*132 + n0 + nf*16 + ln_] = acc2[nf][j];
  }
  __syncthreads();

  {
    int r = tid >> 4, seg = tid & 15;
    int row = m0 + r;
    float v[8]; float sm = 0.f;
    #pragma unroll
    for (int nf = 0; nf < 8; ++nf) {
      int c = nf*16 + seg;
      float xx = vout[r*132 + c] + xt1[(size_t)row*128 + c];
      v[nf] = xx; sm += xx;
    }
    sm += __shfl_xor(sm, 1); sm += __shfl_xor(sm, 2);
    sm += __shfl_xor(sm, 4); sm += __shfl_xor(sm, 8);
    float mu = sm * 0.0078125f;
    float qv = 0.f;
    #pragma unroll
    for (int nf = 0; nf < 8; ++nf) { float d = v[nf] - mu; qv += d*d; }
    qv += __shfl_xor(qv, 1); qv += __shfl_xor(qv, 2);
    qv += __shfl_xor(qv, 4); qv += __shfl_xor(qv, 8);
    float rr = rsqrtf(qv * 0.0078125f + 1e-5f);
    #pragma unroll
    for (int nf = 0; nf < 8; ++nf) {
      int c = nf*16 + seg;
      out[(size_t)row*128 + c] = (v[nf] - mu) * rr * gam[c] + bet[c];
    }
  }
}

// ------------------------- flash attention (swapped-QK, no-max, KV-split 4) -
__global__ __launch_bounds__(256) void attn_k(
    const unsigned short* __restrict__ qkvb,
    unsigned short* __restrict__ po, float* __restrict__ pl) {
  __shared__ unsigned short lK[128][40];
  __shared__ unsigned short lV[32][136];
  const int tid = threadIdx.x, lane = tid & 63, w = tid >> 6;
  const int hh = blockIdx.y, sp = blockIdx.z;
  const int qr = blockIdx.x * 64 + w * 16;
  const int g = lane >> 4, q = lane & 15;

  s16x8 qf = *(const s16x8*)&qkvb[(size_t)(qr + q)*384 + hh*32 + g*8];

  f32x4 o[2];
  o[0] = f32x4{0.f,0.f,0.f,0.f}; o[1] = f32x4{0.f,0.f,0.f,0.f};
  float lrun = 0.f;

  const int srcA = q | ((2*(g & 1)) << 4);
  const int srcB = srcA + 16;
  const bool hi = (g >> 1) != 0;

  for (int kt = sp*8; kt < sp*8 + 8; ++kt) {
    const int k0 = kt * 128;
    __syncthreads();
    {
      int key = tid >> 1, d0 = (tid & 1) * 16;
      const unsigned short* src = qkvb + (size_t)(k0 + key)*384 + 128 + hh*32 + d0;
      *(u16x8*)&lK[key][d0]     = *(const u16x8*)&src[0];
      *(u16x8*)&lK[key][d0 + 8] = *(const u16x8*)&src[8];
    }
    {
      int kp = tid & 63, gg = tid >> 6;
      const unsigned short* s0 = qkvb + (size_t)(k0 + 2*kp)*384 + 256 + hh*32 + gg*8;
      u16x8 e0 = *(const u16x8*)s0;
      u16x8 e1 = *(const u16x8*)(s0 + 384);
      #pragma unroll
      for (int d = 0; d < 8; ++d) {
        unsigned int pkk = (unsigned int)e0[d] | ((unsigned int)e1[d] << 16);
        *(unsigned int*)&lV[gg*8 + d][2*kp] = pkk;
      }
    }
    __syncthreads();

    unsigned int pk[8][2];
    float ps = 0.f;
    #pragma unroll
    for (int nf = 0; nf < 8; ++nf) {
      s16x8 kf = *(const s16x8*)&lK[nf*16 + q][g*8];
      f32x4 c = MFMA16(kf, qf, (f32x4{0.f,0.f,0.f,0.f}));
      float p0 = exp2f(c[0]), p1 = exp2f(c[1]);
      float p2 = exp2f(c[2]), p3 = exp2f(c[3]);
      ps += (p0 + p1) + (p2 + p3);
      unsigned int u0 = __builtin_bit_cast(unsigned int, p0) + 0x8000u;
      unsigned int u1 = __builtin_bit_cast(unsigned int, p1) + 0x8000u;
      unsigned int u2 = __builtin_bit_cast(unsigned int, p2) + 0x8000u;
      unsigned int u3 = __builtin_bit_cast(unsigned int, p3) + 0x8000u;
      pk[nf][0] = (u0 >> 16) | (u1 & 0xffff0000u);
      pk[nf][1] = (u2 >> 16) | (u3 & 0xffff0000u);
    }
    ps += __shfl_xor(ps, 16);
    ps += __shfl_xor(ps, 32);
    lrun += ps;

    #pragma unroll
    for (int kc = 0; kc < 4; ++kc) {
      unsigned int a0 = (unsigned int)__shfl((int)pk[2*kc][0],   srcA);
      unsigned int b0 = (unsigned int)__shfl((int)pk[2*kc+1][0], srcA);
      unsigned int a1 = (unsigned int)__shfl((int)pk[2*kc][1],   srcA);
      unsigned int b1 = (unsigned int)__shfl((int)pk[2*kc+1][1], srcA);
      unsigned int a2 = (unsigned int)__shfl((int)pk[2*kc][0],   srcB);
      unsigned int b2 = (unsigned int)__shfl((int)pk[2*kc+1][0], srcB);
      unsigned int a3 = (unsigned int)__shfl((int)pk[2*kc][1],   srcB);
      unsigned int b3 = (unsigned int)__shfl((int)pk[2*kc+1][1], srcB);
      u32x4 wv;
      wv[0] = hi ? b0 : a0; wv[1] = hi ? b1 : a1;
      wv[2] = hi ? b2 : a2; wv[3] = hi ? b3 : a3;
      s16x8 pa = __builtin_bit_cast(s16x8, wv);
      #pragma unroll
      for (int df = 0; df < 2; ++df) {
        s16x8 vf = *(const s16x8*)&lV[df*16 + q][kc*32 + g*8];
        o[df] = MFMA16(pa, vf, o[df]);
      }
    }
  }
  #pragma unroll
  for (int df = 0; df < 2; ++df)
    #pragma unroll
    for (int j = 0; j < 4; ++j) {
      int row = qr + g*4 + j;
      po[((size_t)sp*4096 + row)*128 + hh*32 + df*16 + q] = f2bf(o[df][j]);
    }
  if (lane < 16)
    pl[((sp*4 + hh) << 12) + qr + lane] = lrun;
}

// ------------------------- launch -------------------------
extern "C" void kernel_launch(void* const* d_in, const int* in_sizes, int n_in,
                              void* d_out, int out_size, void* d_ws, size_t ws_size,
                              hipStream_t stream) {
  const float* x    = (const float*)d_in[0];
  const float* pos  = (const float*)d_in[1];
  const int*   idx  = (const int*)d_in[2];
  const float* W1   = (const float*)d_in[4];
  const float* b1   = (const float*)d_in[5];
  const float* W2   = (const float*)d_in[6];
  const float* b2   = (const float*)d_in[7];
  const float* Wr   = (const float*)d_in[8];
  const float* br   = (const float*)d_in[9];
  const float* ipw  = (const float*)d_in[10];
  const float* ipb  = (const float*)d_in[11];
  const float* opw  = (const float*)d_in[12];
  const float* opb  = (const float*)d_in[13];
  const float* Wm1  = (const float*)d_in[14];
  const float* bm1  = (const float*)d_in[15];
  const float* Wm2  = (const float*)d_in[16];
  const float* bm2  = (const float*)d_in[17];
  const float* g1   = (const float*)d_in[18];
  const float* be1  = (const float*)d_in[19];
  const float* g2   = (const float*)d_in[20];
  const float* be2  = (const float*)d_in[21];
  float* out = (float*)d_out;
  char* ws = (char*)d_ws;

  float4*         pos4  = (float4*)(ws + OFF_POS4);
  int*            colp  = (int*)(ws + OFF_COL);
  unsigned short* w1t   = (unsigned short*)(ws + OFF_W1T);
  unsigned short* w2t   = (unsigned short*)(ws + OFF_W2T);
  unsigned short* wrt   = (unsigned short*)(ws + OFF_WRT);
  unsigned short* wqkvt = (unsigned short*)(ws + OFF_WQKVT);
  unsigned short* woutt = (unsigned short*)(ws + OFF_WOUTT);
  unsigned short* wm1t  = (unsigned short*)(ws + OFF_WM1T);
  unsigned short* wm2t  = (unsigned short*)(ws + OFF_WM2T);
  float4* sposp = (float4*)(ws + OFF_SPOS);
  int*    ccnt  = (int*)(ws + OFF_CELLCNT);
  int2*   cdesc = (int2*)(ws + OFF_CELLDSC);
  int*    cfill = (int*)(ws + OFF_FILL);
  unsigned short* pou = (unsigned short*)(ws + OFF_PO);
  float*  plp   = (float*)(ws + OFF_PL);
  float* aggp  = (float*)(ws + OFF_AGG);
  float* xt0p  = (float*)(ws + OFF_XT0);
  unsigned short* qkvb = (unsigned short*)(ws + OFF_QKV);
  float* xt1p  = (float*)(ws + OFF_XT1);
  float* sbias = (float*)(ws + OFF_SBIAS);

  zero_k<<<128, 256, 0, stream>>>(ccnt);
  prep_k<<<946, 256, 0, stream>>>(pos, W1, W2, Wr, ipw, ipb, opw, Wm1, Wm2,
                                  pos4, w1t, w2t, wrt, wqkvt, woutt, wm1t, wm2t,
                                  ccnt, sbias);
  prefix_k<<<1, 1024, 0, stream>>>(ccnt, cdesc, cfill);
  scatter_k<<<128, 256, 0, stream>>>(pos4, cfill, sposp);
  knn_k<<<1024, 256, 0, stream>>>(sposp, cdesc, pos4, idx, colp,
                                  out + 524288, out + 536576);
  conv_k<<<1024, 256, 0, stream>>>(x, pos4, idx, colp, w1t, b1, w2t, b2, aggp);
  gemm_k<256, 128, false, false, false><<<dim3(64, 2), 256, 0, stream>>>(aggp, wrt, br, nullptr, xt0p);
  gemm_k<128, 384, false, false, true><<<dim3(64, 6), 256, 0, stream>>>(xt0p, wqkvt, sbias, nullptr, (float*)qkvb);
  attn_k<<<dim3(64, 4, 4), 256, 0, stream>>>(qkvb, pou, plp);
  gemmln2_k<128, true><<<256, 256, 0, stream>>>(nullptr, pou, plp, woutt, opb, xt0p, g1, be1, xt1p);
  mlpln_k<<<256, 256, 0, stream>>>(xt1p, wm1t, bm1, wm2t, bm2, g2, be2, out);
}

// Round 16
// 153.379 us; speedup vs baseline: 1.0959x; 1.0212x over previous
//
#include <hip/hip_runtime.h>
#include <hip/hip_bf16.h>

#define DEV static __device__ __forceinline__

typedef __attribute__((ext_vector_type(8))) short          s16x8;
typedef __attribute__((ext_vector_type(8))) unsigned short u16x8;
typedef __attribute__((ext_vector_type(4))) float          f32x4;
typedef __attribute__((ext_vector_type(4))) unsigned int   u32x4;

#define MFMA16(A,B,C) __builtin_amdgcn_mfma_f32_16x16x32_bf16((A),(B),(C),0,0,0)

DEV unsigned short f2bf(float f) {
  unsigned int u = __builtin_bit_cast(unsigned int, f);
  u += 0x7fffu + ((u >> 16) & 1u);
  return (unsigned short)(u >> 16);
}
DEV float bf2f(unsigned short u) {
  unsigned int x = ((unsigned int)u) << 16;
  return __builtin_bit_cast(float, x);
}

// 1/sqrt(32) * log2(e): fold into Q projection so softmax uses exp2 directly
#define QSCL 0.25503562201f

// ------------------------- grid params -------------------------
#define GRID_LO  (-5.0f)
#define GRID_IH  (3.2f)

DEV int cellc(float v) {
  int c = (int)floorf((v - GRID_LO) * GRID_IH);
  return min(31, max(0, c));
}

// ------------------------- ws layout -------------------------
constexpr size_t OFF_POS4  = 0;
constexpr size_t OFF_COL   = 524288;
constexpr size_t OFF_W1T   = 1048576;
constexpr size_t OFF_W2T   = OFF_W1T  + 24576;
constexpr size_t OFF_WRT   = OFF_W2T  + 65536;
constexpr size_t OFF_WQKVT = OFF_WRT  + 65536;
constexpr size_t OFF_WOUTT = OFF_WQKVT+ 98304;
constexpr size_t OFF_WM1T  = OFF_WOUTT+ 32768;
constexpr size_t OFF_WM2T  = OFF_WM1T + 65536;
constexpr size_t OFF_H     = OFF_WM2T + 65536;        // 33554432-byte shared region
// phase 1: cell structures
constexpr size_t OFF_SPOS    = OFF_H;
constexpr size_t OFF_CELLCNT = OFF_H + 524288;
constexpr size_t OFF_CELLDSC = OFF_H + 655360;
constexpr size_t OFF_FILL    = OFF_H + 917504;
// phase 2: attention partials (po bf16: 8*4096*128*2 = 8388608)
constexpr size_t OFF_PO      = OFF_H;
constexpr size_t OFF_PL      = OFF_H + 16777216;      // 524288 (f32, 8 splits)
constexpr size_t OFF_AGG   = OFF_H    + 33554432;
constexpr size_t OFF_XT0   = OFF_AGG  + 4194304;
constexpr size_t OFF_QKV   = OFF_XT0  + 2097152;
constexpr size_t OFF_ATT   = OFF_QKV  + 6291456;
constexpr size_t OFF_PRE   = OFF_ATT  + 2097152;
constexpr size_t OFF_XT1   = OFF_PRE  + 2097152;
constexpr size_t OFF_MLP1  = OFF_XT1  + 2097152;
constexpr size_t OFF_SBIAS = OFF_MLP1 + 4194304;

// ------------------------- zero cell counts -------------------------
__global__ __launch_bounds__(256) void zero_k(int* __restrict__ p) {
  p[blockIdx.x * 256 + threadIdx.x] = 0;
}

// ------------------------- prep -------------------------
__global__ __launch_bounds__(256) void prep_k(
    const float* __restrict__ pos, const float* __restrict__ W1,
    const float* __restrict__ W2, const float* __restrict__ Wr,
    const float* __restrict__ ipw, const float* __restrict__ ipb,
    const float* __restrict__ opw,
    const float* __restrict__ Wm1, const float* __restrict__ Wm2,
    float4* __restrict__ pos4, unsigned short* __restrict__ w1t,
    unsigned short* __restrict__ w2t, unsigned short* __restrict__ wrt,
    unsigned short* __restrict__ wqkvt, unsigned short* __restrict__ woutt,
    unsigned short* __restrict__ wm1t, unsigned short* __restrict__ wm2t,
    int* __restrict__ cellcnt, float* __restrict__ sbias) {
  int T = blockIdx.x * 256 + threadIdx.x;
  if (T < 32768) {
    float px = pos[T*3], py = pos[T*3+1], pz = pos[T*3+2];
    pos4[T] = make_float4(px, py, pz, 0.f);
    int cid = (cellc(pz)*32 + cellc(py))*32 + cellc(px);
    atomicAdd(&cellcnt[cid], 1);
    return;
  }
  T -= 32768;
  if (T < 128*96)  { int n=T/96,  k=T%96;  w1t[T]  = f2bf(k < 67 ? W1[k*128+n] : 0.f); return; }
  T -= 128*96;
  if (T < 256*128) { int n=T/128, k=T%128; w2t[T]  = f2bf(W2[k*256+n]);  return; }
  T -= 256*128;
  if (T < 128*256) { int n=T/256, k=T%256; wrt[T]  = f2bf(Wr[k*128+n]);  return; }
  T -= 128*256;
  if (T < 384*128) { int n=T/128, k=T%128;
                     float v = ipw[k*384+n];
                     if (n < 128) v *= QSCL;
                     wqkvt[T]= f2bf(v); return; }
  T -= 384*128;
  if (T < 128*128) { int n=T/128, k=T%128; woutt[T]= f2bf(opw[k*128+n]); return; }
  T -= 128*128;
  if (T < 256*128) { int n=T/128, k=T%128; wm1t[T] = f2bf(Wm1[k*256+n]); return; }
  T -= 256*128;
  if (T < 128*256) { int n=T/256, k=T%256; wm2t[T] = f2bf(Wm2[k*128+n]); return; }
  T -= 128*256;
  if (T < 384) { sbias[T] = ipb[T] * (T < 128 ? QSCL : 1.f); return; }
}

// ------------------------- prefix over 32768 cell counts -------------------
__global__ __launch_bounds__(1024) void prefix_k(const int* __restrict__ cnt,
                                                 int2* __restrict__ desc,
                                                 int* __restrict__ fill) {
  __shared__ int wsum[16];
  const int tid = threadIdx.x, lane = tid & 63, w = tid >> 6;
  int loc[32]; int s = 0;
  #pragma unroll
  for (int i = 0; i < 32; ++i) { loc[i] = cnt[tid*32 + i]; s += loc[i]; }
  int sc = s;
  #pragma unroll
  for (int off = 1; off < 64; off <<= 1) {
    int v = __shfl_up(sc, off);
    if (lane >= off) sc += v;
  }
  if (lane == 63) wsum[w] = sc;
  __syncthreads();
  if (tid == 0) {
    int run = 0;
    #pragma unroll
    for (int i = 0; i < 16; ++i) { int v = wsum[i]; wsum[i] = run; run += v; }
  }
  __syncthreads();
  int base = wsum[w] + (sc - s);
  #pragma unroll
  for (int i = 0; i < 32; ++i) {
    int c = tid*32 + i;
    desc[c] = make_int2(base, loc[i]);
    fill[c] = base;
    base += loc[i];
  }
}

// ------------------------- scatter -------------------------
__global__ __launch_bounds__(256) void scatter_k(const float4* __restrict__ pos4,
                                                 int* __restrict__ fill,
                                                 float4* __restrict__ spos) {
  int T = blockIdx.x * 256 + threadIdx.x;
  float4 p = pos4[T];
  int cid = (cellc(p.z)*32 + cellc(p.y))*32 + cellc(p.x);
  int slot = atomicAdd(&fill[cid], 1);
  spos[slot] = make_float4(p.x, p.y, p.z, __int_as_float(T));
}

// ------------------------- KNN -------------------------
#define KNN_CAP  320
#define KNN_TRIG 192
#define KNN_KEEP 33
#define KNN_INF  3e37f

__global__ __launch_bounds__(256) void knn_k(
    const float4* __restrict__ spos, const int2* __restrict__ desc,
    const float4* __restrict__ pos4, const int* __restrict__ idx,
    int* __restrict__ col,
    float* __restrict__ outqpos, float* __restrict__ outbatch) {
  __shared__ float bufd[4][KNN_CAP];
  __shared__ int   bufi[4][KNN_CAP];
  __shared__ int   shist[4][64];
  __shared__ int2  segs[4][128];
  const int tid = threadIdx.x, lane = tid & 63, w = tid >> 6;
  const unsigned long long ltmask = (1ull << lane) - 1ull;

  const int q = blockIdx.x * 4 + w;
  const int iq = idx[q];
  const float4 qp = pos4[iq];
  const float qx = qp.x, qy = qp.y, qz = qp.z;
  const int cx0 = cellc(qx), cy0 = cellc(qy), cz0 = cellc(qz);

  float t = KNN_INF;
  int cnt = 0;

  auto compact = [&]() {
    int c_ = min(cnt, KNN_CAP);
    float vd[5]; int vi[5], bs[5]; bool okv[5];
    float dmax = 1e-30f;
    #pragma unroll
    for (int s = 0; s < 5; ++s) {
      int o2 = s*64 + lane;
      okv[s] = o2 < c_;
      vd[s] = okv[s] ? bufd[w][o2] : 0.f;
      vi[s] = okv[s] ? bufi[w][o2] : 0;
      dmax = fmaxf(dmax, vd[s]);
    }
    #pragma unroll
    for (int off = 1; off < 64; off <<= 1) dmax = fmaxf(dmax, __shfl_xor(dmax, off));
    float scale = 63.99f / dmax;
    shist[w][lane] = 0;
    #pragma unroll
    for (int s = 0; s < 5; ++s) {
      bs[s] = okv[s] ? min(63, (int)(vd[s] * scale)) : 64;
      if (okv[s]) atomicAdd(&shist[w][bs[s]], 1);
    }
    int h = shist[w][lane];
    #pragma unroll
    for (int off = 1; off < 64; off <<= 1) {
      int v = __shfl_up(h, off);
      if (lane >= off) h += v;
    }
    unsigned long long mk = __ballot(h >= KNN_KEEP);
    int E = mk ? (__ffsll((long long)mk) - 1) : 63;
    int base = 0;
    #pragma unroll
    for (int s = 0; s < 5; ++s) {
      bool keep = okv[s] && bs[s] <= E;
      unsigned long long km = __ballot(keep);
      int pp = base + (int)__popcll(km & ltmask);
      if (keep) { bufd[w][pp] = vd[s]; bufi[w][pp] = vi[s]; }
      base += (int)__popcll(km);
    }
    cnt = base;
    t = fminf(t, (float)(E + 1) / scale);
  };

  auto scan_rows = [&](int knew, int kold) {
    const int S = 2*knew + 1;
    const int NR = S*S;
    const float invS = 1.f / (float)S;
    for (int r0 = 0; r0 < NR; r0 += 64) {
      int r = r0 + lane;
      bool v = r < NR;
      int dz = (int)((float)r * invS);
      int rem = r - dz*S;
      if (rem < 0) { dz--; rem += S; } else if (rem >= S) { dz++; rem -= S; }
      int ccz = cz0 + dz - knew, ccy = cy0 + rem - knew;
      bool rowok = v && ccz >= 0 && ccz < 32 && ccy >= 0 && ccy < 32;
      bool inner = kold >= 0 && abs(dz - knew) <= kold && abs(rem - knew) <= kold;
      int cbase = (ccz*32 + ccy) * 32;
      int sL = 0, lL = 0, sR = 0, lR = 0;
      if (rowok) {
        int xa = max(cx0 - knew, 0);
        int xb = inner ? (cx0 - kold - 1) : min(cx0 + knew, 31);
        if (xa <= xb) {
          int2 d0 = desc[cbase + xa];
          int2 d1 = desc[cbase + xb];
          sL = d0.x; lL = d1.x + d1.y - d0.x;
        }
        if (inner) {
          int xa2 = cx0 + kold + 1, xb2 = min(cx0 + knew, 31);
          if (xa2 <= xb2 && xa2 >= 0) {
            int2 d0 = desc[cbase + xa2];
            int2 d1 = desc[cbase + xb2];
            sR = d0.x; lR = d1.x + d1.y - d0.x;
          }
        }
      }
      int cumL = lL;
      #pragma unroll
      for (int off = 1; off < 64; off <<= 1) {
        int vv = __shfl_up(cumL, off);
        if (lane >= off) cumL += vv;
      }
      int sumL = __shfl(cumL, 63);
      int cumR = lR;
      #pragma unroll
      for (int off = 1; off < 64; off <<= 1) {
        int vv = __shfl_up(cumR, off);
        if (lane >= off) cumR += vv;
      }
      int sumR = __shfl(cumR, 63);
      segs[w][lane]      = make_int2(sL, cumL - lL);
      segs[w][64 + lane] = make_int2(sR, sumL + cumR - lR);
      const int total = sumL + sumR;

      for (int b = 0; b < total; b += 320) {
        float d2v[5]; int piv[5]; bool hv[5];
        #pragma unroll
        for (int s5 = 0; s5 < 5; ++s5) {
          int p = b + s5*64 + lane;
          bool act = p < total;
          hv[s5] = false; d2v[s5] = 0.f; piv[s5] = 0;
          if (act) {
            int lo = 0;
            #pragma unroll
            for (int st = 64; st > 0; st >>= 1)
              if (segs[w][lo + st].y <= p) lo += st;
            int2 e = segs[w][lo];
            float4 pt = spos[e.x + (p - e.y)];
            float ddx = qx-pt.x, ddy = qy-pt.y, ddz = qz-pt.z;
            float d2 = ddx*ddx + ddy*ddy + ddz*ddz;
            d2v[s5] = d2; piv[s5] = __float_as_int(pt.w);
            hv[s5] = d2 < t;
          }
        }
        #pragma unroll
        for (int s5 = 0; s5 < 5; ++s5) {
          unsigned long long hm = __ballot(hv[s5]);
          if (hm) {
            int pp = cnt + (int)__popcll(hm & ltmask);
            if (hv[s5] && pp < KNN_CAP) { bufd[w][pp] = d2v[s5]; bufi[w][pp] = piv[s5]; }
            cnt += (int)__popcll(hm);
            if (cnt >= KNN_TRIG) compact();
          }
        }
      }
    }
  };

  auto bound32 = [&]() -> float {
    int c_ = min(cnt, KNN_CAP);
    float vv[5]; bool okv[5];
    float dmax = 1e-30f;
    #pragma unroll
    for (int s = 0; s < 5; ++s) {
      int o2 = s*64 + lane;
      okv[s] = o2 < c_;
      vv[s] = okv[s] ? bufd[w][o2] : 0.f;
      dmax = fmaxf(dmax, vv[s]);
    }
    #pragma unroll
    for (int off = 1; off < 64; off <<= 1) dmax = fmaxf(dmax, __shfl_xor(dmax, off));
    float scale = 63.99f / dmax;
    shist[w][lane] = 0;
    #pragma unroll
    for (int s = 0; s < 5; ++s)
      if (okv[s]) atomicAdd(&shist[w][min(63, (int)(vv[s] * scale))], 1);
    int h = shist[w][lane];
    #pragma unroll
    for (int off = 1; off < 64; off <<= 1) {
      int v = __shfl_up(h, off);
      if (lane >= off) h += v;
    }
    unsigned long long m = __ballot(h >= 32);
    int E = m ? (__ffsll((long long)m) - 1) : 63;
    return (float)(E + 1) / scale;
  };

  int kcur = 1;
  scan_rows(1, -1);
  for (int it = 0; it < 64; ++it) {
    if (cnt >= 32) {
      float t32u = bound32();
      t = fminf(t, t32u);
      int kneed = (int)(__builtin_sqrtf(t32u) * GRID_IH) + 1;
      if (kneed <= kcur || kcur >= 31) break;
      int knew = min(kneed, 31);
      scan_rows(knew, kcur);
      kcur = knew;
    } else {
      if (kcur >= 31) break;
      int knew = min(kcur + (cnt == 0 ? 2 : 1), 31);
      scan_rows(knew, kcur);
      kcur = knew;
    }
  }

  // ---- final exact top-32 ----
  {
    int c_ = min(cnt, KNN_CAP);
    float vd[5]; int vi[5], bs[5]; bool okf[5];
    float dmax = 1e-30f;
    #pragma unroll
    for (int s = 0; s < 5; ++s) {
      int o2 = s*64 + lane;
      okf[s] = o2 < c_;
      vd[s] = okf[s] ? bufd[w][o2] : KNN_INF;
      vi[s] = okf[s] ? bufi[w][o2] : 0;
      dmax = fmaxf(dmax, okf[s] ? vd[s] : 0.f);
    }
    #pragma unroll
    for (int off = 1; off < 64; off <<= 1) dmax = fmaxf(dmax, __shfl_xor(dmax, off));
    float sc64 = 63.99f / dmax;
    shist[w][lane] = 0;
    #pragma unroll
    for (int s = 0; s < 5; ++s) {
      bs[s] = okf[s] ? min(63, (int)(vd[s] * sc64)) : 64;
      if (okf[s]) atomicAdd(&shist[w][bs[s]], 1);
    }
    int h = shist[w][lane];
    #pragma unroll
    for (int off = 1; off < 64; off <<= 1) {
      int v = __shfl_up(h, off);
      if (lane >= off) h += v;
    }
    unsigned long long m = __ballot(h >= 32);
    int E = m ? (__ffsll((long long)m) - 1) : 63;
    int c0 = (E > 0) ? __shfl(h, E - 1) : 0;
    int base = 0;
    #pragma unroll
    for (int s = 0; s < 5; ++s) {
      bool wr = okf[s] && (bs[s] < E);
      unsigned long long km = __ballot(wr);
      int pp = base + (int)__popcll(km & ltmask);
      if (wr) col[q*32 + pp] = vi[s];
      base += (int)__popcll(km);
    }
    #pragma unroll
    for (int s = 0; s < 5; ++s)
      if (!(okf[s] && bs[s] == E)) vd[s] = KNN_INF;
    int r = 32 - c0;
    #pragma unroll 1
    for (int kk = 0; kk < r; ++kk) {
      float bd = vd[0]; int bi = vi[0]; int bc = lane*8;
      #pragma unroll
      for (int s = 1; s < 5; ++s)
        if (vd[s] < bd) { bd = vd[s]; bi = vi[s]; bc = lane*8 + s; }
      #pragma unroll
      for (int off = 1; off < 64; off <<= 1) {
        float od = __shfl_xor(bd, off);
        int   oi = __shfl_xor(bi, off);
        int   oc = __shfl_xor(bc, off);
        if (od < bd || (od == bd && oc < bc)) { bd = od; bi = oi; bc = oc; }
      }
      if ((bc >> 3) == lane) {
        int sl = bc & 7;
        #pragma unroll
        for (int s = 0; s < 5; ++s) if (sl == s) vd[s] = KNN_INF;
      }
      if (lane == 0) col[q*32 + c0 + kk] = bi;
    }
  }
  if (lane == 0) {
    outqpos[q*3+0] = qx; outqpos[q*3+1] = qy; outqpos[q*3+2] = qz;
    outbatch[q] = 0.f;
  }
}

// ------------------------- fused conv (round-13 structure) -----------------
#define LA1(r,c) S[(r)*104 + (c)]
#define LB1(r,c) S[13312 + (r)*104 + (c)]
#define HB(r,c)  S[(r)*136 + (c)]
#define W2C(r,c) S[17408 + (r)*136 + (c)]

__global__ __launch_bounds__(256) void conv_k(
    const float* __restrict__ x, const float4* __restrict__ pos4,
    const int* __restrict__ idx, const int* __restrict__ col,
    const unsigned short* __restrict__ w1t, const float* __restrict__ b1,
    const unsigned short* __restrict__ w2t, const float* __restrict__ b2,
    float* __restrict__ agg) {
  __shared__ __align__(16) unsigned short S[26624];
  __shared__ int   sci[128];
  __shared__ float sqp[4][3];
  const int tid = threadIdx.x, lane = tid & 63, w = tid >> 6;
  const int wm = w >> 1, wn = w & 1;
  const int m0 = blockIdx.x * 4;

  if (tid < 128) sci[tid] = col[m0*32 + tid];
  if (tid >= 128 && tid < 132) {
    int m = m0 + tid - 128;
    float4 p = pos4[idx[m]];
    sqp[tid-128][0] = p.x; sqp[tid-128][1] = p.y; sqp[tid-128][2] = p.z;
  }
  #pragma unroll
  for (int rnd = 0; rnd < 6; ++rnd) {
    int e = (rnd*256 + tid) * 8;
    int n = e / 96, k = e % 96;
    *(u16x8*)&LB1(n, k) = *(const u16x8*)&w1t[e];
  }
  __syncthreads();

  {
    int r = tid >> 1, half = tid & 1;
    int ci = sci[r];
    const float* src = x + (size_t)ci*64 + half*32;
    #pragma unroll
    for (int c = 0; c < 4; ++c) {
      float4 va = ((const float4*)src)[c*2], vb = ((const float4*)src)[c*2+1];
      u16x8 v;
      v[0]=f2bf(va.x); v[1]=f2bf(va.y); v[2]=f2bf(va.z); v[3]=f2bf(va.w);
      v[4]=f2bf(vb.x); v[5]=f2bf(vb.y); v[6]=f2bf(vb.z); v[7]=f2bf(vb.w);
      *(u16x8*)&LA1(r, half*32 + c*8) = v;
    }
  }
  if (tid < 128) {
    int r = tid, g = r >> 5;
    float4 p = pos4[sci[r]];
    u16x8 z;
    #pragma unroll
    for (int e = 0; e < 8; ++e) z[e] = 0;
    u16x8 v0 = z;
    v0[0] = f2bf(p.x - sqp[g][0]); v0[1] = f2bf(p.y - sqp[g][1]); v0[2] = f2bf(p.z - sqp[g][2]);
    *(u16x8*)&LA1(r, 64) = v0;
    #pragma unroll
    for (int c = 1; c < 5; ++c) *(u16x8*)&LA1(r, 64 + c*8) = z;
  }
  __syncthreads();

  f32x4 acc[4][4];
  #pragma unroll
  for (int nf = 0; nf < 4; ++nf) {
    float bv = b1[wn*64 + nf*16 + (lane & 15)];
    #pragma unroll
    for (int mf = 0; mf < 4; ++mf) acc[mf][nf] = f32x4{bv, bv, bv, bv};
  }
  #pragma unroll
  for (int kc = 0; kc < 3; ++kc) {
    s16x8 af[4], bf_[4];
    #pragma unroll
    for (int mf = 0; mf < 4; ++mf)
      af[mf] = *(const s16x8*)&LA1(wm*64 + mf*16 + (lane&15), kc*32 + (lane>>4)*8);
    #pragma unroll
    for (int nf = 0; nf < 4; ++nf)
      bf_[nf] = *(const s16x8*)&LB1(wn*64 + nf*16 + (lane&15), kc*32 + (lane>>4)*8);
    #pragma unroll
    for (int mf = 0; mf < 4; ++mf)
      #pragma unroll
      for (int nf = 0; nf < 4; ++nf)
        acc[mf][nf] = MFMA16(af[mf], bf_[nf], acc[mf][nf]);
  }
  __syncthreads();

  #pragma unroll
  for (int mf = 0; mf < 4; ++mf)
    #pragma unroll
    for (int nf = 0; nf < 4; ++nf)
      #pragma unroll
      for (int j = 0; j < 4; ++j) {
        int rloc = wm*64 + mf*16 + ((lane>>4)<<2) + j;
        int cloc = wn*64 + nf*16 + (lane & 15);
        HB(rloc, cloc) = f2bf(fmaxf(acc[mf][nf][j], 0.f));
      }
  {
    int r2 = tid >> 2, kq = (tid & 3) * 32;
    const unsigned short* src = w2t + (size_t)r2*128 + kq;
    #pragma unroll
    for (int c = 0; c < 4; ++c)
      *(u16x8*)&W2C(r2, kq + c*8) = *(const u16x8*)&src[c*8];
  }
  __syncthreads();

  #pragma unroll 1
  for (int nc = 0; nc < 4; ++nc) {
    f32x4 acc2[2][4];
    #pragma unroll
    for (int nf = 0; nf < 4; ++nf) {
      float bv = b2[nc*64 + nf*16 + (lane & 15)];
      acc2[0][nf] = f32x4{bv, bv, bv, bv};
      acc2[1][nf] = f32x4{bv, bv, bv, bv};
    }
    #pragma unroll
    for (int ks = 0; ks < 4; ++ks) {
      s16x8 af[2], bf_[4];
      #pragma unroll
      for (int mf = 0; mf < 2; ++mf)
        af[mf] = *(const s16x8*)&HB(w*32 + mf*16 + (lane&15), ks*32 + (lane>>4)*8);
      #pragma unroll
      for (int nf = 0; nf < 4; ++nf)
        bf_[nf] = *(const s16x8*)&W2C(nf*16 + (lane&15), ks*32 + (lane>>4)*8);
      #pragma unroll
      for (int mf = 0; mf < 2; ++mf)
        #pragma unroll
        for (int nf = 0; nf < 4; ++nf)
          acc2[mf][nf] = MFMA16(af[mf], bf_[nf], acc2[mf][nf]);
    }
    #pragma unroll
    for (int nf = 0; nf < 4; ++nf) {
      float mx = acc2[0][nf][0];
      #pragma unroll
      for (int j = 1; j < 4; ++j) mx = fmaxf(mx, acc2[0][nf][j]);
      #pragma unroll
      for (int j = 0; j < 4; ++j) mx = fmaxf(mx, acc2[1][nf][j]);
      mx = fmaxf(mx, __shfl_xor(mx, 16));
      mx = fmaxf(mx, __shfl_xor(mx, 32));
      if (lane < 16) agg[(size_t)(m0 + w)*256 + nc*64 + nf*16 + lane] = mx;
    }
    if (nc < 3) {
      __syncthreads();
      int r2 = tid >> 2, kq = (tid & 3) * 32;
      const unsigned short* src = w2t + (size_t)((nc+1)*64 + r2)*128 + kq;
      #pragma unroll
      for (int c = 0; c < 4; ++c)
        *(u16x8*)&W2C(r2, kq + c*8) = *(const u16x8*)&src[c*8];
      __syncthreads();
    }
  }
}

// ------------------------- 64x64-tile GEMM -------------------------
template<int KFULL, int NFULL, bool RELU, bool HAS_RES, bool OBF16>
__global__ __launch_bounds__(256) void gemm_k(
    const float* __restrict__ A, const unsigned short* __restrict__ Bt,
    const float* __restrict__ bias, const float* __restrict__ res,
    float* __restrict__ out) {
  __shared__ unsigned short lA[64][72];
  __shared__ unsigned short lB[64][72];
  const int tid = threadIdx.x, lane = tid & 63, w = tid >> 6;
  const int m0 = blockIdx.x * 64, n0 = blockIdx.y * 64;

  f32x4 acc[4];
  #pragma unroll
  for (int nf = 0; nf < 4; ++nf) {
    float bv = bias[n0 + nf*16 + (lane & 15)];
    acc[nf] = f32x4{bv, bv, bv, bv};
  }

  for (int kb = 0; kb < KFULL; kb += 64) {
    __syncthreads();
    {
      int r = tid >> 2, kq = (tid & 3) * 16;
      const float* src = A + (size_t)(m0 + r)*KFULL + kb + kq;
      #pragma unroll
      for (int c = 0; c < 2; ++c) {
        float4 va = ((const float4*)src)[c*2], vb = ((const float4*)src)[c*2+1];
        u16x8 v;
        v[0]=f2bf(va.x); v[1]=f2bf(va.y); v[2]=f2bf(va.z); v[3]=f2bf(va.w);
        v[4]=f2bf(vb.x); v[5]=f2bf(vb.y); v[6]=f2bf(vb.z); v[7]=f2bf(vb.w);
        *(u16x8*)&lA[r][kq + c*8] = v;
      }
      const unsigned short* srcb = Bt + (size_t)(n0 + r)*KFULL + kb + kq;
      #pragma unroll
      for (int c = 0; c < 2; ++c)
        *(u16x8*)&lB[r][kq + c*8] = *(const u16x8*)&srcb[c*8];
    }
    __syncthreads();
    #pragma unroll
    for (int ks = 0; ks < 2; ++ks) {
      s16x8 af = *(const s16x8*)&lA[w*16 + (lane&15)][ks*32 + (lane>>4)*8];
      s16x8 bf_[4];
      #pragma unroll
      for (int nf = 0; nf < 4; ++nf)
        bf_[nf] = *(const s16x8*)&lB[nf*16 + (lane&15)][ks*32 + (lane>>4)*8];
      #pragma unroll
      for (int nf = 0; nf < 4; ++nf)
        acc[nf] = MFMA16(af, bf_[nf], acc[nf]);
    }
  }
  #pragma unroll
  for (int nf = 0; nf < 4; ++nf)
    #pragma unroll
    for (int j = 0; j < 4; ++j) {
      int row = m0 + w*16 + ((lane>>4)<<2) + j;
      int colg = n0 + nf*16 + (lane & 15);
      float v = acc[nf][j];
      if (HAS_RES) v += res[(size_t)row*NFULL + colg];
      if (RELU)    v = fmaxf(v, 0.f);
      if (OBF16) ((unsigned short*)out)[(size_t)row*NFULL + colg] = f2bf(v);
      else       out[(size_t)row*NFULL + colg] = v;
    }
}

// ------------------------- fused out_proj + residual + LN (N-split) --------
template<int KFULL, bool COMBINE>
__global__ __launch_bounds__(256) void gemmln2_k(
    const float* __restrict__ A,
    const unsigned short* __restrict__ po, const float* __restrict__ pl,
    const unsigned short* __restrict__ Bt, const float* __restrict__ bias,
    const float* __restrict__ res,
    const float* __restrict__ gam, const float* __restrict__ bet,
    float* __restrict__ out) {
  constexpr int KP = KFULL + 8;
  __shared__ __align__(16) unsigned short lA[16 * KP];
  __shared__ float vout[16 * 132];
  const int tid = threadIdx.x, lane = tid & 63, w = tid >> 6;
  const int g = lane >> 4, ln_ = lane & 15;
  const int m0 = blockIdx.x * 16;

  {
    int r = tid >> 4, seg = tid & 15;
    int row = m0 + r;
    if (COMBINE) {
      int hh = seg >> 2;
      float lsum = 0.f;
      #pragma unroll
      for (int s = 0; s < 8; ++s) lsum += pl[((s*4 + hh) << 12) + row];
      float inv = 1.f / lsum;
      float a[8] = {0,0,0,0,0,0,0,0};
      #pragma unroll
      for (int s = 0; s < 8; ++s) {
        u16x8 v = *(const u16x8*)&po[((size_t)s*4096 + row)*128 + seg*8];
        #pragma unroll
        for (int e = 0; e < 8; ++e) a[e] += bf2f(v[e]);
      }
      u16x8 ov;
      #pragma unroll
      for (int e = 0; e < 8; ++e) ov[e] = f2bf(a[e] * inv);
      *(u16x8*)&lA[r*KP + seg*8] = ov;
    } else {
      const float* src = A + (size_t)row*KFULL + seg*(KFULL/16);
      #pragma unroll
      for (int c = 0; c < KFULL/128; ++c) {
        float4 va = ((const float4*)src)[c*2], vb = ((const float4*)src)[c*2+1];
        u16x8 v;
        v[0]=f2bf(va.x); v[1]=f2bf(va.y); v[2]=f2bf(va.z); v[3]=f2bf(va.w);
        v[4]=f2bf(vb.x); v[5]=f2bf(vb.y); v[6]=f2bf(vb.z); v[7]=f2bf(vb.w);
        *(u16x8*)&lA[r*KP + seg*(KFULL/16) + c*8] = v;
      }
    }
  }
  __syncthreads();

  const int n0 = w * 32;
  f32x4 acc[2];
  #pragma unroll
  for (int nf = 0; nf < 2; ++nf) {
    float bv = bias[n0 + nf*16 + ln_];
    acc[nf] = f32x4{bv, bv, bv, bv};
  }
  #pragma unroll
  for (int ks = 0; ks < KFULL/32; ++ks) {
    s16x8 af = *(const s16x8*)&lA[ln_*KP + ks*32 + g*8];
    #pragma unroll
    for (int nf = 0; nf < 2; ++nf) {
      s16x8 bf_ = *(const s16x8*)&Bt[(size_t)(n0 + nf*16 + ln_)*KFULL + ks*32 + g*8];
      acc[nf] = MFMA16(af, bf_, acc[nf]);
    }
  }
  #pragma unroll
  for (int nf = 0; nf < 2; ++nf)
    #pragma unroll
    for (int j = 0; j < 4; ++j)
      vout[(g*4 + j)*132 + n0 + nf*16 + ln_] = acc[nf][j];
  __syncthreads();

  {
    int r = tid >> 4, seg = tid & 15;
    int row = m0 + r;
    float v[8]; float sm = 0.f;
    #pragma unroll
    for (int nf = 0; nf < 8; ++nf) {
      int c = nf*16 + seg;
      float xx = vout[r*132 + c] + res[(size_t)row*128 + c];
      v[nf] = xx; sm += xx;
    }
    sm += __shfl_xor(sm, 1); sm += __shfl_xor(sm, 2);
    sm += __shfl_xor(sm, 4); sm += __shfl_xor(sm, 8);
    float mu = sm * 0.0078125f;
    float qv = 0.f;
    #pragma unroll
    for (int nf = 0; nf < 8; ++nf) { float d = v[nf] - mu; qv += d*d; }
    qv += __shfl_xor(qv, 1); qv += __shfl_xor(qv, 2);
    qv += __shfl_xor(qv, 4); qv += __shfl_xor(qv, 8);
    float rr = rsqrtf(qv * 0.0078125f + 1e-5f);
    #pragma unroll
    for (int nf = 0; nf < 8; ++nf) {
      int c = nf*16 + seg;
      out[(size_t)row*128 + c] = (v[nf] - mu) * rr * gam[c] + bet[c];
    }
  }
}

// ------------------------- fused MLP (mlp1+relu+mlp2+res+LN) ---------------
__global__ __launch_bounds__(256) void mlpln_k(
    const float* __restrict__ xt1,
    const unsigned short* __restrict__ wm1t, const float* __restrict__ bm1,
    const unsigned short* __restrict__ wm2t, const float* __restrict__ bm2,
    const float* __restrict__ gam, const float* __restrict__ bet,
    float* __restrict__ out) {
  __shared__ __align__(16) unsigned short lA[16 * 136];
  __shared__ __align__(16) unsigned short lH[16 * 264];
  __shared__ float vout[16 * 132];
  const int tid = threadIdx.x, lane = tid & 63, w = tid >> 6;
  const int g = lane >> 4, ln_ = lane & 15;
  const int m0 = blockIdx.x * 16;

  {
    int r = tid >> 4, seg = tid & 15;
    const float* src = xt1 + (size_t)(m0 + r)*128 + seg*8;
    float4 va = ((const float4*)src)[0], vb = ((const float4*)src)[1];
    u16x8 v;
    v[0]=f2bf(va.x); v[1]=f2bf(va.y); v[2]=f2bf(va.z); v[3]=f2bf(va.w);
    v[4]=f2bf(vb.x); v[5]=f2bf(vb.y); v[6]=f2bf(vb.z); v[7]=f2bf(vb.w);
    *(u16x8*)&lA[r*136 + seg*8] = v;
  }
  __syncthreads();

  {
    const int n0 = w * 64;
    f32x4 acc1[4];
    #pragma unroll
    for (int nf = 0; nf < 4; ++nf) {
      float bv = bm1[n0 + nf*16 + ln_];
      acc1[nf] = f32x4{bv, bv, bv, bv};
    }
    #pragma unroll
    for (int ks = 0; ks < 4; ++ks) {
      s16x8 af = *(const s16x8*)&lA[ln_*136 + ks*32 + g*8];
      #pragma unroll
      for (int nf = 0; nf < 4; ++nf) {
        s16x8 bf_ = *(const s16x8*)&wm1t[(size_t)(n0 + nf*16 + ln_)*128 + ks*32 + g*8];
        acc1[nf] = MFMA16(af, bf_, acc1[nf]);
      }
    }
    #pragma unroll
    for (int nf = 0; nf < 4; ++nf)
      #pragma unroll
      for (int j = 0; j < 4; ++j)
        lH[(g*4 + j)*264 + n0 + nf*16 + ln_] = f2bf(fmaxf(acc1[nf][j], 0.f));
  }
  __syncthreads();

  {
    const int n0 = w * 32;
    f32x4 acc2[2];
    #pragma unroll
    for (int nf = 0; nf < 2; ++nf) {
      float bv = bm2[n0 + nf*16 + ln_];
      acc2[nf] = f32x4{bv, bv, bv, bv};
    }
    #pragma unroll
    for (int ks = 0; ks < 8; ++ks) {
      s16x8 af = *(const s16x8*)&lH[ln_*264 + ks*32 + g*8];
      #pragma unroll
      for (int nf = 0; nf < 2; ++nf) {
        s16x8 bf_ = *(const s16x8*)&wm2t[(size_t)(n0 + nf*16 + ln_)*256 + ks*32 + g*8];
        acc2[nf] = MFMA16(af, bf_, acc2[nf]);
      }
    }
    #pragma unroll
    for (int nf = 0; nf < 2; ++nf)
      #pragma unroll
      for (int j = 0; j < 4; ++j)
        vout[(g*4 + j)*132 + n0 + nf*16 + ln_] = acc2[nf][j];
  }
  __syncthreads();

  {
    int r = tid >> 4, seg = tid & 15;
    int row = m0 + r;
    float v[8]; float sm = 0.f;
    #pragma unroll
    for (int nf = 0; nf < 8; ++nf) {
      int c = nf*16 + seg;
      float xx = vout[r*132 + c] + xt1[(size_t)row*128 + c];
      v[nf] = xx; sm += xx;
    }
    sm += __shfl_xor(sm, 1); sm += __shfl_xor(sm, 2);
    sm += __shfl_xor(sm, 4); sm += __shfl_xor(sm, 8);
    float mu = sm * 0.0078125f;
    float qv = 0.f;
    #pragma unroll
    for (int nf = 0; nf < 8; ++nf) { float d = v[nf] - mu; qv += d*d; }
    qv += __shfl_xor(qv, 1); qv += __shfl_xor(qv, 2);
    qv += __shfl_xor(qv, 4); qv += __shfl_xor(qv, 8);
    float rr = rsqrtf(qv * 0.0078125f + 1e-5f);
    #pragma unroll
    for (int nf = 0; nf < 8; ++nf) {
      int c = nf*16 + seg;
      out[(size_t)row*128 + c] = (v[nf] - mu) * rr * gam[c] + bet[c];
    }
  }
}

// ------------------------- flash attention (swapped-QK, no-max, KV-split 8) -
// l computed via constant-ones MFMA B-fragment (matrix pipe, not VALU);
// P packed to bf16 via v_cvt_pk_bf16_f32.
__global__ __launch_bounds__(256) void attn_k(
    const unsigned short* __restrict__ qkvb,
    unsigned short* __restrict__ po, float* __restrict__ pl) {
  __shared__ unsigned short lK[128][40];
  __shared__ unsigned short lV[32][136];
  const int tid = threadIdx.x, lane = tid & 63, w = tid >> 6;
  const int hh = blockIdx.y, sp = blockIdx.z;
  const int qr = blockIdx.x * 64 + w * 16;
  const int g = lane >> 4, q = lane & 15;

  s16x8 qf = *(const s16x8*)&qkvb[(size_t)(qr + q)*384 + hh*32 + g*8];

  f32x4 o[2], ol;
  o[0] = f32x4{0.f,0.f,0.f,0.f}; o[1] = f32x4{0.f,0.f,0.f,0.f};
  ol = f32x4{0.f,0.f,0.f,0.f};

  // constant ones B-fragment: column 0 of a virtual ones-matrix
  s16x8 onesf;
  {
    short ov = (q == 0) ? (short)0x3F80 : (short)0;
    #pragma unroll
    for (int e = 0; e < 8; ++e) onesf[e] = ov;
  }

  const int srcA = q | ((2*(g & 1)) << 4);
  const int srcB = srcA + 16;
  const bool hi = (g >> 1) != 0;

  for (int kt = sp*4; kt < sp*4 + 4; ++kt) {
    const int k0 = kt * 128;
    __syncthreads();
    {
      int key = tid >> 1, d0 = (tid & 1) * 16;
      const unsigned short* src = qkvb + (size_t)(k0 + key)*384 + 128 + hh*32 + d0;
      *(u16x8*)&lK[key][d0]     = *(const u16x8*)&src[0];
      *(u16x8*)&lK[key][d0 + 8] = *(const u16x8*)&src[8];
    }
    {
      int kp = tid & 63, gg = tid >> 6;
      const unsigned short* s0 = qkvb + (size_t)(k0 + 2*kp)*384 + 256 + hh*32 + gg*8;
      u16x8 e0 = *(const u16x8*)s0;
      u16x8 e1 = *(const u16x8*)(s0 + 384);
      #pragma unroll
      for (int d = 0; d < 8; ++d) {
        unsigned int pkk = (unsigned int)e0[d] | ((unsigned int)e1[d] << 16);
        *(unsigned int*)&lV[gg*8 + d][2*kp] = pkk;
      }
    }
    __syncthreads();

    unsigned int pk[8][2];
    #pragma unroll
    for (int nf = 0; nf < 8; ++nf) {
      s16x8 kf = *(const s16x8*)&lK[nf*16 + q][g*8];
      f32x4 c = MFMA16(kf, qf, (f32x4{0.f,0.f,0.f,0.f}));
      float p0 = exp2f(c[0]), p1 = exp2f(c[1]);
      float p2 = exp2f(c[2]), p3 = exp2f(c[3]);
      unsigned int r0, r1;
      asm("v_cvt_pk_bf16_f32 %0, %1, %2" : "=v"(r0) : "v"(p0), "v"(p1));
      asm("v_cvt_pk_bf16_f32 %0, %1, %2" : "=v"(r1) : "v"(p2), "v"(p3));
      pk[nf][0] = r0;
      pk[nf][1] = r1;
    }

    #pragma unroll
    for (int kc = 0; kc < 4; ++kc) {
      unsigned int a0 = (unsigned int)__shfl((int)pk[2*kc][0],   srcA);
      unsigned int b0 = (unsigned int)__shfl((int)pk[2*kc+1][0], srcA);
      unsigned int a1 = (unsigned int)__shfl((int)pk[2*kc][1],   srcA);
      unsigned int b1 = (unsigned int)__shfl((int)pk[2*kc+1][1], srcA);
      unsigned int a2 = (unsigned int)__shfl((int)pk[2*kc][0],   srcB);
      unsigned int b2 = (unsigned int)__shfl((int)pk[2*kc+1][0], srcB);
      unsigned int a3 = (unsigned int)__shfl((int)pk[2*kc][1],   srcB);
      unsigned int b3 = (unsigned int)__shfl((int)pk[2*kc+1][1], srcB);
      u32x4 wv;
      wv[0] = hi ? b0 : a0; wv[1] = hi ? b1 : a1;
      wv[2] = hi ? b2 : a2; wv[3] = hi ? b3 : a3;
      s16x8 pa = __builtin_bit_cast(s16x8, wv);
      #pragma unroll
      for (int df = 0; df < 2; ++df) {
        s16x8 vf = *(const s16x8*)&lV[df*16 + q][kc*32 + g*8];
        o[df] = MFMA16(pa, vf, o[df]);
      }
      ol = MFMA16(pa, onesf, ol);   // row-sums accumulate into col 0 (q==0 lanes)
    }
  }
  #pragma unroll
  for (int df = 0; df < 2; ++df)
    #pragma unroll
    for (int j = 0; j < 4; ++j) {
      int row = qr + g*4 + j;
      po[((size_t)sp*4096 + row)*128 + hh*32 + df*16 + q] = f2bf(o[df][j]);
    }
  if (q == 0) {
    #pragma unroll
    for (int j = 0; j < 4; ++j)
      pl[((sp*4 + hh) << 12) + qr + g*4 + j] = ol[j];
  }
}

// ------------------------- launch -------------------------
extern "C" void kernel_launch(void* const* d_in, const int* in_sizes, int n_in,
                              void* d_out, int out_size, void* d_ws, size_t ws_size,
                              hipStream_t stream) {
  const float* x    = (const float*)d_in[0];
  const float* pos  = (const float*)d_in[1];
  const int*   idx  = (const int*)d_in[2];
  const float* W1   = (const float*)d_in[4];
  const float* b1   = (const float*)d_in[5];
  const float* W2   = (const float*)d_in[6];
  const float* b2   = (const float*)d_in[7];
  const float* Wr   = (const float*)d_in[8];
  const float* br   = (const float*)d_in[9];
  const float* ipw  = (const float*)d_in[10];
  const float* ipb  = (const float*)d_in[11];
  const float* opw  = (const float*)d_in[12];
  const float* opb  = (const float*)d_in[13];
  const float* Wm1  = (const float*)d_in[14];
  const float* bm1  = (const float*)d_in[15];
  const float* Wm2  = (const float*)d_in[16];
  const float* bm2  = (const float*)d_in[17];
  const float* g1   = (const float*)d_in[18];
  const float* be1  = (const float*)d_in[19];
  const float* g2   = (const float*)d_in[20];
  const float* be2  = (const float*)d_in[21];
  float* out = (float*)d_out;
  char* ws = (char*)d_ws;

  float4*         pos4  = (float4*)(ws + OFF_POS4);
  int*            colp  = (int*)(ws + OFF_COL);
  unsigned short* w1t   = (unsigned short*)(ws + OFF_W1T);
  unsigned short* w2t   = (unsigned short*)(ws + OFF_W2T);
  unsigned short* wrt   = (unsigned short*)(ws + OFF_WRT);
  unsigned short* wqkvt = (unsigned short*)(ws + OFF_WQKVT);
  unsigned short* woutt = (unsigned short*)(ws + OFF_WOUTT);
  unsigned short* wm1t  = (unsigned short*)(ws + OFF_WM1T);
  unsigned short* wm2t  = (unsigned short*)(ws + OFF_WM2T);
  float4* sposp = (float4*)(ws + OFF_SPOS);
  int*    ccnt  = (int*)(ws + OFF_CELLCNT);
  int2*   cdesc = (int2*)(ws + OFF_CELLDSC);
  int*    cfill = (int*)(ws + OFF_FILL);
  unsigned short* pou = (unsigned short*)(ws + OFF_PO);
  float*  plp   = (float*)(ws + OFF_PL);
  float* aggp  = (float*)(ws + OFF_AGG);
  float* xt0p  = (float*)(ws + OFF_XT0);
  unsigned short* qkvb = (unsigned short*)(ws + OFF_QKV);
  float* xt1p  = (float*)(ws + OFF_XT1);
  float* sbias = (float*)(ws + OFF_SBIAS);

  zero_k<<<128, 256, 0, stream>>>(ccnt);
  prep_k<<<946, 256, 0, stream>>>(pos, W1, W2, Wr, ipw, ipb, opw, Wm1, Wm2,
                                  pos4, w1t, w2t, wrt, wqkvt, woutt, wm1t, wm2t,
                                  ccnt, sbias);
  prefix_k<<<1, 1024, 0, stream>>>(ccnt, cdesc, cfill);
  scatter_k<<<128, 256, 0, stream>>>(pos4, cfill, sposp);
  knn_k<<<1024, 256, 0, stream>>>(sposp, cdesc, pos4, idx, colp,
                                  out + 524288, out + 536576);
  conv_k<<<1024, 256, 0, stream>>>(x, pos4, idx, colp, w1t, b1, w2t, b2, aggp);
  gemm_k<256, 128, false, false, false><<<dim3(64, 2), 256, 0, stream>>>(aggp, wrt, br, nullptr, xt0p);
  gemm_k<128, 384, false, false, true><<<dim3(64, 6), 256, 0, stream>>>(xt0p, wqkvt, sbias, nullptr, (float*)qkvb);
  attn_k<<<dim3(64, 4, 8), 256, 0, stream>>>(qkvb, pou, plp);
  gemmln2_k<128, true><<<256, 256, 0, stream>>>(nullptr, pou, plp, woutt, opb, xt0p, g1, be1, xt1p);
  mlpln_k<<<256, 256, 0, stream>>>(xt1p, wm1t, bm1, wm2t, bm2, g2, be2, out);
}

// Round 17
// 152.368 us; speedup vs baseline: 1.1031x; 1.0066x over previous
//
#include <hip/hip_runtime.h>
#include <hip/hip_bf16.h>

#define DEV static __device__ __forceinline__

typedef __attribute__((ext_vector_type(8))) short          s16x8;
typedef __attribute__((ext_vector_type(8))) unsigned short u16x8;
typedef __attribute__((ext_vector_type(4))) float          f32x4;
typedef __attribute__((ext_vector_type(4))) unsigned int   u32x4;

#define MFMA16(A,B,C) __builtin_amdgcn_mfma_f32_16x16x32_bf16((A),(B),(C),0,0,0)

DEV unsigned short f2bf(float f) {
  unsigned int u = __builtin_bit_cast(unsigned int, f);
  u += 0x7fffu + ((u >> 16) & 1u);
  return (unsigned short)(u >> 16);
}
DEV float bf2f(unsigned short u) {
  unsigned int x = ((unsigned int)u) << 16;
  return __builtin_bit_cast(float, x);
}

// 1/sqrt(32) * log2(e): fold into Q projection so softmax uses exp2 directly
#define QSCL 0.25503562201f

// ------------------------- grid params -------------------------
#define GRID_LO  (-5.0f)
#define GRID_IH  (3.2f)

DEV int cellc(float v) {
  int c = (int)floorf((v - GRID_LO) * GRID_IH);
  return min(31, max(0, c));
}

// ------------------------- ws layout -------------------------
constexpr size_t OFF_POS4  = 0;
constexpr size_t OFF_COL   = 524288;
constexpr size_t OFF_W1T   = 1048576;
constexpr size_t OFF_W2T   = OFF_W1T  + 24576;
constexpr size_t OFF_WRT   = OFF_W2T  + 65536;
constexpr size_t OFF_WQKVT = OFF_WRT  + 65536;
constexpr size_t OFF_WOUTT = OFF_WQKVT+ 98304;
constexpr size_t OFF_WM1T  = OFF_WOUTT+ 32768;
constexpr size_t OFF_WM2T  = OFF_WM1T + 65536;
constexpr size_t OFF_H     = OFF_WM2T + 65536;        // 33554432-byte shared region
// phase 1: cell structures
constexpr size_t OFF_SPOS    = OFF_H;
constexpr size_t OFF_CELLCNT = OFF_H + 524288;
constexpr size_t OFF_CELLDSC = OFF_H + 655360;
constexpr size_t OFF_FILL    = OFF_H + 917504;
// phase 2: attention partials (po bf16: 8*4096*128*2 = 8388608)
constexpr size_t OFF_PO      = OFF_H;
constexpr size_t OFF_PL      = OFF_H + 16777216;      // 524288 (f32, 8 splits)
constexpr size_t OFF_AGG   = OFF_H    + 33554432;
constexpr size_t OFF_XT0   = OFF_AGG  + 4194304;
constexpr size_t OFF_QKV   = OFF_XT0  + 2097152;
constexpr size_t OFF_ATT   = OFF_QKV  + 6291456;
constexpr size_t OFF_PRE   = OFF_ATT  + 2097152;
constexpr size_t OFF_XT1   = OFF_PRE  + 2097152;
constexpr size_t OFF_MLP1  = OFF_XT1  + 2097152;
constexpr size_t OFF_SBIAS = OFF_MLP1 + 4194304;

// ------------------------- zero cell counts -------------------------
__global__ __launch_bounds__(256) void zero_k(int* __restrict__ p) {
  p[blockIdx.x * 256 + threadIdx.x] = 0;
}

// ------------------------- prep -------------------------
__global__ __launch_bounds__(256) void prep_k(
    const float* __restrict__ pos, const float* __restrict__ W1,
    const float* __restrict__ W2, const float* __restrict__ Wr,
    const float* __restrict__ ipw, const float* __restrict__ ipb,
    const float* __restrict__ opw,
    const float* __restrict__ Wm1, const float* __restrict__ Wm2,
    float4* __restrict__ pos4, unsigned short* __restrict__ w1t,
    unsigned short* __restrict__ w2t, unsigned short* __restrict__ wrt,
    unsigned short* __restrict__ wqkvt, unsigned short* __restrict__ woutt,
    unsigned short* __restrict__ wm1t, unsigned short* __restrict__ wm2t,
    int* __restrict__ cellcnt, float* __restrict__ sbias) {
  int T = blockIdx.x * 256 + threadIdx.x;
  if (T < 32768) {
    float px = pos[T*3], py = pos[T*3+1], pz = pos[T*3+2];
    pos4[T] = make_float4(px, py, pz, 0.f);
    int cid = (cellc(pz)*32 + cellc(py))*32 + cellc(px);
    atomicAdd(&cellcnt[cid], 1);
    return;
  }
  T -= 32768;
  if (T < 128*96)  { int n=T/96,  k=T%96;  w1t[T]  = f2bf(k < 67 ? W1[k*128+n] : 0.f); return; }
  T -= 128*96;
  if (T < 256*128) { int n=T/128, k=T%128; w2t[T]  = f2bf(W2[k*256+n]);  return; }
  T -= 256*128;
  if (T < 128*256) { int n=T/256, k=T%256; wrt[T]  = f2bf(Wr[k*128+n]);  return; }
  T -= 128*256;
  if (T < 384*128) { int n=T/128, k=T%128;
                     float v = ipw[k*384+n];
                     if (n < 128) v *= QSCL;
                     wqkvt[T]= f2bf(v); return; }
  T -= 384*128;
  if (T < 128*128) { int n=T/128, k=T%128; woutt[T]= f2bf(opw[k*128+n]); return; }
  T -= 128*128;
  if (T < 256*128) { int n=T/128, k=T%128; wm1t[T] = f2bf(Wm1[k*256+n]); return; }
  T -= 256*128;
  if (T < 128*256) { int n=T/256, k=T%256; wm2t[T] = f2bf(Wm2[k*128+n]); return; }
  T -= 128*256;
  if (T < 384) { sbias[T] = ipb[T] * (T < 128 ? QSCL : 1.f); return; }
}

// ------------------------- prefix over 32768 cell counts -------------------
__global__ __launch_bounds__(1024) void prefix_k(const int* __restrict__ cnt,
                                                 int2* __restrict__ desc,
                                                 int* __restrict__ fill) {
  __shared__ int wsum[16];
  const int tid = threadIdx.x, lane = tid & 63, w = tid >> 6;
  int loc[32]; int s = 0;
  #pragma unroll
  for (int i = 0; i < 32; ++i) { loc[i] = cnt[tid*32 + i]; s += loc[i]; }
  int sc = s;
  #pragma unroll
  for (int off = 1; off < 64; off <<= 1) {
    int v = __shfl_up(sc, off);
    if (lane >= off) sc += v;
  }
  if (lane == 63) wsum[w] = sc;
  __syncthreads();
  if (tid == 0) {
    int run = 0;
    #pragma unroll
    for (int i = 0; i < 16; ++i) { int v = wsum[i]; wsum[i] = run; run += v; }
  }
  __syncthreads();
  int base = wsum[w] + (sc - s);
  #pragma unroll
  for (int i = 0; i < 32; ++i) {
    int c = tid*32 + i;
    desc[c] = make_int2(base, loc[i]);
    fill[c] = base;
    base += loc[i];
  }
}

// ------------------------- scatter -------------------------
__global__ __launch_bounds__(256) void scatter_k(const float4* __restrict__ pos4,
                                                 int* __restrict__ fill,
                                                 float4* __restrict__ spos) {
  int T = blockIdx.x * 256 + threadIdx.x;
  float4 p = pos4[T];
  int cid = (cellc(p.z)*32 + cellc(p.y))*32 + cellc(p.x);
  int slot = atomicAdd(&fill[cid], 1);
  spos[slot] = make_float4(p.x, p.y, p.z, __int_as_float(T));
}

// ------------------------- KNN -------------------------
#define KNN_CAP  320
#define KNN_TRIG 192
#define KNN_KEEP 33
#define KNN_INF  3e37f

__global__ __launch_bounds__(256) void knn_k(
    const float4* __restrict__ spos, const int2* __restrict__ desc,
    const float4* __restrict__ pos4, const int* __restrict__ idx,
    int* __restrict__ col,
    float* __restrict__ outqpos, float* __restrict__ outbatch) {
  __shared__ float bufd[4][KNN_CAP];
  __shared__ int   bufi[4][KNN_CAP];
  __shared__ int   shist[4][64];
  __shared__ int2  segs[4][128];
  const int tid = threadIdx.x, lane = tid & 63, w = tid >> 6;
  const unsigned long long ltmask = (1ull << lane) - 1ull;

  const int q = blockIdx.x * 4 + w;
  const int iq = idx[q];
  const float4 qp = pos4[iq];
  const float qx = qp.x, qy = qp.y, qz = qp.z;
  const int cx0 = cellc(qx), cy0 = cellc(qy), cz0 = cellc(qz);

  float t = KNN_INF;
  int cnt = 0;

  auto compact = [&]() {
    int c_ = min(cnt, KNN_CAP);
    float vd[5]; int vi[5], bs[5]; bool okv[5];
    float dmax = 1e-30f;
    #pragma unroll
    for (int s = 0; s < 5; ++s) {
      int o2 = s*64 + lane;
      okv[s] = o2 < c_;
      vd[s] = okv[s] ? bufd[w][o2] : 0.f;
      vi[s] = okv[s] ? bufi[w][o2] : 0;
      dmax = fmaxf(dmax, vd[s]);
    }
    #pragma unroll
    for (int off = 1; off < 64; off <<= 1) dmax = fmaxf(dmax, __shfl_xor(dmax, off));
    float scale = 63.99f / dmax;
    shist[w][lane] = 0;
    #pragma unroll
    for (int s = 0; s < 5; ++s) {
      bs[s] = okv[s] ? min(63, (int)(vd[s] * scale)) : 64;
      if (okv[s]) atomicAdd(&shist[w][bs[s]], 1);
    }
    int h = shist[w][lane];
    #pragma unroll
    for (int off = 1; off < 64; off <<= 1) {
      int v = __shfl_up(h, off);
      if (lane >= off) h += v;
    }
    unsigned long long mk = __ballot(h >= KNN_KEEP);
    int E = mk ? (__ffsll((long long)mk) - 1) : 63;
    int base = 0;
    #pragma unroll
    for (int s = 0; s < 5; ++s) {
      bool keep = okv[s] && bs[s] <= E;
      unsigned long long km = __ballot(keep);
      int pp = base + (int)__popcll(km & ltmask);
      if (keep) { bufd[w][pp] = vd[s]; bufi[w][pp] = vi[s]; }
      base += (int)__popcll(km);
    }
    cnt = base;
    t = fminf(t, (float)(E + 1) / scale);
  };

  auto scan_rows = [&](int knew, int kold) {
    const int S = 2*knew + 1;
    const int NR = S*S;
    const float invS = 1.f / (float)S;
    for (int r0 = 0; r0 < NR; r0 += 64) {
      int r = r0 + lane;
      bool v = r < NR;
      int dz = (int)((float)r * invS);
      int rem = r - dz*S;
      if (rem < 0) { dz--; rem += S; } else if (rem >= S) { dz++; rem -= S; }
      int ccz = cz0 + dz - knew, ccy = cy0 + rem - knew;
      bool rowok = v && ccz >= 0 && ccz < 32 && ccy >= 0 && ccy < 32;
      bool inner = kold >= 0 && abs(dz - knew) <= kold && abs(rem - knew) <= kold;
      int cbase = (ccz*32 + ccy) * 32;
      int sL = 0, lL = 0, sR = 0, lR = 0;
      if (rowok) {
        int xa = max(cx0 - knew, 0);
        int xb = inner ? (cx0 - kold - 1) : min(cx0 + knew, 31);
        if (xa <= xb) {
          int2 d0 = desc[cbase + xa];
          int2 d1 = desc[cbase + xb];
          sL = d0.x; lL = d1.x + d1.y - d0.x;
        }
        if (inner) {
          int xa2 = cx0 + kold + 1, xb2 = min(cx0 + knew, 31);
          if (xa2 <= xb2 && xa2 >= 0) {
            int2 d0 = desc[cbase + xa2];
            int2 d1 = desc[cbase + xb2];
            sR = d0.x; lR = d1.x + d1.y - d0.x;
          }
        }
      }
      int cumL = lL;
      #pragma unroll
      for (int off = 1; off < 64; off <<= 1) {
        int vv = __shfl_up(cumL, off);
        if (lane >= off) cumL += vv;
      }
      int sumL = __shfl(cumL, 63);
      int cumR = lR;
      #pragma unroll
      for (int off = 1; off < 64; off <<= 1) {
        int vv = __shfl_up(cumR, off);
        if (lane >= off) cumR += vv;
      }
      int sumR = __shfl(cumR, 63);
      segs[w][lane]      = make_int2(sL, cumL - lL);
      segs[w][64 + lane] = make_int2(sR, sumL + cumR - lR);
      const int total = sumL + sumR;

      for (int b = 0; b < total; b += 320) {
        float d2v[5]; int piv[5]; bool hv[5];
        #pragma unroll
        for (int s5 = 0; s5 < 5; ++s5) {
          int p = b + s5*64 + lane;
          bool act = p < total;
          hv[s5] = false; d2v[s5] = 0.f; piv[s5] = 0;
          if (act) {
            int lo = 0;
            #pragma unroll
            for (int st = 64; st > 0; st >>= 1)
              if (segs[w][lo + st].y <= p) lo += st;
            int2 e = segs[w][lo];
            float4 pt = spos[e.x + (p - e.y)];
            float ddx = qx-pt.x, ddy = qy-pt.y, ddz = qz-pt.z;
            float d2 = ddx*ddx + ddy*ddy + ddz*ddz;
            d2v[s5] = d2; piv[s5] = __float_as_int(pt.w);
            hv[s5] = d2 < t;
          }
        }
        #pragma unroll
        for (int s5 = 0; s5 < 5; ++s5) {
          unsigned long long hm = __ballot(hv[s5]);
          if (hm) {
            int pp = cnt + (int)__popcll(hm & ltmask);
            if (hv[s5] && pp < KNN_CAP) { bufd[w][pp] = d2v[s5]; bufi[w][pp] = piv[s5]; }
            cnt += (int)__popcll(hm);
            if (cnt >= KNN_TRIG) compact();
          }
        }
      }
    }
  };

  auto bound32 = [&]() -> float {
    int c_ = min(cnt, KNN_CAP);
    float vv[5]; bool okv[5];
    float dmax = 1e-30f;
    #pragma unroll
    for (int s = 0; s < 5; ++s) {
      int o2 = s*64 + lane;
      okv[s] = o2 < c_;
      vv[s] = okv[s] ? bufd[w][o2] : 0.f;
      dmax = fmaxf(dmax, vv[s]);
    }
    #pragma unroll
    for (int off = 1; off < 64; off <<= 1) dmax = fmaxf(dmax, __shfl_xor(dmax, off));
    float scale = 63.99f / dmax;
    shist[w][lane] = 0;
    #pragma unroll
    for (int s = 0; s < 5; ++s)
      if (okv[s]) atomicAdd(&shist[w][min(63, (int)(vv[s] * scale))], 1);
    int h = shist[w][lane];
    #pragma unroll
    for (int off = 1; off < 64; off <<= 1) {
      int v = __shfl_up(h, off);
      if (lane >= off) h += v;
    }
    unsigned long long m = __ballot(h >= 32);
    int E = m ? (__ffsll((long long)m) - 1) : 63;
    return (float)(E + 1) / scale;
  };

  int kcur = 1;
  scan_rows(1, -1);
  for (int it = 0; it < 64; ++it) {
    if (cnt >= 32) {
      float t32u = bound32();
      t = fminf(t, t32u);
      int kneed = (int)(__builtin_sqrtf(t32u) * GRID_IH) + 1;
      if (kneed <= kcur || kcur >= 31) break;
      int knew = min(kneed, 31);
      scan_rows(knew, kcur);
      kcur = knew;
    } else {
      if (kcur >= 31) break;
      int knew = min(kcur + (cnt == 0 ? 2 : 1), 31);
      scan_rows(knew, kcur);
      kcur = knew;
    }
  }

  // ---- final exact top-32 ----
  {
    int c_ = min(cnt, KNN_CAP);
    float vd[5]; int vi[5], bs[5]; bool okf[5];
    float dmax = 1e-30f;
    #pragma unroll
    for (int s = 0; s < 5; ++s) {
      int o2 = s*64 + lane;
      okf[s] = o2 < c_;
      vd[s] = okf[s] ? bufd[w][o2] : KNN_INF;
      vi[s] = okf[s] ? bufi[w][o2] : 0;
      dmax = fmaxf(dmax, okf[s] ? vd[s] : 0.f);
    }
    #pragma unroll
    for (int off = 1; off < 64; off <<= 1) dmax = fmaxf(dmax, __shfl_xor(dmax, off));
    float sc64 = 63.99f / dmax;
    shist[w][lane] = 0;
    #pragma unroll
    for (int s = 0; s < 5; ++s) {
      bs[s] = okf[s] ? min(63, (int)(vd[s] * sc64)) : 64;
      if (okf[s]) atomicAdd(&shist[w][bs[s]], 1);
    }
    int h = shist[w][lane];
    #pragma unroll
    for (int off = 1; off < 64; off <<= 1) {
      int v = __shfl_up(h, off);
      if (lane >= off) h += v;
    }
    unsigned long long m = __ballot(h >= 32);
    int E = m ? (__ffsll((long long)m) - 1) : 63;
    int c0 = (E > 0) ? __shfl(h, E - 1) : 0;
    int base = 0;
    #pragma unroll
    for (int s = 0; s < 5; ++s) {
      bool wr = okf[s] && (bs[s] < E);
      unsigned long long km = __ballot(wr);
      int pp = base + (int)__popcll(km & ltmask);
      if (wr) col[q*32 + pp] = vi[s];
      base += (int)__popcll(km);
    }
    #pragma unroll
    for (int s = 0; s < 5; ++s)
      if (!(okf[s] && bs[s] == E)) vd[s] = KNN_INF;
    int r = 32 - c0;
    #pragma unroll 1
    for (int kk = 0; kk < r; ++kk) {
      float bd = vd[0]; int bi = vi[0]; int bc = lane*8;
      #pragma unroll
      for (int s = 1; s < 5; ++s)
        if (vd[s] < bd) { bd = vd[s]; bi = vi[s]; bc = lane*8 + s; }
      #pragma unroll
      for (int off = 1; off < 64; off <<= 1) {
        float od = __shfl_xor(bd, off);
        int   oi = __shfl_xor(bi, off);
        int   oc = __shfl_xor(bc, off);
        if (od < bd || (od == bd && oc < bc)) { bd = od; bi = oi; bc = oc; }
      }
      if ((bc >> 3) == lane) {
        int sl = bc & 7;
        #pragma unroll
        for (int s = 0; s < 5; ++s) if (sl == s) vd[s] = KNN_INF;
      }
      if (lane == 0) col[q*32 + c0 + kk] = bi;
    }
  }
  if (lane == 0) {
    outqpos[q*3+0] = qx; outqpos[q*3+1] = qy; outqpos[q*3+2] = qz;
    outbatch[q] = 0.f;
  }
}

// ------------------------- fused conv -------------------------
#define LA1(r,c) S[(r)*104 + (c)]
#define LB1(r,c) S[13312 + (r)*104 + (c)]
#define HB(r,c)  S[(r)*136 + (c)]
#define W2C(r,c) S[17408 + (r)*136 + (c)]

__global__ __launch_bounds__(256) void conv_k(
    const float* __restrict__ x, const float4* __restrict__ pos4,
    const int* __restrict__ idx, const int* __restrict__ col,
    const unsigned short* __restrict__ w1t, const float* __restrict__ b1,
    const unsigned short* __restrict__ w2t, const float* __restrict__ b2,
    float* __restrict__ agg) {
  __shared__ __align__(16) unsigned short S[26624];
  __shared__ int   sci[128];
  __shared__ float sqp[4][3];
  const int tid = threadIdx.x, lane = tid & 63, w = tid >> 6;
  const int wm = w >> 1, wn = w & 1;
  const int m0 = blockIdx.x * 4;

  if (tid < 128) sci[tid] = col[m0*32 + tid];
  if (tid >= 128 && tid < 132) {
    int m = m0 + tid - 128;
    float4 p = pos4[idx[m]];
    sqp[tid-128][0] = p.x; sqp[tid-128][1] = p.y; sqp[tid-128][2] = p.z;
  }
  #pragma unroll
  for (int rnd = 0; rnd < 6; ++rnd) {
    int e = (rnd*256 + tid) * 8;
    int n = e / 96, k = e % 96;
    *(u16x8*)&LB1(n, k) = *(const u16x8*)&w1t[e];
  }
  __syncthreads();

  {
    int r = tid >> 1, half = tid & 1;
    int ci = sci[r];
    const float* src = x + (size_t)ci*64 + half*32;
    #pragma unroll
    for (int c = 0; c < 4; ++c) {
      float4 va = ((const float4*)src)[c*2], vb = ((const float4*)src)[c*2+1];
      u16x8 v;
      v[0]=f2bf(va.x); v[1]=f2bf(va.y); v[2]=f2bf(va.z); v[3]=f2bf(va.w);
      v[4]=f2bf(vb.x); v[5]=f2bf(vb.y); v[6]=f2bf(vb.z); v[7]=f2bf(vb.w);
      *(u16x8*)&LA1(r, half*32 + c*8) = v;
    }
  }
  if (tid < 128) {
    int r = tid, g = r >> 5;
    float4 p = pos4[sci[r]];
    u16x8 z;
    #pragma unroll
    for (int e = 0; e < 8; ++e) z[e] = 0;
    u16x8 v0 = z;
    v0[0] = f2bf(p.x - sqp[g][0]); v0[1] = f2bf(p.y - sqp[g][1]); v0[2] = f2bf(p.z - sqp[g][2]);
    *(u16x8*)&LA1(r, 64) = v0;
    #pragma unroll
    for (int c = 1; c < 5; ++c) *(u16x8*)&LA1(r, 64 + c*8) = z;
  }
  __syncthreads();

  f32x4 acc[4][4];
  #pragma unroll
  for (int nf = 0; nf < 4; ++nf) {
    float bv = b1[wn*64 + nf*16 + (lane & 15)];
    #pragma unroll
    for (int mf = 0; mf < 4; ++mf) acc[mf][nf] = f32x4{bv, bv, bv, bv};
  }
  #pragma unroll
  for (int kc = 0; kc < 3; ++kc) {
    s16x8 af[4], bf_[4];
    #pragma unroll
    for (int mf = 0; mf < 4; ++mf)
      af[mf] = *(const s16x8*)&LA1(wm*64 + mf*16 + (lane&15), kc*32 + (lane>>4)*8);
    #pragma unroll
    for (int nf = 0; nf < 4; ++nf)
      bf_[nf] = *(const s16x8*)&LB1(wn*64 + nf*16 + (lane&15), kc*32 + (lane>>4)*8);
    #pragma unroll
    for (int mf = 0; mf < 4; ++mf)
      #pragma unroll
      for (int nf = 0; nf < 4; ++nf)
        acc[mf][nf] = MFMA16(af[mf], bf_[nf], acc[mf][nf]);
  }
  __syncthreads();

  #pragma unroll
  for (int mf = 0; mf < 4; ++mf)
    #pragma unroll
    for (int nf = 0; nf < 4; ++nf)
      #pragma unroll
      for (int j = 0; j < 4; ++j) {
        int rloc = wm*64 + mf*16 + ((lane>>4)<<2) + j;
        int cloc = wn*64 + nf*16 + (lane & 15);
        HB(rloc, cloc) = f2bf(fmaxf(acc[mf][nf][j], 0.f));
      }
  {
    int r2 = tid >> 2, kq = (tid & 3) * 32;
    const unsigned short* src = w2t + (size_t)r2*128 + kq;
    #pragma unroll
    for (int c = 0; c < 4; ++c)
      *(u16x8*)&W2C(r2, kq + c*8) = *(const u16x8*)&src[c*8];
  }
  __syncthreads();

  #pragma unroll 1
  for (int nc = 0; nc < 4; ++nc) {
    f32x4 acc2[2][4];
    #pragma unroll
    for (int nf = 0; nf < 4; ++nf) {
      float bv = b2[nc*64 + nf*16 + (lane & 15)];
      acc2[0][nf] = f32x4{bv, bv, bv, bv};
      acc2[1][nf] = f32x4{bv, bv, bv, bv};
    }
    #pragma unroll
    for (int ks = 0; ks < 4; ++ks) {
      s16x8 af[2], bf_[4];
      #pragma unroll
      for (int mf = 0; mf < 2; ++mf)
        af[mf] = *(const s16x8*)&HB(w*32 + mf*16 + (lane&15), ks*32 + (lane>>4)*8);
      #pragma unroll
      for (int nf = 0; nf < 4; ++nf)
        bf_[nf] = *(const s16x8*)&W2C(nf*16 + (lane&15), ks*32 + (lane>>4)*8);
      #pragma unroll
      for (int mf = 0; mf < 2; ++mf)
        #pragma unroll
        for (int nf = 0; nf < 4; ++nf)
          acc2[mf][nf] = MFMA16(af[mf], bf_[nf], acc2[mf][nf]);
    }
    #pragma unroll
    for (int nf = 0; nf < 4; ++nf) {
      float mx = acc2[0][nf][0];
      #pragma unroll
      for (int j = 1; j < 4; ++j) mx = fmaxf(mx, acc2[0][nf][j]);
      #pragma unroll
      for (int j = 0; j < 4; ++j) mx = fmaxf(mx, acc2[1][nf][j]);
      mx = fmaxf(mx, __shfl_xor(mx, 16));
      mx = fmaxf(mx, __shfl_xor(mx, 32));
      if (lane < 16) agg[(size_t)(m0 + w)*256 + nc*64 + nf*16 + lane] = mx;
    }
    if (nc < 3) {
      __syncthreads();
      int r2 = tid >> 2, kq = (tid & 3) * 32;
      const unsigned short* src = w2t + (size_t)((nc+1)*64 + r2)*128 + kq;
      #pragma unroll
      for (int c = 0; c < 4; ++c)
        *(u16x8*)&W2C(r2, kq + c*8) = *(const u16x8*)&src[c*8];
      __syncthreads();
    }
  }
}

// ------------------------- fused reduction GEMM + qkv GEMM -----------------
// 16 rows/block, 256 blocks. GEMM1: xt0 = agg@Wr + br (N-split 4x32, K=256,
// global B-frags). xt0 -> f32 global (residual) + bf16 LDS. GEMM2: qkv =
// xt0@Wqkv + sbias (N-split 4x96, K=128), bf16 out.
__global__ __launch_bounds__(256) void rqkv_k(
    const float* __restrict__ agg, const unsigned short* __restrict__ wrt,
    const float* __restrict__ br, const unsigned short* __restrict__ wqkvt,
    const float* __restrict__ sbias, float* __restrict__ xt0,
    unsigned short* __restrict__ qkvb) {
  __shared__ __align__(16) unsigned short lA[16 * 264];
  __shared__ __align__(16) unsigned short lX[16 * 136];
  const int tid = threadIdx.x, lane = tid & 63, w = tid >> 6;
  const int g = lane >> 4, ln_ = lane & 15;
  const int m0 = blockIdx.x * 16;

  {
    int r = tid >> 4, seg = tid & 15;
    const float* src = agg + (size_t)(m0 + r)*256 + seg*16;
    #pragma unroll
    for (int c = 0; c < 2; ++c) {
      float4 va = ((const float4*)src)[c*2], vb = ((const float4*)src)[c*2+1];
      u16x8 v;
      v[0]=f2bf(va.x); v[1]=f2bf(va.y); v[2]=f2bf(va.z); v[3]=f2bf(va.w);
      v[4]=f2bf(vb.x); v[5]=f2bf(vb.y); v[6]=f2bf(vb.z); v[7]=f2bf(vb.w);
      *(u16x8*)&lA[r*264 + seg*16 + c*8] = v;
    }
  }
  __syncthreads();

  { // GEMM1: cols n0..n0+31, K=256
    const int n0 = w * 32;
    f32x4 acc[2];
    #pragma unroll
    for (int nf = 0; nf < 2; ++nf) {
      float bv = br[n0 + nf*16 + ln_];
      acc[nf] = f32x4{bv, bv, bv, bv};
    }
    #pragma unroll
    for (int ks = 0; ks < 8; ++ks) {
      s16x8 af = *(const s16x8*)&lA[ln_*264 + ks*32 + g*8];
      #pragma unroll
      for (int nf = 0; nf < 2; ++nf) {
        s16x8 bf_ = *(const s16x8*)&wrt[(size_t)(n0 + nf*16 + ln_)*256 + ks*32 + g*8];
        acc[nf] = MFMA16(af, bf_, acc[nf]);
      }
    }
    #pragma unroll
    for (int nf = 0; nf < 2; ++nf)
      #pragma unroll
      for (int j = 0; j < 4; ++j) {
        int row = m0 + g*4 + j;
        int c = n0 + nf*16 + ln_;
        float v = acc[nf][j];
        xt0[(size_t)row*128 + c] = v;
        lX[(g*4 + j)*136 + c] = f2bf(v);
      }
  }
  __syncthreads();

  { // GEMM2: qkv cols n0q..n0q+95, K=128
    const int n0q = w * 96;
    f32x4 acc2[6];
    #pragma unroll
    for (int nf = 0; nf < 6; ++nf) {
      float bv = sbias[n0q + nf*16 + ln_];
      acc2[nf] = f32x4{bv, bv, bv, bv};
    }
    #pragma unroll
    for (int ks = 0; ks < 4; ++ks) {
      s16x8 af = *(const s16x8*)&lX[ln_*136 + ks*32 + g*8];
      #pragma unroll
      for (int nf = 0; nf < 6; ++nf) {
        s16x8 bf_ = *(const s16x8*)&wqkvt[(size_t)(n0q + nf*16 + ln_)*128 + ks*32 + g*8];
        acc2[nf] = MFMA16(af, bf_, acc2[nf]);
      }
    }
    #pragma unroll
    for (int nf = 0; nf < 6; ++nf)
      #pragma unroll
      for (int j = 0; j < 4; ++j) {
        int row = m0 + g*4 + j;
        qkvb[(size_t)row*384 + n0q + nf*16 + ln_] = f2bf(acc2[nf][j]);
      }
  }
}

// ------------------------- fused out_proj + residual + LN (N-split) --------
template<int KFULL, bool COMBINE>
__global__ __launch_bounds__(256) void gemmln2_k(
    const float* __restrict__ A,
    const unsigned short* __restrict__ po, const float* __restrict__ pl,
    const unsigned short* __restrict__ Bt, const float* __restrict__ bias,
    const float* __restrict__ res,
    const float* __restrict__ gam, const float* __restrict__ bet,
    float* __restrict__ out) {
  constexpr int KP = KFULL + 8;
  __shared__ __align__(16) unsigned short lA[16 * KP];
  __shared__ float vout[16 * 132];
  const int tid = threadIdx.x, lane = tid & 63, w = tid >> 6;
  const int g = lane >> 4, ln_ = lane & 15;
  const int m0 = blockIdx.x * 16;

  {
    int r = tid >> 4, seg = tid & 15;
    int row = m0 + r;
    if (COMBINE) {
      int hh = seg >> 2;
      float lsum = 0.f;
      #pragma unroll
      for (int s = 0; s < 8; ++s) lsum += pl[((s*4 + hh) << 12) + row];
      float inv = 1.f / lsum;
      float a[8] = {0,0,0,0,0,0,0,0};
      #pragma unroll
      for (int s = 0; s < 8; ++s) {
        u16x8 v = *(const u16x8*)&po[((size_t)s*4096 + row)*128 + seg*8];
        #pragma unroll
        for (int e = 0; e < 8; ++e) a[e] += bf2f(v[e]);
      }
      u16x8 ov;
      #pragma unroll
      for (int e = 0; e < 8; ++e) ov[e] = f2bf(a[e] * inv);
      *(u16x8*)&lA[r*KP + seg*8] = ov;
    } else {
      const float* src = A + (size_t)row*KFULL + seg*(KFULL/16);
      #pragma unroll
      for (int c = 0; c < KFULL/128; ++c) {
        float4 va = ((const float4*)src)[c*2], vb = ((const float4*)src)[c*2+1];
        u16x8 v;
        v[0]=f2bf(va.x); v[1]=f2bf(va.y); v[2]=f2bf(va.z); v[3]=f2bf(va.w);
        v[4]=f2bf(vb.x); v[5]=f2bf(vb.y); v[6]=f2bf(vb.z); v[7]=f2bf(vb.w);
        *(u16x8*)&lA[r*KP + seg*(KFULL/16) + c*8] = v;
      }
    }
  }
  __syncthreads();

  const int n0 = w * 32;
  f32x4 acc[2];
  #pragma unroll
  for (int nf = 0; nf < 2; ++nf) {
    float bv = bias[n0 + nf*16 + ln_];
    acc[nf] = f32x4{bv, bv, bv, bv};
  }
  #pragma unroll
  for (int ks = 0; ks < KFULL/32; ++ks) {
    s16x8 af = *(const s16x8*)&lA[ln_*KP + ks*32 + g*8];
    #pragma unroll
    for (int nf = 0; nf < 2; ++nf) {
      s16x8 bf_ = *(const s16x8*)&Bt[(size_t)(n0 + nf*16 + ln_)*KFULL + ks*32 + g*8];
      acc[nf] = MFMA16(af, bf_, acc[nf]);
    }
  }
  #pragma unroll
  for (int nf = 0; nf < 2; ++nf)
    #pragma unroll
    for (int j = 0; j < 4; ++j)
      vout[(g*4 + j)*132 + n0 + nf*16 + ln_] = acc[nf][j];
  __syncthreads();

  {
    int r = tid >> 4, seg = tid & 15;
    int row = m0 + r;
    float v[8]; float sm = 0.f;
    #pragma unroll
    for (int nf = 0; nf < 8; ++nf) {
      int c = nf*16 + seg;
      float xx = vout[r*132 + c] + res[(size_t)row*128 + c];
      v[nf] = xx; sm += xx;
    }
    sm += __shfl_xor(sm, 1); sm += __shfl_xor(sm, 2);
    sm += __shfl_xor(sm, 4); sm += __shfl_xor(sm, 8);
    float mu = sm * 0.0078125f;
    float qv = 0.f;
    #pragma unroll
    for (int nf = 0; nf < 8; ++nf) { float d = v[nf] - mu; qv += d*d; }
    qv += __shfl_xor(qv, 1); qv += __shfl_xor(qv, 2);
    qv += __shfl_xor(qv, 4); qv += __shfl_xor(qv, 8);
    float rr = rsqrtf(qv * 0.0078125f + 1e-5f);
    #pragma unroll
    for (int nf = 0; nf < 8; ++nf) {
      int c = nf*16 + seg;
      out[(size_t)row*128 + c] = (v[nf] - mu) * rr * gam[c] + bet[c];
    }
  }
}

// ------------------------- fused MLP (mlp1+relu+mlp2+res+LN) ---------------
__global__ __launch_bounds__(256) void mlpln_k(
    const float* __restrict__ xt1,
    const unsigned short* __restrict__ wm1t, const float* __restrict__ bm1,
    const unsigned short* __restrict__ wm2t, const float* __restrict__ bm2,
    const float* __restrict__ gam, const float* __restrict__ bet,
    float* __restrict__ out) {
  __shared__ __align__(16) unsigned short lA[16 * 136];
  __shared__ __align__(16) unsigned short lH[16 * 264];
  __shared__ float vout[16 * 132];
  const int tid = threadIdx.x, lane = tid & 63, w = tid >> 6;
  const int g = lane >> 4, ln_ = lane & 15;
  const int m0 = blockIdx.x * 16;

  {
    int r = tid >> 4, seg = tid & 15;
    const float* src = xt1 + (size_t)(m0 + r)*128 + seg*8;
    float4 va = ((const float4*)src)[0], vb = ((const float4*)src)[1];
    u16x8 v;
    v[0]=f2bf(va.x); v[1]=f2bf(va.y); v[2]=f2bf(va.z); v[3]=f2bf(va.w);
    v[4]=f2bf(vb.x); v[5]=f2bf(vb.y); v[6]=f2bf(vb.z); v[7]=f2bf(vb.w);
    *(u16x8*)&lA[r*136 + seg*8] = v;
  }
  __syncthreads();

  {
    const int n0 = w * 64;
    f32x4 acc1[4];
    #pragma unroll
    for (int nf = 0; nf < 4; ++nf) {
      float bv = bm1[n0 + nf*16 + ln_];
      acc1[nf] = f32x4{bv, bv, bv, bv};
    }
    #pragma unroll
    for (int ks = 0; ks < 4; ++ks) {
      s16x8 af = *(const s16x8*)&lA[ln_*136 + ks*32 + g*8];
      #pragma unroll
      for (int nf = 0; nf < 4; ++nf) {
        s16x8 bf_ = *(const s16x8*)&wm1t[(size_t)(n0 + nf*16 + ln_)*128 + ks*32 + g*8];
        acc1[nf] = MFMA16(af, bf_, acc1[nf]);
      }
    }
    #pragma unroll
    for (int nf = 0; nf < 4; ++nf)
      #pragma unroll
      for (int j = 0; j < 4; ++j)
        lH[(g*4 + j)*264 + n0 + nf*16 + ln_] = f2bf(fmaxf(acc1[nf][j], 0.f));
  }
  __syncthreads();

  {
    const int n0 = w * 32;
    f32x4 acc2[2];
    #pragma unroll
    for (int nf = 0; nf < 2; ++nf) {
      float bv = bm2[n0 + nf*16 + ln_];
      acc2[nf] = f32x4{bv, bv, bv, bv};
    }
    #pragma unroll
    for (int ks = 0; ks < 8; ++ks) {
      s16x8 af = *(const s16x8*)&lH[ln_*264 + ks*32 + g*8];
      #pragma unroll
      for (int nf = 0; nf < 2; ++nf) {
        s16x8 bf_ = *(const s16x8*)&wm2t[(size_t)(n0 + nf*16 + ln_)*256 + ks*32 + g*8];
        acc2[nf] = MFMA16(af, bf_, acc2[nf]);
      }
    }
    #pragma unroll
    for (int nf = 0; nf < 2; ++nf)
      #pragma unroll
      for (int j = 0; j < 4; ++j)
        vout[(g*4 + j)*132 + n0 + nf*16 + ln_] = acc2[nf][j];
  }
  __syncthreads();

  {
    int r = tid >> 4, seg = tid & 15;
    int row = m0 + r;
    float v[8]; float sm = 0.f;
    #pragma unroll
    for (int nf = 0; nf < 8; ++nf) {
      int c = nf*16 + seg;
      float xx = vout[r*132 + c] + xt1[(size_t)row*128 + c];
      v[nf] = xx; sm += xx;
    }
    sm += __shfl_xor(sm, 1); sm += __shfl_xor(sm, 2);
    sm += __shfl_xor(sm, 4); sm += __shfl_xor(sm, 8);
    float mu = sm * 0.0078125f;
    float qv = 0.f;
    #pragma unroll
    for (int nf = 0; nf < 8; ++nf) { float d = v[nf] - mu; qv += d*d; }
    qv += __shfl_xor(qv, 1); qv += __shfl_xor(qv, 2);
    qv += __shfl_xor(qv, 4); qv += __shfl_xor(qv, 8);
    float rr = rsqrtf(qv * 0.0078125f + 1e-5f);
    #pragma unroll
    for (int nf = 0; nf < 8; ++nf) {
      int c = nf*16 + seg;
      out[(size_t)row*128 + c] = (v[nf] - mu) * rr * gam[c] + bet[c];
    }
  }
}

// ------------------------- flash attention (swapped-QK, no-max, KV-split 8) -
__global__ __launch_bounds__(256) void attn_k(
    const unsigned short* __restrict__ qkvb,
    unsigned short* __restrict__ po, float* __restrict__ pl) {
  __shared__ unsigned short lK[128][40];
  __shared__ unsigned short lV[32][136];
  const int tid = threadIdx.x, lane = tid & 63, w = tid >> 6;
  const int hh = blockIdx.y, sp = blockIdx.z;
  const int qr = blockIdx.x * 64 + w * 16;
  const int g = lane >> 4, q = lane & 15;

  s16x8 qf = *(const s16x8*)&qkvb[(size_t)(qr + q)*384 + hh*32 + g*8];

  f32x4 o[2], ol;
  o[0] = f32x4{0.f,0.f,0.f,0.f}; o[1] = f32x4{0.f,0.f,0.f,0.f};
  ol = f32x4{0.f,0.f,0.f,0.f};

  s16x8 onesf;
  {
    short ov = (q == 0) ? (short)0x3F80 : (short)0;
    #pragma unroll
    for (int e = 0; e < 8; ++e) onesf[e] = ov;
  }

  const int srcA = q | ((2*(g & 1)) << 4);
  const int srcB = srcA + 16;
  const bool hi = (g >> 1) != 0;

  for (int kt = sp*4; kt < sp*4 + 4; ++kt) {
    const int k0 = kt * 128;
    __syncthreads();
    {
      int key = tid >> 1, d0 = (tid & 1) * 16;
      const unsigned short* src = qkvb + (size_t)(k0 + key)*384 + 128 + hh*32 + d0;
      *(u16x8*)&lK[key][d0]     = *(const u16x8*)&src[0];
      *(u16x8*)&lK[key][d0 + 8] = *(const u16x8*)&src[8];
    }
    {
      int kp = tid & 63, gg = tid >> 6;
      const unsigned short* s0 = qkvb + (size_t)(k0 + 2*kp)*384 + 256 + hh*32 + gg*8;
      u16x8 e0 = *(const u16x8*)s0;
      u16x8 e1 = *(const u16x8*)(s0 + 384);
      #pragma unroll
      for (int d = 0; d < 8; ++d) {
        unsigned int pkk = (unsigned int)e0[d] | ((unsigned int)e1[d] << 16);
        *(unsigned int*)&lV[gg*8 + d][2*kp] = pkk;
      }
    }
    __syncthreads();

    unsigned int pk[8][2];
    #pragma unroll
    for (int nf = 0; nf < 8; ++nf) {
      s16x8 kf = *(const s16x8*)&lK[nf*16 + q][g*8];
      f32x4 c = MFMA16(kf, qf, (f32x4{0.f,0.f,0.f,0.f}));
      float p0 = exp2f(c[0]), p1 = exp2f(c[1]);
      float p2 = exp2f(c[2]), p3 = exp2f(c[3]);
      unsigned int r0, r1;
      asm("v_cvt_pk_bf16_f32 %0, %1, %2" : "=v"(r0) : "v"(p0), "v"(p1));
      asm("v_cvt_pk_bf16_f32 %0, %1, %2" : "=v"(r1) : "v"(p2), "v"(p3));
      pk[nf][0] = r0;
      pk[nf][1] = r1;
    }

    #pragma unroll
    for (int kc = 0; kc < 4; ++kc) {
      unsigned int a0 = (unsigned int)__shfl((int)pk[2*kc][0],   srcA);
      unsigned int b0 = (unsigned int)__shfl((int)pk[2*kc+1][0], srcA);
      unsigned int a1 = (unsigned int)__shfl((int)pk[2*kc][1],   srcA);
      unsigned int b1 = (unsigned int)__shfl((int)pk[2*kc+1][1], srcA);
      unsigned int a2 = (unsigned int)__shfl((int)pk[2*kc][0],   srcB);
      unsigned int b2 = (unsigned int)__shfl((int)pk[2*kc+1][0], srcB);
      unsigned int a3 = (unsigned int)__shfl((int)pk[2*kc][1],   srcB);
      unsigned int b3 = (unsigned int)__shfl((int)pk[2*kc+1][1], srcB);
      u32x4 wv;
      wv[0] = hi ? b0 : a0; wv[1] = hi ? b1 : a1;
      wv[2] = hi ? b2 : a2; wv[3] = hi ? b3 : a3;
      s16x8 pa = __builtin_bit_cast(s16x8, wv);
      #pragma unroll
      for (int df = 0; df < 2; ++df) {
        s16x8 vf = *(const s16x8*)&lV[df*16 + q][kc*32 + g*8];
        o[df] = MFMA16(pa, vf, o[df]);
      }
      ol = MFMA16(pa, onesf, ol);
    }
  }
  #pragma unroll
  for (int df = 0; df < 2; ++df)
    #pragma unroll
    for (int j = 0; j < 4; ++j) {
      int row = qr + g*4 + j;
      po[((size_t)sp*4096 + row)*128 + hh*32 + df*16 + q] = f2bf(o[df][j]);
    }
  if (q == 0) {
    #pragma unroll
    for (int j = 0; j < 4; ++j)
      pl[((sp*4 + hh) << 12) + qr + g*4 + j] = ol[j];
  }
}

// ------------------------- launch -------------------------
extern "C" void kernel_launch(void* const* d_in, const int* in_sizes, int n_in,
                              void* d_out, int out_size, void* d_ws, size_t ws_size,
                              hipStream_t stream) {
  const float* x    = (const float*)d_in[0];
  const float* pos  = (const float*)d_in[1];
  const int*   idx  = (const int*)d_in[2];
  const float* W1   = (const float*)d_in[4];
  const float* b1   = (const float*)d_in[5];
  const float* W2   = (const float*)d_in[6];
  const float* b2   = (const float*)d_in[7];
  const float* Wr   = (const float*)d_in[8];
  const float* br   = (const float*)d_in[9];
  const float* ipw  = (const float*)d_in[10];
  const float* ipb  = (const float*)d_in[11];
  const float* opw  = (const float*)d_in[12];
  const float* opb  = (const float*)d_in[13];
  const float* Wm1  = (const float*)d_in[14];
  const float* bm1  = (const float*)d_in[15];
  const float* Wm2  = (const float*)d_in[16];
  const float* bm2  = (const float*)d_in[17];
  const float* g1   = (const float*)d_in[18];
  const float* be1  = (const float*)d_in[19];
  const float* g2   = (const float*)d_in[20];
  const float* be2  = (const float*)d_in[21];
  float* out = (float*)d_out;
  char* ws = (char*)d_ws;

  float4*         pos4  = (float4*)(ws + OFF_POS4);
  int*            colp  = (int*)(ws + OFF_COL);
  unsigned short* w1t   = (unsigned short*)(ws + OFF_W1T);
  unsigned short* w2t   = (unsigned short*)(ws + OFF_W2T);
  unsigned short* wrt   = (unsigned short*)(ws + OFF_WRT);
  unsigned short* wqkvt = (unsigned short*)(ws + OFF_WQKVT);
  unsigned short* woutt = (unsigned short*)(ws + OFF_WOUTT);
  unsigned short* wm1t  = (unsigned short*)(ws + OFF_WM1T);
  unsigned short* wm2t  = (unsigned short*)(ws + OFF_WM2T);
  float4* sposp = (float4*)(ws + OFF_SPOS);
  int*    ccnt  = (int*)(ws + OFF_CELLCNT);
  int2*   cdesc = (int2*)(ws + OFF_CELLDSC);
  int*    cfill = (int*)(ws + OFF_FILL);
  unsigned short* pou = (unsigned short*)(ws + OFF_PO);
  float*  plp   = (float*)(ws + OFF_PL);
  float* aggp  = (float*)(ws + OFF_AGG);
  float* xt0p  = (float*)(ws + OFF_XT0);
  unsigned short* qkvb = (unsigned short*)(ws + OFF_QKV);
  float* xt1p  = (float*)(ws + OFF_XT1);
  float* sbias = (float*)(ws + OFF_SBIAS);

  zero_k<<<128, 256, 0, stream>>>(ccnt);
  prep_k<<<946, 256, 0, stream>>>(pos, W1, W2, Wr, ipw, ipb, opw, Wm1, Wm2,
                                  pos4, w1t, w2t, wrt, wqkvt, woutt, wm1t, wm2t,
                                  ccnt, sbias);
  prefix_k<<<1, 1024, 0, stream>>>(ccnt, cdesc, cfill);
  scatter_k<<<128, 256, 0, stream>>>(pos4, cfill, sposp);
  knn_k<<<1024, 256, 0, stream>>>(sposp, cdesc, pos4, idx, colp,
                                  out + 524288, out + 536576);
  conv_k<<<1024, 256, 0, stream>>>(x, pos4, idx, colp, w1t, b1, w2t, b2, aggp);
  rqkv_k<<<256, 256, 0, stream>>>(aggp, wrt, br, wqkvt, sbias, xt0p, qkvb);
  attn_k<<<dim3(64, 4, 8), 256, 0, stream>>>(qkvb, pou, plp);
  gemmln2_k<128, true><<<256, 256, 0, stream>>>(nullptr, pou, plp, woutt, opb, xt0p, g1, be1, xt1p);
  mlpln_k<<<256, 256, 0, stream>>>(xt1p, wm1t, bm1, wm2t, bm2, g2, be2, out);
}